// Round 8
// baseline (316.802 us; speedup 1.0000x reference)
//
#include <hip/hip_runtime.h>
#include <math.h>

typedef unsigned short u16;
typedef unsigned char u8;
typedef unsigned int u32;
typedef __attribute__((ext_vector_type(4))) float f32x4;
typedef __attribute__((ext_vector_type(8))) short s16x8;
typedef __attribute__((ext_vector_type(4))) short s16x4;
typedef __attribute__((ext_vector_type(4))) u32 u32x4;
typedef __attribute__((ext_vector_type(2))) u32 u32x2;

__device__ __forceinline__ u16 f2bf(float f) {
  unsigned u = __builtin_bit_cast(unsigned, f);
  u += 0x7fffu + ((u >> 16) & 1u);
  return (u16)(u >> 16);
}

__device__ __forceinline__ u32 cvtpk_bf16(float lo, float hi) {
  u32 r;
  asm("v_cvt_pk_bf16_f32 %0, %1, %2" : "=v"(r) : "v"(lo), "v"(hi));
  return r;
}

__device__ __forceinline__ float max3f(float a, float b, float c) {
  return fmaxf(fmaxf(a, b), c);  // fuses to v_max3_f32
}

#define GLDS16(g, l) __builtin_amdgcn_global_load_lds( \
    (const __attribute__((address_space(1))) void*)(g), \
    (__attribute__((address_space(3))) void*)(l), 16, 0, 0)

// ---------------- GEMM: C[M,N] = A[M,K](bf16) @ BT[N,K](bf16)^T ----------------
// 2-phase double-buffered staging. BM=128 (4 row-tiles/wave) or BM=64 (2).
template <int EPI, int BM>
__global__ __launch_bounds__(256, 2) void gemm_bt(
    const u16* __restrict__ A, const u16* __restrict__ BT, int M, int N, int K,
    const float* __restrict__ bias, const float* __restrict__ resid,
    u16* __restrict__ outB, float* __restrict__ outF) {
  constexpr int MT = BM / 32;  // acc row-tiles per wave
  __shared__ __align__(16) u16 lA[2][BM * 32];
  __shared__ __align__(16) u16 lB[2][128 * 32];
  const int tid = threadIdx.x;
  const int wave = __builtin_amdgcn_readfirstlane(tid >> 6);
  const int lane = tid & 63;
  const int l15 = lane & 15, l4 = lane >> 4;
  const int wr = wave >> 1, wc = wave & 1;
  const int row0 = blockIdx.y * BM, col0 = blockIdx.x * 128;

  f32x4 acc[MT][4] = {};

  auto stage = [&](int bi, int k0) {
#pragma unroll
    for (int c = 0; c < BM / 64; ++c) {
      const int chunk = c * 4 + wave;          // 1KB chunks of A
      const int idx = chunk * 64 + lane;       // 16B-unit index
      const int r = idx >> 2, cb = (idx & 3) * 8;
      GLDS16(A + (size_t)(row0 + r) * K + k0 + cb, &lA[bi][chunk * 512]);
    }
#pragma unroll
    for (int c = 0; c < 2; ++c) {
      const int chunk = c * 4 + wave;
      const int idx = chunk * 64 + lane;
      const int r = idx >> 2, cb = (idx & 3) * 8;
      GLDS16(BT + (size_t)(col0 + r) * K + k0 + cb, &lB[bi][chunk * 512]);
    }
  };

  stage(0, 0);
  __syncthreads();
  int buf = 0;

  for (int k0 = 0; k0 < K; k0 += 32) {
    if (k0 + 32 < K) stage(buf ^ 1, k0 + 32);  // async prefetch, drained at loop-end barrier
    s16x8 af[MT], bfr[4];
#pragma unroll
    for (int m = 0; m < MT; ++m)
      af[m] = *(const s16x8*)&lA[buf][(wr * (BM / 2) + m * 16 + l15) * 32 + l4 * 8];
#pragma unroll
    for (int n = 0; n < 4; ++n)
      bfr[n] = *(const s16x8*)&lB[buf][(wc * 64 + n * 16 + l15) * 32 + l4 * 8];
#pragma unroll
    for (int m = 0; m < MT; ++m)
#pragma unroll
      for (int n = 0; n < 4; ++n)
        acc[m][n] = __builtin_amdgcn_mfma_f32_16x16x32_bf16(af[m], bfr[n], acc[m][n], 0, 0, 0);
    __syncthreads();
    buf ^= 1;
  }

#pragma unroll
  for (int m = 0; m < MT; ++m) {
    const int rowb = row0 + wr * (BM / 2) + m * 16 + l4 * 4;
#pragma unroll
    for (int n = 0; n < 4; ++n) {
      const int col = col0 + wc * 64 + n * 16 + l15;
#pragma unroll
      for (int j = 0; j < 4; ++j) {
        const int r = rowb + j;
        float v = acc[m][n][j];
        if (EPI == 0) {
          outB[(size_t)r * N + col] = f2bf(v);
        } else if (EPI == 1) {
          v += bias[col];
          outB[(size_t)r * N + col] = f2bf(v > 0.0f ? v : 0.0f);
        } else {
          v += bias[col] + resid[(size_t)r * N + col];
          outF[(size_t)r * N + col] = v;
        }
      }
    }
  }
}

// ---------------- weight transpose f32 -> bf16 ----------------
__global__ __launch_bounds__(256) void transpose_f32_bf16(
    const float* __restrict__ in, u16* __restrict__ out, int R, int C) {
  __shared__ float t[32][33];
  const int c0 = blockIdx.x * 32, r0 = blockIdx.y * 32;
  const int tx = threadIdx.x & 31, ty = threadIdx.x >> 5;
#pragma unroll
  for (int i = 0; i < 4; ++i)
    t[ty + i * 8][tx] = in[(size_t)(r0 + ty + i * 8) * C + c0 + tx];
  __syncthreads();
#pragma unroll
  for (int i = 0; i < 4; ++i)
    out[(size_t)(c0 + ty + i * 8) * R + r0 + tx] = f2bf(t[tx][ty + i * 8]);
}

// ---------------- batched bf16 transpose (strided input, col-offset) ----------------
__global__ __launch_bounds__(256) void transpose_bf16_b(
    const u16* __restrict__ in, u16* __restrict__ out, int R, int C, int rstr, int coff) {
  __shared__ u16 t[32][34];
  const int b = blockIdx.z;
  const u16* pi = in + (size_t)b * R * rstr + coff;
  u16* po = out + (size_t)b * R * C;
  const int c0 = blockIdx.x * 32, r0 = blockIdx.y * 32;
  const int tx = threadIdx.x & 31, ty = threadIdx.x >> 5;
#pragma unroll
  for (int i = 0; i < 4; ++i)
    t[ty + i * 8][tx] = pi[(size_t)(r0 + ty + i * 8) * rstr + c0 + tx];
  __syncthreads();
#pragma unroll
  for (int i = 0; i < 4; ++i)
    po[(size_t)(c0 + ty + i * 8) * R + r0 + tx] = t[tx][ty + i * 8];
}

// ---------------- f32 -> bf16 elementwise ----------------
__global__ __launch_bounds__(256) void cvt_f32_bf16(
    const float* __restrict__ in, u16* __restrict__ out, int n4) {
  const int i = blockIdx.x * 256 + threadIdx.x;
  if (i >= n4) return;
  f32x4 v = *(const f32x4*)&in[(size_t)i * 4];
  s16x4 o;
#pragma unroll
  for (int j = 0; j < 4; ++j) o[j] = (short)f2bf(v[j]);
  *(s16x4*)&out[(size_t)i * 4] = o;
}

// ---------------- LayerNorm over D=1024 ----------------
template <int WB>
__global__ __launch_bounds__(256) void layernorm_k(
    const float* __restrict__ in, const float* __restrict__ gm, const float* __restrict__ bt,
    float* __restrict__ outF, u16* __restrict__ outB) {
  const int row = blockIdx.x;
  const int t = threadIdx.x;
  const float* xr = in + (size_t)row * 1024;
  f32x4 v = *(const f32x4*)&xr[t * 4];
  float s = v[0] + v[1] + v[2] + v[3];
  float s2 = v[0] * v[0] + v[1] * v[1] + v[2] * v[2] + v[3] * v[3];
#pragma unroll
  for (int o = 32; o; o >>= 1) {
    s += __shfl_down(s, o);
    s2 += __shfl_down(s2, o);
  }
  __shared__ float red[8];
  const int lane = t & 63, wv = t >> 6;
  if (lane == 0) { red[wv] = s; red[4 + wv] = s2; }
  __syncthreads();
  s = red[0] + red[1] + red[2] + red[3];
  s2 = red[4] + red[5] + red[6] + red[7];
  const float mu = s * (1.0f / 1024.0f);
  const float var = fmaxf(s2 * (1.0f / 1024.0f) - mu * mu, 0.0f);
  const float rs = rsqrtf(var + 1e-5f);
  f32x4 g4 = *(const f32x4*)&gm[t * 4];
  f32x4 b4 = *(const f32x4*)&bt[t * 4];
  f32x4 ov;
#pragma unroll
  for (int j = 0; j < 4; ++j) ov[j] = (v[j] - mu) * rs * g4[j] + b4[j];
  *(f32x4*)&outF[(size_t)row * 1024 + t * 4] = ov;
  if (WB) {
    s16x4 ob;
#pragma unroll
    for (int j = 0; j < 4; ++j) ob[j] = (short)f2bf(ov[j]);
    *(s16x4*)&outB[(size_t)row * 1024 + t * 4] = ob;
  }
}

// ---------------- mask tile summary: any() over 64x64 tiles ----------------
__global__ __launch_bounds__(256) void mask_summary(
    const u8* __restrict__ mask, u8* __restrict__ msum) {
  const int kt = blockIdx.x, qt = blockIdx.y, b = blockIdx.z;
  const int tid = threadIdx.x;
  __shared__ int any_flag;
  if (tid == 0) any_flag = 0;
  __syncthreads();
  const u8* base = mask + ((size_t)(b * 2048 + qt * 64 + (tid >> 2))) * 2048 + kt * 64 + (tid & 3) * 16;
  const u32x4 v = *(const u32x4*)base;
  if (v[0] | v[1] | v[2] | v[3]) any_flag = 1;
  __syncthreads();
  if (tid == 0) msum[((size_t)b * 32 + qt) * 32 + kt] = (u8)any_flag;
}

// ---------------- flash attention, split-KV (2 blocks per q-tile) ----------------
// Grid 1024: (32 bh) x (16 qt) x (2 kv-halves); 4 waves x 32 q-rows (two 16-row
// groups sharing reg-cached K/V frags). Each block does 16 kv-iters over its half
// and writes UNNORMALIZED partial O (f32) + per-row (m,l); attn_combine merges.
// Restores 4 blocks/CU occupancy (R7's 512-block grid was the 102->117 regression).
__global__ __launch_bounds__(256) void attn_k(
    const u16* __restrict__ QKV, const u16* __restrict__ VT,
    const u8* __restrict__ mask, const u8* __restrict__ msum,
    float* __restrict__ opart, float* __restrict__ mlpart) {
  const int S = 2048, QSTR = 3072;
  const int wgid = blockIdx.x;  // 0..1023
  const int xcd = wgid & 7, slot = wgid >> 3;       // slot 0..127
  const int bh = xcd * 4 + (slot >> 5);             // 4 bh per XCD (KV L2-resident)
  const int rem = slot & 31;
  const int kvh = rem >> 4;                         // kv half: 0 or 1
  const int qt = rem & 15;
  const int b = bh >> 4, h = bh & 15;
  const int wave = threadIdx.x >> 6, lane = threadIdx.x & 63;
  const int l15 = lane & 15, l4 = lane >> 4;
  const int q0 = qt * 128 + wave * 32;
  const int kv0 = kvh * 1024, kvend = kv0 + 1024;
  const float CE = 0.125f * 1.44269504f;  // 1/sqrt(64) * log2(e)

  __shared__ __align__(16) u16 lK[2][4096];  // [buf][64 rows x 64 cols], XOR-swizzled
  __shared__ __align__(16) u16 lV[2][4096];

  s16x8 qa[2][2];
#pragma unroll
  for (int g = 0; g < 2; ++g) {
    const size_t qoff = (size_t)(b * S + q0 + g * 16 + l15) * QSTR + h * 64;
    qa[g][0] = *(const s16x8*)&QKV[qoff + l4 * 8];
    qa[g][1] = *(const s16x8*)&QKV[qoff + 32 + l4 * 8];
  }

  f32x4 o[2][4] = {};
  float mr[2] = {-1e30f, -1e30f}, lr[2] = {0.0f, 0.0f};
  const u8* mb = mask + (size_t)b * S * S;
  const u8* msb = msum + (size_t)(b * 32 + qt * 2 + (wave >> 1)) * 32;
  const u16* vbase = VT + (size_t)bh * 64 * S;
  const int bS = b * S;

  auto stage = [&](int bi, int kvv) {
#pragma unroll
    for (int c = 0; c < 2; ++c) {
      const int byt = ((c * 4 + wave) * 64 + lane) * 16;  // 0..8191
      const int row = byt >> 7;
      const int cb = (byt & 127) ^ ((row & 7) << 4);
      GLDS16(QKV + (size_t)(bS + kvv + row) * QSTR + 1024 + h * 64 + (cb >> 1),
             &lK[bi][(c * 4 + wave) * 512]);
      GLDS16(vbase + (size_t)row * S + kvv + (cb >> 1),
             &lV[bi][(c * 4 + wave) * 512]);
    }
  };

  auto body = [&](int bi, int kvv) {
    if (kvv + 64 < kvend) stage(bi ^ 1, kvv + 64);
    const char* kbuf = (const char*)&lK[bi][0];
    const char* vbuf = (const char*)&lV[bi][0];
    // ---- K frags (q-independent, shared by both groups) ----
    s16x8 kf[4][2];
#pragma unroll
    for (int t = 0; t < 4; ++t) {
      const int row = t * 16 + l15;
      const int sw = (row & 7) << 4;
      kf[t][0] = *(const s16x8*)(kbuf + row * 128 + ((l4 * 16) ^ sw));
      kf[t][1] = *(const s16x8*)(kbuf + row * 128 + ((64 + l4 * 16) ^ sw));
    }
    // ---- V frags (q-independent) ----
    s16x4 va[4][4];  // [n][t]
#pragma unroll
    for (int n = 0; n < 4; ++n) {
      const int row = n * 16 + l15;
      const int sw = (row & 7) << 4;
#pragma unroll
      for (int t = 0; t < 4; ++t)
        va[n][t] = *(const s16x4*)(vbuf + row * 128 + ((t * 32 + l4 * 8) ^ sw));
    }
    const int mrow = msb[kvv >> 6];
#pragma unroll
    for (int g = 0; g < 2; ++g) {
      // ---- QK^T (swapped): sc[t] = mfma(K, Q_g) ----
      f32x4 sc[4];
      __builtin_amdgcn_s_setprio(1);
#pragma unroll
      for (int t = 0; t < 4; ++t) {
        f32x4 z = {};
        z = __builtin_amdgcn_mfma_f32_16x16x32_bf16(kf[t][0], qa[g][0], z, 0, 0, 0);
        z = __builtin_amdgcn_mfma_f32_16x16x32_bf16(kf[t][1], qa[g][1], z, 0, 0, 0);
        sc[t] = z;
      }
      __builtin_amdgcn_s_setprio(0);
      // ---- mask (rare slow path via tile summary) ----
      if (mrow) {
#pragma unroll
        for (int t = 0; t < 4; ++t) {
          const uchar4 m4 = *(const uchar4*)&mb[(size_t)(q0 + g * 16 + l15) * S + kvv + t * 16 + l4 * 4];
          if (m4.x) sc[t][0] = -1e30f;
          if (m4.y) sc[t][1] = -1e30f;
          if (m4.z) sc[t][2] = -1e30f;
          if (m4.w) sc[t][3] = -1e30f;
        }
      }
      // ---- INF/NaN scrub (insurance) ----
#pragma unroll
      for (int t = 0; t < 4; ++t)
#pragma unroll
        for (int j = 0; j < 4; ++j) sc[t][j] = fminf(sc[t][j], 1e30f);
      // ---- online softmax with defer-max; max via v_max3 tree ----
      float pm = max3f(sc[0][0], sc[0][1], sc[0][2]);
      pm = max3f(pm, sc[0][3], sc[1][0]);
      pm = max3f(pm, sc[1][1], sc[1][2]);
      pm = max3f(pm, sc[1][3], sc[2][0]);
      pm = max3f(pm, sc[2][1], sc[2][2]);
      pm = max3f(pm, sc[2][3], sc[3][0]);
      pm = max3f(pm, sc[3][1], sc[3][2]);
      pm = fmaxf(pm, sc[3][3]);
      pm = fmaxf(pm, __shfl_xor(pm, 16));
      pm = fmaxf(pm, __shfl_xor(pm, 32));
      if (!__all(pm <= mr[g] + 44.0f)) {  // 44 raw = 8 exp2-units
        const float mn = fmaxf(mr[g], pm);
        const float al = exp2f((mr[g] - mn) * CE);
        mr[g] = mn;
        lr[g] *= al;
#pragma unroll
        for (int n = 0; n < 4; ++n)
#pragma unroll
          for (int j = 0; j < 4; ++j) o[g][n][j] *= al;
      }
      const float mrc = mr[g] * CE;
      float rsum = 0.0f;
#pragma unroll
      for (int t = 0; t < 4; ++t)
#pragma unroll
        for (int j = 0; j < 4; ++j) {
          const float p = exp2f(fmaf(sc[t][j], CE, -mrc));
          sc[t][j] = p;
          rsum += p;
        }
      rsum += __shfl_xor(rsum, 16);
      rsum += __shfl_xor(rsum, 32);
      lr[g] += rsum;
      // ---- pack P into 16x16x16 B-frags (zero cross-lane) ----
      s16x4 pb[4];
#pragma unroll
      for (int t = 0; t < 4; ++t) {
        const u32 lo = cvtpk_bf16(sc[t][0], sc[t][1]);
        const u32 hi = cvtpk_bf16(sc[t][2], sc[t][3]);
        pb[t] = __builtin_bit_cast(s16x4, u32x2{lo, hi});
      }
      // ---- PV: o[g][n] += mfma_16x16x16(V frag, P frag) ----
      __builtin_amdgcn_s_setprio(1);
#pragma unroll
      for (int n = 0; n < 4; ++n)
#pragma unroll
        for (int t = 0; t < 4; ++t)
          o[g][n] = __builtin_amdgcn_mfma_f32_16x16x16bf16_1k(va[n][t], pb[t], o[g][n], 0, 0, 0);
      __builtin_amdgcn_s_setprio(0);
    }
    __syncthreads();  // drains prefetch vmcnt + protects buf swap
  };

  stage(0, kv0);
  __syncthreads();
  for (int kv = kv0; kv < kvend; kv += 128) {  // 8 pairs; buf compile-time per body
    body(0, kv);
    body(1, kv + 64);
  }
  // ---- epilogue: store UNNORMALIZED partial O (f32) + (m,l) per q-row ----
  float* obase = opart + ((size_t)kvh * 65536 + (size_t)bh * 2048) * 64;
#pragma unroll
  for (int g = 0; g < 2; ++g) {
    const int row = q0 + g * 16 + l15;
#pragma unroll
    for (int n = 0; n < 4; ++n)
      *(f32x4*)&obase[(size_t)row * 64 + n * 16 + l4 * 4] = o[g][n];
    if (l4 == 0) {
      const size_t mli = ((size_t)kvh * 65536 + (size_t)bh * 2048 + row) * 2;
      mlpart[mli] = mr[g];
      mlpart[mli + 1] = lr[g];
    }
  }
}

// ---------------- split-KV combine: merge 2 partials, write bf16 attn out ----------------
// row r in [0,65536): bh = r>>11, q = r&2047. Block = 4 rows x 64 lanes (D=64).
__global__ __launch_bounds__(256) void attn_combine(
    const float* __restrict__ opart, const float* __restrict__ mlpart,
    u16* __restrict__ out) {
  const int row = blockIdx.x * 4 + (threadIdx.x >> 6);
  const int lane = threadIdx.x & 63;
  const float CE = 0.125f * 1.44269504f;
  const float m1 = mlpart[(size_t)row * 2], l1 = mlpart[(size_t)row * 2 + 1];
  const float m2 = mlpart[65536ull * 2 + (size_t)row * 2], l2 = mlpart[65536ull * 2 + (size_t)row * 2 + 1];
  const float m = fmaxf(m1, m2);
  const float a1 = exp2f((m1 - m) * CE);
  const float a2 = exp2f((m2 - m) * CE);
  const float l = a1 * l1 + a2 * l2;
  const float inv = l > 0.0f ? 1.0f / l : 0.0f;
  const float o1 = opart[(size_t)row * 64 + lane];
  const float o2 = opart[65536ull * 64 + (size_t)row * 64 + lane];
  const float ov = (a1 * o1 + a2 * o2) * inv;
  const int bh = row >> 11, q = row & 2047;
  out[((size_t)((bh >> 4) * 2048 + q)) * 1024 + (bh & 15) * 64 + lane] = f2bf(ov);
}

extern "C" void kernel_launch(void* const* d_in, const int* in_sizes, int n_in,
                              void* d_out, int out_size, void* d_ws, size_t ws_size,
                              hipStream_t stream) {
  (void)in_sizes; (void)n_in; (void)out_size; (void)ws_size;
  const float* x = (const float*)d_in[0];
  const u8* mask = (const u8*)d_in[1];
  const float* Wq = (const float*)d_in[2];
  const float* Wk = (const float*)d_in[3];
  const float* Wv = (const float*)d_in[4];
  const float* Wo = (const float*)d_in[5];
  const float* bo = (const float*)d_in[6];
  const float* W1 = (const float*)d_in[7];
  const float* b1 = (const float*)d_in[8];
  const float* W2 = (const float*)d_in[9];
  const float* b2 = (const float*)d_in[10];
  const float* g1 = (const float*)d_in[11];
  const float* be1 = (const float*)d_in[12];
  const float* g2 = (const float*)d_in[13];
  const float* be2 = (const float*)d_in[14];
  float* outp = (float*)d_out;

  const int B = 2, S = 2048, D = 1024, FF = 4096;
  const int M = B * S;  // 4096
  char* w = (char*)d_ws;
  const size_t MB = 1024 * 1024;
  u16* wqkvT = (u16*)(w + 0 * MB);    // [3072,1024] bf16   [0,6)
  u16* woT = (u16*)(w + 6 * MB);      // [1024,1024]        [6,8)
  u16* w1T = (u16*)(w + 8 * MB);      // [4096,1024]        [8,16)
  u16* w2T = (u16*)(w + 16 * MB);     // [1024,4096]        [16,24)
  u16* xb  = (u16*)(w + 24 * MB);     // [4096,1024]        [24,32)
  u16* qkv = (u16*)(w + 32 * MB);     // [4096,3072]        [32,56)
  u16* vt  = (u16*)(w + 56 * MB);     // [B*H,64,S]         [56,64)
  float* x0f = (float*)(w + 64 * MB); // [4096,1024] f32    [64,80)  (written after combine)
  float* x1f = (float*)(w + 80 * MB); //                    [80,96)
  u16* x1b = (u16*)(w + 96 * MB);     // [4096,1024] bf16   [96,104)
  u8* msum = (u8*)(w + 64 * MB);      // 2 KB at 64, dead before x0f written
  // split-KV partials: live only between attn_k and attn_combine; overlap x0f/x1f/x1b
  float* opart = (float*)(w + 65 * MB);   // [2][65536][64] f32 = 33.6 MB  [65, 98.6)
  float* mlpart = (float*)(w + 99 * MB);  // [2][65536][2]  f32 = 1.05 MB [99, 100.1)
  u16* attn_o = xb;                   // xb dead after QKV gemm
  u16* ff1 = (u16*)(w + 32 * MB);     // [4096,4096] bf16, reuses qkv+vt [32,64)
  float* y0f = x0f;

  // weight prep (Wq/Wk/Wv transposed into one contiguous [3072,1024] block)
  transpose_f32_bf16<<<dim3(32, 32), 256, 0, stream>>>(Wq, wqkvT, 1024, 1024);
  transpose_f32_bf16<<<dim3(32, 32), 256, 0, stream>>>(Wk, wqkvT + 1024 * 1024, 1024, 1024);
  transpose_f32_bf16<<<dim3(32, 32), 256, 0, stream>>>(Wv, wqkvT + 2048 * 1024, 1024, 1024);
  transpose_f32_bf16<<<dim3(32, 32), 256, 0, stream>>>(Wo, woT, 1024, 1024);
  transpose_f32_bf16<<<dim3(128, 32), 256, 0, stream>>>(W1, w1T, 1024, 4096);
  transpose_f32_bf16<<<dim3(32, 128), 256, 0, stream>>>(W2, w2T, 4096, 1024);
  cvt_f32_bf16<<<dim3(M * D / 4 / 256), 256, 0, stream>>>(x, xb, M * D / 4);
  mask_summary<<<dim3(32, 32, 2), 256, 0, stream>>>(mask, msum);

  // fused QKV projection: [4096,1024] @ [3072,1024]^T -> [4096,3072]
  gemm_bt<0, 128><<<dim3(3 * D / 128, M / 128), 256, 0, stream>>>(xb, wqkvT, M, 3 * D, D, nullptr, nullptr, qkv, nullptr);
  // V -> V^T per batch (strided read from qkv cols 2048..3071)
  transpose_bf16_b<<<dim3(32, 64, 2), 256, 0, stream>>>(qkv, vt, 2048, 1024, 3072, 2048);

  // attention: 1024 blocks (split-KV), then combine
  attn_k<<<dim3(1024), 256, 0, stream>>>(qkv, vt, mask, msum, opart, mlpart);
  attn_combine<<<dim3(65536 / 4), 256, 0, stream>>>(opart, mlpart, attn_o);

  // Wo projection + bias + residual(x) -- BM=64
  gemm_bt<2, 64><<<dim3(D / 128, M / 64), 256, 0, stream>>>(attn_o, woT, M, D, D, bo, x, nullptr, x0f);
  layernorm_k<1><<<dim3(M), 256, 0, stream>>>(x0f, g1, be1, x1f, x1b);
  gemm_bt<1, 128><<<dim3(FF / 128, M / 128), 256, 0, stream>>>(x1b, w1T, M, FF, D, b1, nullptr, ff1, nullptr);
  gemm_bt<2, 64><<<dim3(D / 128, M / 64), 256, 0, stream>>>(ff1, w2T, M, D, FF, b2, x1f, nullptr, y0f);
  layernorm_k<0><<<dim3(M), 256, 0, stream>>>(y0f, g2, be2, outp, nullptr);
}

// Round 9
// 301.524 us; speedup vs baseline: 1.0507x; 1.0507x over previous
//
#include <hip/hip_runtime.h>
#include <math.h>

typedef unsigned short u16;
typedef unsigned char u8;
typedef unsigned int u32;
typedef __attribute__((ext_vector_type(4))) float f32x4;
typedef __attribute__((ext_vector_type(8))) short s16x8;
typedef __attribute__((ext_vector_type(4))) short s16x4;
typedef __attribute__((ext_vector_type(4))) u32 u32x4;
typedef __attribute__((ext_vector_type(2))) u32 u32x2;

__device__ __forceinline__ u16 f2bf(float f) {
  unsigned u = __builtin_bit_cast(unsigned, f);
  u += 0x7fffu + ((u >> 16) & 1u);
  return (u16)(u >> 16);
}

__device__ __forceinline__ u32 cvtpk_bf16(float lo, float hi) {
  u32 r;
  asm("v_cvt_pk_bf16_f32 %0, %1, %2" : "=v"(r) : "v"(lo), "v"(hi));
  return r;
}

__device__ __forceinline__ float max3f(float a, float b, float c) {
  return fmaxf(fmaxf(a, b), c);  // fuses to v_max3_f32
}

#define GLDS16(g, l) __builtin_amdgcn_global_load_lds( \
    (const __attribute__((address_space(1))) void*)(g), \
    (__attribute__((address_space(3))) void*)(l), 16, 0, 0)

// ---------------- GEMM: C[M,N] = A[M,K](bf16) @ BT[N,K](bf16)^T ----------------
// 2-phase double-buffered staging; XCD-aware block swizzle (nwg%8==0 for all
// launched grids -> bijective): XCD j gets a contiguous flat-id chunk -> shared
// A-row panels stay L2-resident per XCD.
template <int EPI, int BM>
__global__ __launch_bounds__(256, 2) void gemm_bt(
    const u16* __restrict__ A, const u16* __restrict__ BT, int M, int N, int K,
    const float* __restrict__ bias, const float* __restrict__ resid,
    u16* __restrict__ outB, float* __restrict__ outF) {
  constexpr int MT = BM / 32;  // acc row-tiles per wave
  __shared__ __align__(16) u16 lA[2][BM * 32];
  __shared__ __align__(16) u16 lB[2][128 * 32];
  const int tid = threadIdx.x;
  const int wave = __builtin_amdgcn_readfirstlane(tid >> 6);
  const int lane = tid & 63;
  const int l15 = lane & 15, l4 = lane >> 4;
  const int wr = wave >> 1, wc = wave & 1;
  const int nwg = gridDim.x * gridDim.y;
  int wg = blockIdx.y * gridDim.x + blockIdx.x;
  wg = (wg & 7) * (nwg >> 3) + (wg >> 3);  // XCD swizzle (bijective: nwg%8==0)
  const int bx = wg % gridDim.x, by = wg / gridDim.x;
  const int row0 = by * BM, col0 = bx * 128;

  f32x4 acc[MT][4] = {};

  auto stage = [&](int bi, int k0) {
#pragma unroll
    for (int c = 0; c < BM / 64; ++c) {
      const int chunk = c * 4 + wave;          // 1KB chunks of A
      const int idx = chunk * 64 + lane;       // 16B-unit index
      const int r = idx >> 2, cb = (idx & 3) * 8;
      GLDS16(A + (size_t)(row0 + r) * K + k0 + cb, &lA[bi][chunk * 512]);
    }
#pragma unroll
    for (int c = 0; c < 2; ++c) {
      const int chunk = c * 4 + wave;
      const int idx = chunk * 64 + lane;
      const int r = idx >> 2, cb = (idx & 3) * 8;
      GLDS16(BT + (size_t)(col0 + r) * K + k0 + cb, &lB[bi][chunk * 512]);
    }
  };

  stage(0, 0);
  __syncthreads();
  int buf = 0;

  for (int k0 = 0; k0 < K; k0 += 32) {
    if (k0 + 32 < K) stage(buf ^ 1, k0 + 32);  // async prefetch, drained at loop-end barrier
    s16x8 af[MT], bfr[4];
#pragma unroll
    for (int m = 0; m < MT; ++m)
      af[m] = *(const s16x8*)&lA[buf][(wr * (BM / 2) + m * 16 + l15) * 32 + l4 * 8];
#pragma unroll
    for (int n = 0; n < 4; ++n)
      bfr[n] = *(const s16x8*)&lB[buf][(wc * 64 + n * 16 + l15) * 32 + l4 * 8];
#pragma unroll
    for (int m = 0; m < MT; ++m)
#pragma unroll
      for (int n = 0; n < 4; ++n)
        acc[m][n] = __builtin_amdgcn_mfma_f32_16x16x32_bf16(af[m], bfr[n], acc[m][n], 0, 0, 0);
    __syncthreads();
    buf ^= 1;
  }

#pragma unroll
  for (int m = 0; m < MT; ++m) {
    const int rowb = row0 + wr * (BM / 2) + m * 16 + l4 * 4;
#pragma unroll
    for (int n = 0; n < 4; ++n) {
      const int col = col0 + wc * 64 + n * 16 + l15;
#pragma unroll
      for (int j = 0; j < 4; ++j) {
        const int r = rowb + j;
        float v = acc[m][n][j];
        if (EPI == 0) {
          outB[(size_t)r * N + col] = f2bf(v);
        } else if (EPI == 1) {
          v += bias[col];
          outB[(size_t)r * N + col] = f2bf(v > 0.0f ? v : 0.0f);
        } else {
          v += bias[col] + resid[(size_t)r * N + col];
          outF[(size_t)r * N + col] = v;
        }
      }
    }
  }
}

// ---------------- weight transpose f32 -> bf16 ----------------
__global__ __launch_bounds__(256) void transpose_f32_bf16(
    const float* __restrict__ in, u16* __restrict__ out, int R, int C) {
  __shared__ float t[32][33];
  const int c0 = blockIdx.x * 32, r0 = blockIdx.y * 32;
  const int tx = threadIdx.x & 31, ty = threadIdx.x >> 5;
#pragma unroll
  for (int i = 0; i < 4; ++i)
    t[ty + i * 8][tx] = in[(size_t)(r0 + ty + i * 8) * C + c0 + tx];
  __syncthreads();
#pragma unroll
  for (int i = 0; i < 4; ++i)
    out[(size_t)(c0 + ty + i * 8) * R + r0 + tx] = f2bf(t[tx][ty + i * 8]);
}

// ---------------- batched bf16 transpose (strided input, col-offset) ----------------
__global__ __launch_bounds__(256) void transpose_bf16_b(
    const u16* __restrict__ in, u16* __restrict__ out, int R, int C, int rstr, int coff) {
  __shared__ u16 t[32][34];
  const int b = blockIdx.z;
  const u16* pi = in + (size_t)b * R * rstr + coff;
  u16* po = out + (size_t)b * R * C;
  const int c0 = blockIdx.x * 32, r0 = blockIdx.y * 32;
  const int tx = threadIdx.x & 31, ty = threadIdx.x >> 5;
#pragma unroll
  for (int i = 0; i < 4; ++i)
    t[ty + i * 8][tx] = pi[(size_t)(r0 + ty + i * 8) * rstr + c0 + tx];
  __syncthreads();
#pragma unroll
  for (int i = 0; i < 4; ++i)
    po[(size_t)(c0 + ty + i * 8) * R + r0 + tx] = t[tx][ty + i * 8];
}

// ---------------- f32 -> bf16 elementwise ----------------
__global__ __launch_bounds__(256) void cvt_f32_bf16(
    const float* __restrict__ in, u16* __restrict__ out, int n4) {
  const int i = blockIdx.x * 256 + threadIdx.x;
  if (i >= n4) return;
  f32x4 v = *(const f32x4*)&in[(size_t)i * 4];
  s16x4 o;
#pragma unroll
  for (int j = 0; j < 4; ++j) o[j] = (short)f2bf(v[j]);
  *(s16x4*)&out[(size_t)i * 4] = o;
}

// ---------------- LayerNorm over D=1024 ----------------
template <int WB>
__global__ __launch_bounds__(256) void layernorm_k(
    const float* __restrict__ in, const float* __restrict__ gm, const float* __restrict__ bt,
    float* __restrict__ outF, u16* __restrict__ outB) {
  const int row = blockIdx.x;
  const int t = threadIdx.x;
  const float* xr = in + (size_t)row * 1024;
  f32x4 v = *(const f32x4*)&xr[t * 4];
  float s = v[0] + v[1] + v[2] + v[3];
  float s2 = v[0] * v[0] + v[1] * v[1] + v[2] * v[2] + v[3] * v[3];
#pragma unroll
  for (int o = 32; o; o >>= 1) {
    s += __shfl_down(s, o);
    s2 += __shfl_down(s2, o);
  }
  __shared__ float red[8];
  const int lane = t & 63, wv = t >> 6;
  if (lane == 0) { red[wv] = s; red[4 + wv] = s2; }
  __syncthreads();
  s = red[0] + red[1] + red[2] + red[3];
  s2 = red[4] + red[5] + red[6] + red[7];
  const float mu = s * (1.0f / 1024.0f);
  const float var = fmaxf(s2 * (1.0f / 1024.0f) - mu * mu, 0.0f);
  const float rs = rsqrtf(var + 1e-5f);
  f32x4 g4 = *(const f32x4*)&gm[t * 4];
  f32x4 b4 = *(const f32x4*)&bt[t * 4];
  f32x4 ov;
#pragma unroll
  for (int j = 0; j < 4; ++j) ov[j] = (v[j] - mu) * rs * g4[j] + b4[j];
  *(f32x4*)&outF[(size_t)row * 1024 + t * 4] = ov;
  if (WB) {
    s16x4 ob;
#pragma unroll
    for (int j = 0; j < 4; ++j) ob[j] = (short)f2bf(ov[j]);
    *(s16x4*)&outB[(size_t)row * 1024 + t * 4] = ob;
  }
}

// ---------------- mask tile summary: any() over 64x64 tiles ----------------
__global__ __launch_bounds__(256) void mask_summary(
    const u8* __restrict__ mask, u8* __restrict__ msum) {
  const int kt = blockIdx.x, qt = blockIdx.y, b = blockIdx.z;
  const int tid = threadIdx.x;
  __shared__ int any_flag;
  if (tid == 0) any_flag = 0;
  __syncthreads();
  const u8* base = mask + ((size_t)(b * 2048 + qt * 64 + (tid >> 2))) * 2048 + kt * 64 + (tid & 3) * 16;
  const u32x4 v = *(const u32x4*)base;
  if (v[0] | v[1] | v[2] | v[3]) any_flag = 1;
  __syncthreads();
  if (tid == 0) msum[((size_t)b * 32 + qt) * 32 + kt] = (u8)any_flag;
}

// ---------------- flash attention: R5 body (52 VGPR) + split-KV grid ----------------
// Grid 2048: (8 xcd) x (4 bh/xcd) x (2 kv-halves) x (32 qt); 4 waves x 16 q-rows
// (R5-proven 1-group body). Each block does 16 kv-iters over its half, writes
// UNNORMALIZED partial O (f32) + (m,l) per q-row; attn_combine merges the halves.
__global__ __launch_bounds__(256) void attn_k(
    const u16* __restrict__ QKV, const u16* __restrict__ VT,
    const u8* __restrict__ mask, const u8* __restrict__ msum,
    float* __restrict__ opart, float* __restrict__ mlpart) {
  const int S = 2048, QSTR = 3072;
  const int wgid = blockIdx.x;                   // 0..2047
  const int xcd = wgid & 7, slot = wgid >> 3;    // slot 0..255
  const int bh = xcd * 4 + (slot >> 6);          // 4 bh per XCD (KV L2-resident)
  const int rem = slot & 63;
  const int kvh = rem >> 5;                      // kv half
  const int qt = rem & 31;                       // 32 q-tiles of 64 rows
  const int b = bh >> 4, h = bh & 15;
  const int wave = threadIdx.x >> 6, lane = threadIdx.x & 63;
  const int l15 = lane & 15, l4 = lane >> 4;
  const int q0 = qt * 64 + wave * 16;
  const int kv0 = kvh * 1024, kvend = kv0 + 1024;
  const float CE = 0.125f * 1.44269504f;  // 1/sqrt(64) * log2(e)

  __shared__ __align__(16) u16 lK[2][4096];  // [buf][64 rows x 64 cols], XOR-swizzled
  __shared__ __align__(16) u16 lV[2][4096];

  const size_t qoff = (size_t)(b * S + q0 + l15) * QSTR + h * 64;
  const s16x8 qa0 = *(const s16x8*)&QKV[qoff + l4 * 8];
  const s16x8 qa1 = *(const s16x8*)&QKV[qoff + 32 + l4 * 8];

  f32x4 o[4] = {};
  float mr = -1e30f, lr = 0.0f;
  const u8* mb = mask + (size_t)b * S * S;
  const u8* msb = msum + (size_t)(b * 32 + qt) * 32;
  const u16* vbase = VT + (size_t)bh * 64 * S;
  const int bS = b * S;

  auto stage = [&](int bi, int kvv) {
#pragma unroll
    for (int c = 0; c < 2; ++c) {
      const int byt = ((c * 4 + wave) * 64 + lane) * 16;  // 0..8191
      const int row = byt >> 7;
      const int cb = (byt & 127) ^ ((row & 7) << 4);
      GLDS16(QKV + (size_t)(bS + kvv + row) * QSTR + 1024 + h * 64 + (cb >> 1),
             &lK[bi][(c * 4 + wave) * 512]);
      GLDS16(vbase + (size_t)row * S + kvv + (cb >> 1),
             &lV[bi][(c * 4 + wave) * 512]);
    }
  };

  auto body = [&](int bi, int kvv) {
    if (kvv + 64 < kvend) stage(bi ^ 1, kvv + 64);
    const char* kbuf = (const char*)&lK[bi][0];
    const char* vbuf = (const char*)&lV[bi][0];

    // ---- QK^T (swapped): sc[t] = mfma(K, Q) ----
    f32x4 sc[4];
    __builtin_amdgcn_s_setprio(1);
#pragma unroll
    for (int t = 0; t < 4; ++t) {
      const int row = t * 16 + l15;
      const int sw = (row & 7) << 4;
      const s16x8 kf0 = *(const s16x8*)(kbuf + row * 128 + ((l4 * 16) ^ sw));
      const s16x8 kf1 = *(const s16x8*)(kbuf + row * 128 + ((64 + l4 * 16) ^ sw));
      f32x4 z = {};
      z = __builtin_amdgcn_mfma_f32_16x16x32_bf16(kf0, qa0, z, 0, 0, 0);
      z = __builtin_amdgcn_mfma_f32_16x16x32_bf16(kf1, qa1, z, 0, 0, 0);
      sc[t] = z;
    }
    __builtin_amdgcn_s_setprio(0);
    // ---- mask (rare slow path via tile summary) ----
    if (msb[kvv >> 6]) {
#pragma unroll
      for (int t = 0; t < 4; ++t) {
        const uchar4 m4 = *(const uchar4*)&mb[(size_t)(q0 + l15) * S + kvv + t * 16 + l4 * 4];
        if (m4.x) sc[t][0] = -1e30f;
        if (m4.y) sc[t][1] = -1e30f;
        if (m4.z) sc[t][2] = -1e30f;
        if (m4.w) sc[t][3] = -1e30f;
      }
    }
    // ---- INF/NaN scrub (insurance) ----
#pragma unroll
    for (int t = 0; t < 4; ++t)
#pragma unroll
      for (int j = 0; j < 4; ++j) sc[t][j] = fminf(sc[t][j], 1e30f);
    // ---- online softmax with defer-max; max via v_max3 tree ----
    float pm = max3f(sc[0][0], sc[0][1], sc[0][2]);
    pm = max3f(pm, sc[0][3], sc[1][0]);
    pm = max3f(pm, sc[1][1], sc[1][2]);
    pm = max3f(pm, sc[1][3], sc[2][0]);
    pm = max3f(pm, sc[2][1], sc[2][2]);
    pm = max3f(pm, sc[2][3], sc[3][0]);
    pm = max3f(pm, sc[3][1], sc[3][2]);
    pm = fmaxf(pm, sc[3][3]);
    pm = fmaxf(pm, __shfl_xor(pm, 16));
    pm = fmaxf(pm, __shfl_xor(pm, 32));
    if (!__all(pm <= mr + 44.0f)) {  // 44 raw = 8 exp2-units
      const float mn = fmaxf(mr, pm);
      const float al = exp2f((mr - mn) * CE);
      mr = mn;
      lr *= al;
#pragma unroll
      for (int n = 0; n < 4; ++n)
#pragma unroll
        for (int j = 0; j < 4; ++j) o[n][j] *= al;
    }
    const float mrc = mr * CE;
    float rsum = 0.0f;
#pragma unroll
    for (int t = 0; t < 4; ++t)
#pragma unroll
      for (int j = 0; j < 4; ++j) {
        const float p = exp2f(fmaf(sc[t][j], CE, -mrc));
        sc[t][j] = p;
        rsum += p;
      }
    rsum += __shfl_xor(rsum, 16);
    rsum += __shfl_xor(rsum, 32);
    lr += rsum;
    // ---- pack P into 16x16x16 B-frags (zero cross-lane) ----
    s16x4 pb[4];
#pragma unroll
    for (int t = 0; t < 4; ++t) {
      const u32 lo = cvtpk_bf16(sc[t][0], sc[t][1]);
      const u32 hi = cvtpk_bf16(sc[t][2], sc[t][3]);
      pb[t] = __builtin_bit_cast(s16x4, u32x2{lo, hi});
    }
    // ---- PV: o[n] += mfma_16x16x16(V frag, P frag) ----
    __builtin_amdgcn_s_setprio(1);
#pragma unroll
    for (int n = 0; n < 4; ++n) {
      const int row = n * 16 + l15;
      const int sw = (row & 7) << 4;
#pragma unroll
      for (int t = 0; t < 4; ++t) {
        const s16x4 va = *(const s16x4*)(vbuf + row * 128 + ((t * 32 + l4 * 8) ^ sw));
        o[n] = __builtin_amdgcn_mfma_f32_16x16x16bf16_1k(va, pb[t], o[n], 0, 0, 0);
      }
    }
    __builtin_amdgcn_s_setprio(0);
    __syncthreads();  // drains prefetch vmcnt + protects buf swap
  };

  stage(0, kv0);
  __syncthreads();
  for (int kv = kv0; kv < kvend; kv += 128) {  // 8 pairs; buf compile-time per body
    body(0, kv);
    body(1, kv + 64);
  }
  // ---- epilogue: store UNNORMALIZED partial O (f32) + (m,l) per q-row ----
  const int prow = q0 + l15;  // q row within [0,2048)
  float* obase = opart + ((size_t)kvh * 65536 + (size_t)bh * 2048 + prow) * 64;
#pragma unroll
  for (int n = 0; n < 4; ++n)
    *(f32x4*)&obase[n * 16 + l4 * 4] = o[n];
  if (l4 == 0) {
    const size_t mli = ((size_t)kvh * 65536 + (size_t)bh * 2048 + prow) * 2;
    mlpart[mli] = mr;
    mlpart[mli + 1] = lr;
  }
}

// ---------------- split-KV combine: merge 2 partials, write bf16 attn out ----------------
// row r in [0,65536): bh = r>>11, q = r&2047. Block = 4 rows x 64 lanes (D=64).
__global__ __launch_bounds__(256) void attn_combine(
    const float* __restrict__ opart, const float* __restrict__ mlpart,
    u16* __restrict__ out) {
  const int row = blockIdx.x * 4 + (threadIdx.x >> 6);
  const int lane = threadIdx.x & 63;
  const float CE = 0.125f * 1.44269504f;
  const float m1 = mlpart[(size_t)row * 2], l1 = mlpart[(size_t)row * 2 + 1];
  const float m2 = mlpart[65536ull * 2 + (size_t)row * 2], l2 = mlpart[65536ull * 2 + (size_t)row * 2 + 1];
  const float m = fmaxf(m1, m2);
  const float a1 = exp2f((m1 - m) * CE);
  const float a2 = exp2f((m2 - m) * CE);
  const float l = a1 * l1 + a2 * l2;
  const float inv = l > 0.0f ? 1.0f / l : 0.0f;
  const float o1 = opart[(size_t)row * 64 + lane];
  const float o2 = opart[65536ull * 64 + (size_t)row * 64 + lane];
  const float ov = (a1 * o1 + a2 * o2) * inv;
  const int bh = row >> 11, q = row & 2047;
  out[((size_t)((bh >> 4) * 2048 + q)) * 1024 + (bh & 15) * 64 + lane] = f2bf(ov);
}

extern "C" void kernel_launch(void* const* d_in, const int* in_sizes, int n_in,
                              void* d_out, int out_size, void* d_ws, size_t ws_size,
                              hipStream_t stream) {
  (void)in_sizes; (void)n_in; (void)out_size; (void)ws_size;
  const float* x = (const float*)d_in[0];
  const u8* mask = (const u8*)d_in[1];
  const float* Wq = (const float*)d_in[2];
  const float* Wk = (const float*)d_in[3];
  const float* Wv = (const float*)d_in[4];
  const float* Wo = (const float*)d_in[5];
  const float* bo = (const float*)d_in[6];
  const float* W1 = (const float*)d_in[7];
  const float* b1 = (const float*)d_in[8];
  const float* W2 = (const float*)d_in[9];
  const float* b2 = (const float*)d_in[10];
  const float* g1 = (const float*)d_in[11];
  const float* be1 = (const float*)d_in[12];
  const float* g2 = (const float*)d_in[13];
  const float* be2 = (const float*)d_in[14];
  float* outp = (float*)d_out;

  const int B = 2, S = 2048, D = 1024, FF = 4096;
  const int M = B * S;  // 4096
  char* w = (char*)d_ws;
  const size_t MB = 1024 * 1024;
  u16* wqkvT = (u16*)(w + 0 * MB);    // [3072,1024] bf16   [0,6)
  u16* woT = (u16*)(w + 6 * MB);      // [1024,1024]        [6,8)
  u16* w1T = (u16*)(w + 8 * MB);      // [4096,1024]        [8,16)
  u16* w2T = (u16*)(w + 16 * MB);     // [1024,4096]        [16,24)
  u16* xb  = (u16*)(w + 24 * MB);     // [4096,1024]        [24,32)
  u16* qkv = (u16*)(w + 32 * MB);     // [4096,3072]        [32,56)
  u16* vt  = (u16*)(w + 56 * MB);     // [B*H,64,S]         [56,64)
  float* x0f = (float*)(w + 64 * MB); // [4096,1024] f32    [64,80)  (written after combine)
  float* x1f = (float*)(w + 80 * MB); //                    [80,96)
  u16* x1b = (u16*)(w + 96 * MB);     // [4096,1024] bf16   [96,104)
  u8* msum = (u8*)(w + 64 * MB);      // 2 KB at 64, dead before x0f written
  // split-KV partials: live only between attn_k and attn_combine; overlap x0f/x1f/x1b
  float* opart = (float*)(w + 65 * MB);   // [2][65536][64] f32 = 33.6 MB  [65, 98.6)
  float* mlpart = (float*)(w + 99 * MB);  // [2][65536][2]  f32 = 1.05 MB [99, 100.1)
  u16* attn_o = xb;                   // xb dead after QKV gemm
  u16* ff1 = (u16*)(w + 32 * MB);     // [4096,4096] bf16, reuses qkv+vt [32,64)
  float* y0f = x0f;

  // weight prep (Wq/Wk/Wv transposed into one contiguous [3072,1024] block)
  transpose_f32_bf16<<<dim3(32, 32), 256, 0, stream>>>(Wq, wqkvT, 1024, 1024);
  transpose_f32_bf16<<<dim3(32, 32), 256, 0, stream>>>(Wk, wqkvT + 1024 * 1024, 1024, 1024);
  transpose_f32_bf16<<<dim3(32, 32), 256, 0, stream>>>(Wv, wqkvT + 2048 * 1024, 1024, 1024);
  transpose_f32_bf16<<<dim3(32, 32), 256, 0, stream>>>(Wo, woT, 1024, 1024);
  transpose_f32_bf16<<<dim3(128, 32), 256, 0, stream>>>(W1, w1T, 1024, 4096);
  transpose_f32_bf16<<<dim3(32, 128), 256, 0, stream>>>(W2, w2T, 4096, 1024);
  cvt_f32_bf16<<<dim3(M * D / 4 / 256), 256, 0, stream>>>(x, xb, M * D / 4);
  mask_summary<<<dim3(32, 32, 2), 256, 0, stream>>>(mask, msum);

  // fused QKV projection: [4096,1024] @ [3072,1024]^T -> [4096,3072]
  gemm_bt<0, 128><<<dim3(3 * D / 128, M / 128), 256, 0, stream>>>(xb, wqkvT, M, 3 * D, D, nullptr, nullptr, qkv, nullptr);
  // V -> V^T per batch (strided read from qkv cols 2048..3071)
  transpose_bf16_b<<<dim3(32, 64, 2), 256, 0, stream>>>(qkv, vt, 2048, 1024, 3072, 2048);

  // attention: 2048 blocks (split-KV, R5 body), then combine
  attn_k<<<dim3(2048), 256, 0, stream>>>(qkv, vt, mask, msum, opart, mlpart);
  attn_combine<<<dim3(65536 / 4), 256, 0, stream>>>(opart, mlpart, attn_o);

  // Wo projection + bias + residual(x) -- BM=64
  gemm_bt<2, 64><<<dim3(D / 128, M / 64), 256, 0, stream>>>(attn_o, woT, M, D, D, bo, x, nullptr, x0f);
  layernorm_k<1><<<dim3(M), 256, 0, stream>>>(x0f, g1, be1, x1f, x1b);
  gemm_bt<1, 128><<<dim3(FF / 128, M / 128), 256, 0, stream>>>(x1b, w1T, M, FF, D, b1, nullptr, ff1, nullptr);
  gemm_bt<2, 64><<<dim3(D / 128, M / 64), 256, 0, stream>>>(ff1, w2T, M, D, FF, b2, x1f, nullptr, y0f);
  layernorm_k<0><<<dim3(M), 256, 0, stream>>>(y0f, g2, be2, outp, nullptr);
}

// Round 10
// 299.481 us; speedup vs baseline: 1.0578x; 1.0068x over previous
//
#include <hip/hip_runtime.h>
#include <math.h>

typedef unsigned short u16;
typedef unsigned char u8;
typedef unsigned int u32;
typedef __attribute__((ext_vector_type(4))) float f32x4;
typedef __attribute__((ext_vector_type(8))) short s16x8;
typedef __attribute__((ext_vector_type(4))) short s16x4;
typedef __attribute__((ext_vector_type(4))) u32 u32x4;
typedef __attribute__((ext_vector_type(2))) u32 u32x2;

__device__ __forceinline__ u16 f2bf(float f) {
  unsigned u = __builtin_bit_cast(unsigned, f);
  u += 0x7fffu + ((u >> 16) & 1u);
  return (u16)(u >> 16);
}

__device__ __forceinline__ u32 cvtpk_bf16(float lo, float hi) {
  u32 r;
  asm("v_cvt_pk_bf16_f32 %0, %1, %2" : "=v"(r) : "v"(lo), "v"(hi));
  return r;
}

__device__ __forceinline__ float max3f(float a, float b, float c) {
  return fmaxf(fmaxf(a, b), c);  // fuses to v_max3_f32
}

#define GLDS16(g, l) __builtin_amdgcn_global_load_lds( \
    (const __attribute__((address_space(1))) void*)(g), \
    (__attribute__((address_space(3))) void*)(l), 16, 0, 0)

// ---------------- GEMM: C[M,N] = A[M,K](bf16) @ BT[N,K](bf16)^T ----------------
// 2-phase double-buffered staging; XCD-aware block swizzle (all grids %8==0).
template <int EPI, int BM>
__global__ __launch_bounds__(256, 2) void gemm_bt(
    const u16* __restrict__ A, const u16* __restrict__ BT, int M, int N, int K,
    const float* __restrict__ bias, const float* __restrict__ resid,
    u16* __restrict__ outB, float* __restrict__ outF) {
  constexpr int MT = BM / 32;  // acc row-tiles per wave
  __shared__ __align__(16) u16 lA[2][BM * 32];
  __shared__ __align__(16) u16 lB[2][128 * 32];
  const int tid = threadIdx.x;
  const int wave = __builtin_amdgcn_readfirstlane(tid >> 6);
  const int lane = tid & 63;
  const int l15 = lane & 15, l4 = lane >> 4;
  const int wr = wave >> 1, wc = wave & 1;
  const int nwg = gridDim.x * gridDim.y;
  int wg = blockIdx.y * gridDim.x + blockIdx.x;
  wg = (wg & 7) * (nwg >> 3) + (wg >> 3);  // XCD swizzle (bijective: nwg%8==0)
  const int bx = wg % gridDim.x, by = wg / gridDim.x;
  const int row0 = by * BM, col0 = bx * 128;

  f32x4 acc[MT][4] = {};

  auto stage = [&](int bi, int k0) {
#pragma unroll
    for (int c = 0; c < BM / 64; ++c) {
      const int chunk = c * 4 + wave;          // 1KB chunks of A
      const int idx = chunk * 64 + lane;       // 16B-unit index
      const int r = idx >> 2, cb = (idx & 3) * 8;
      GLDS16(A + (size_t)(row0 + r) * K + k0 + cb, &lA[bi][chunk * 512]);
    }
#pragma unroll
    for (int c = 0; c < 2; ++c) {
      const int chunk = c * 4 + wave;
      const int idx = chunk * 64 + lane;
      const int r = idx >> 2, cb = (idx & 3) * 8;
      GLDS16(BT + (size_t)(col0 + r) * K + k0 + cb, &lB[bi][chunk * 512]);
    }
  };

  stage(0, 0);
  __syncthreads();
  int buf = 0;

  for (int k0 = 0; k0 < K; k0 += 32) {
    if (k0 + 32 < K) stage(buf ^ 1, k0 + 32);  // async prefetch, drained at loop-end barrier
    s16x8 af[MT], bfr[4];
#pragma unroll
    for (int m = 0; m < MT; ++m)
      af[m] = *(const s16x8*)&lA[buf][(wr * (BM / 2) + m * 16 + l15) * 32 + l4 * 8];
#pragma unroll
    for (int n = 0; n < 4; ++n)
      bfr[n] = *(const s16x8*)&lB[buf][(wc * 64 + n * 16 + l15) * 32 + l4 * 8];
#pragma unroll
    for (int m = 0; m < MT; ++m)
#pragma unroll
      for (int n = 0; n < 4; ++n)
        acc[m][n] = __builtin_amdgcn_mfma_f32_16x16x32_bf16(af[m], bfr[n], acc[m][n], 0, 0, 0);
    __syncthreads();
    buf ^= 1;
  }

#pragma unroll
  for (int m = 0; m < MT; ++m) {
    const int rowb = row0 + wr * (BM / 2) + m * 16 + l4 * 4;
#pragma unroll
    for (int n = 0; n < 4; ++n) {
      const int col = col0 + wc * 64 + n * 16 + l15;
#pragma unroll
      for (int j = 0; j < 4; ++j) {
        const int r = rowb + j;
        float v = acc[m][n][j];
        if (EPI == 0) {
          outB[(size_t)r * N + col] = f2bf(v);
        } else if (EPI == 1) {
          v += bias[col];
          outB[(size_t)r * N + col] = f2bf(v > 0.0f ? v : 0.0f);
        } else {
          v += bias[col] + resid[(size_t)r * N + col];
          outF[(size_t)r * N + col] = v;
        }
      }
    }
  }
}

// ---------------- weight transpose f32 -> bf16 ----------------
__global__ __launch_bounds__(256) void transpose_f32_bf16(
    const float* __restrict__ in, u16* __restrict__ out, int R, int C) {
  __shared__ float t[32][33];
  const int c0 = blockIdx.x * 32, r0 = blockIdx.y * 32;
  const int tx = threadIdx.x & 31, ty = threadIdx.x >> 5;
#pragma unroll
  for (int i = 0; i < 4; ++i)
    t[ty + i * 8][tx] = in[(size_t)(r0 + ty + i * 8) * C + c0 + tx];
  __syncthreads();
#pragma unroll
  for (int i = 0; i < 4; ++i)
    out[(size_t)(c0 + ty + i * 8) * R + r0 + tx] = f2bf(t[tx][ty + i * 8]);
}

// ---------------- batched bf16 transpose (strided input, col-offset) ----------------
__global__ __launch_bounds__(256) void transpose_bf16_b(
    const u16* __restrict__ in, u16* __restrict__ out, int R, int C, int rstr, int coff) {
  __shared__ u16 t[32][34];
  const int b = blockIdx.z;
  const u16* pi = in + (size_t)b * R * rstr + coff;
  u16* po = out + (size_t)b * R * C;
  const int c0 = blockIdx.x * 32, r0 = blockIdx.y * 32;
  const int tx = threadIdx.x & 31, ty = threadIdx.x >> 5;
#pragma unroll
  for (int i = 0; i < 4; ++i)
    t[ty + i * 8][tx] = pi[(size_t)(r0 + ty + i * 8) * rstr + c0 + tx];
  __syncthreads();
#pragma unroll
  for (int i = 0; i < 4; ++i)
    po[(size_t)(c0 + ty + i * 8) * R + r0 + tx] = t[tx][ty + i * 8];
}

// ---------------- f32 -> bf16 elementwise ----------------
__global__ __launch_bounds__(256) void cvt_f32_bf16(
    const float* __restrict__ in, u16* __restrict__ out, int n4) {
  const int i = blockIdx.x * 256 + threadIdx.x;
  if (i >= n4) return;
  f32x4 v = *(const f32x4*)&in[(size_t)i * 4];
  s16x4 o;
#pragma unroll
  for (int j = 0; j < 4; ++j) o[j] = (short)f2bf(v[j]);
  *(s16x4*)&out[(size_t)i * 4] = o;
}

// ---------------- LayerNorm over D=1024 ----------------
template <int WB>
__global__ __launch_bounds__(256) void layernorm_k(
    const float* __restrict__ in, const float* __restrict__ gm, const float* __restrict__ bt,
    float* __restrict__ outF, u16* __restrict__ outB) {
  const int row = blockIdx.x;
  const int t = threadIdx.x;
  const float* xr = in + (size_t)row * 1024;
  f32x4 v = *(const f32x4*)&xr[t * 4];
  float s = v[0] + v[1] + v[2] + v[3];
  float s2 = v[0] * v[0] + v[1] * v[1] + v[2] * v[2] + v[3] * v[3];
#pragma unroll
  for (int o = 32; o; o >>= 1) {
    s += __shfl_down(s, o);
    s2 += __shfl_down(s2, o);
  }
  __shared__ float red[8];
  const int lane = t & 63, wv = t >> 6;
  if (lane == 0) { red[wv] = s; red[4 + wv] = s2; }
  __syncthreads();
  s = red[0] + red[1] + red[2] + red[3];
  s2 = red[4] + red[5] + red[6] + red[7];
  const float mu = s * (1.0f / 1024.0f);
  const float var = fmaxf(s2 * (1.0f / 1024.0f) - mu * mu, 0.0f);
  const float rs = rsqrtf(var + 1e-5f);
  f32x4 g4 = *(const f32x4*)&gm[t * 4];
  f32x4 b4 = *(const f32x4*)&bt[t * 4];
  f32x4 ov;
#pragma unroll
  for (int j = 0; j < 4; ++j) ov[j] = (v[j] - mu) * rs * g4[j] + b4[j];
  *(f32x4*)&outF[(size_t)row * 1024 + t * 4] = ov;
  if (WB) {
    s16x4 ob;
#pragma unroll
    for (int j = 0; j < 4; ++j) ob[j] = (short)f2bf(ov[j]);
    *(s16x4*)&outB[(size_t)row * 1024 + t * 4] = ob;
  }
}

// ---------------- mask tile summary: any() over 64x64 tiles ----------------
__global__ __launch_bounds__(256) void mask_summary(
    const u8* __restrict__ mask, u8* __restrict__ msum) {
  const int kt = blockIdx.x, qt = blockIdx.y, b = blockIdx.z;
  const int tid = threadIdx.x;
  __shared__ int any_flag;
  if (tid == 0) any_flag = 0;
  __syncthreads();
  const u8* base = mask + ((size_t)(b * 2048 + qt * 64 + (tid >> 2))) * 2048 + kt * 64 + (tid & 3) * 16;
  const u32x4 v = *(const u32x4*)base;
  if (v[0] | v[1] | v[2] | v[3]) any_flag = 1;
  __syncthreads();
  if (tid == 0) msum[((size_t)b * 32 + qt) * 32 + kt] = (u8)any_flag;
}

// ---------------- flash attention (R5 structure + MFMA row-sum) ----------------
// 1024 blocks (xcd-mapped), 4 waves x 16 q-rows, full kv sweep, direct bf16 out.
// Swapped QK^T: lane (l4,l15) holds S^T[kv=16t+4*l4+j][q=l15].
// PV via mfma_16x16x16 (acc layout == B-frag layout -> zero-shuffle P).
// Row-sum l via MFMA with all-ones A: lacc[.][q] = sum_k P[k][q] -- replaces
// 16 v_add + 2 shfl per iter with 4 MFMAs on the under-utilized matrix pipe.
__global__ __launch_bounds__(256) void attn_k(
    const u16* __restrict__ QKV, const u16* __restrict__ VT,
    const u8* __restrict__ mask, const u8* __restrict__ msum, u16* __restrict__ out) {
  const int S = 2048, QSTR = 3072, Dm = 1024;
  const int wgid = blockIdx.x;  // 0..1023
  const int xcd = wgid & 7, slot = wgid >> 3;
  const int bh = xcd * 4 + (slot >> 5);  // 4 bh per XCD -> 2MB KV L2-resident
  const int qt = slot & 31;
  const int b = bh >> 4, h = bh & 15;
  const int wave = threadIdx.x >> 6, lane = threadIdx.x & 63;
  const int l15 = lane & 15, l4 = lane >> 4;
  const int q0 = qt * 64 + wave * 16;
  const float CE = 0.125f * 1.44269504f;  // 1/sqrt(64) * log2(e)
  const s16x4 ones = {(short)0x3F80, (short)0x3F80, (short)0x3F80, (short)0x3F80};  // bf16 1.0

  __shared__ __align__(16) u16 lK[2][4096];  // [buf][64 rows x 64 cols], XOR-swizzled
  __shared__ __align__(16) u16 lV[2][4096];

  const size_t qoff = (size_t)(b * S + q0 + l15) * QSTR + h * 64;
  const s16x8 qa0 = *(const s16x8*)&QKV[qoff + l4 * 8];
  const s16x8 qa1 = *(const s16x8*)&QKV[qoff + 32 + l4 * 8];

  f32x4 o[4] = {};
  f32x4 lacc = {};
  float mr = -1e30f;
  const u8* mb = mask + (size_t)b * S * S;
  const u8* msb = msum + (size_t)(b * 32 + qt) * 32;
  const u16* vbase = VT + (size_t)bh * 64 * S;
  const int bS = b * S;

  auto stage = [&](int bi, int kvv) {
#pragma unroll
    for (int c = 0; c < 2; ++c) {
      const int byt = ((c * 4 + wave) * 64 + lane) * 16;  // 0..8191
      const int row = byt >> 7;
      const int cb = (byt & 127) ^ ((row & 7) << 4);
      GLDS16(QKV + (size_t)(bS + kvv + row) * QSTR + 1024 + h * 64 + (cb >> 1),
             &lK[bi][(c * 4 + wave) * 512]);
      GLDS16(vbase + (size_t)row * S + kvv + (cb >> 1),
             &lV[bi][(c * 4 + wave) * 512]);
    }
  };

  auto body = [&](int bi, int kvv) {
    if (kvv + 64 < S) stage(bi ^ 1, kvv + 64);
    const char* kbuf = (const char*)&lK[bi][0];
    const char* vbuf = (const char*)&lV[bi][0];

    // ---- QK^T (swapped): sc[t] = mfma(K, Q) ----
    f32x4 sc[4];
    __builtin_amdgcn_s_setprio(1);
#pragma unroll
    for (int t = 0; t < 4; ++t) {
      const int row = t * 16 + l15;
      const int sw = (row & 7) << 4;
      const s16x8 kf0 = *(const s16x8*)(kbuf + row * 128 + ((l4 * 16) ^ sw));
      const s16x8 kf1 = *(const s16x8*)(kbuf + row * 128 + ((64 + l4 * 16) ^ sw));
      f32x4 z = {};
      z = __builtin_amdgcn_mfma_f32_16x16x32_bf16(kf0, qa0, z, 0, 0, 0);
      z = __builtin_amdgcn_mfma_f32_16x16x32_bf16(kf1, qa1, z, 0, 0, 0);
      sc[t] = z;
    }
    __builtin_amdgcn_s_setprio(0);
    // ---- mask (rare slow path via tile summary; finite sentinel) ----
    if (msb[kvv >> 6]) {
#pragma unroll
      for (int t = 0; t < 4; ++t) {
        const uchar4 m4 = *(const uchar4*)&mb[(size_t)(q0 + l15) * S + kvv + t * 16 + l4 * 4];
        if (m4.x) sc[t][0] = -1e30f;
        if (m4.y) sc[t][1] = -1e30f;
        if (m4.z) sc[t][2] = -1e30f;
        if (m4.w) sc[t][3] = -1e30f;
      }
    }
    // ---- online softmax with defer-max; max via v_max3 tree ----
    float pm = max3f(sc[0][0], sc[0][1], sc[0][2]);
    pm = max3f(pm, sc[0][3], sc[1][0]);
    pm = max3f(pm, sc[1][1], sc[1][2]);
    pm = max3f(pm, sc[1][3], sc[2][0]);
    pm = max3f(pm, sc[2][1], sc[2][2]);
    pm = max3f(pm, sc[2][3], sc[3][0]);
    pm = max3f(pm, sc[3][1], sc[3][2]);
    pm = fmaxf(pm, sc[3][3]);
    pm = fmaxf(pm, __shfl_xor(pm, 16));
    pm = fmaxf(pm, __shfl_xor(pm, 32));
    if (!__all(pm <= mr + 44.0f)) {  // 44 raw = 8 exp2-units; p bounded by 2^8
      const float mn = fmaxf(mr, pm);
      const float al = exp2f((mr - mn) * CE);
      mr = mn;
#pragma unroll
      for (int j = 0; j < 4; ++j) lacc[j] *= al;
#pragma unroll
      for (int n = 0; n < 4; ++n)
#pragma unroll
        for (int j = 0; j < 4; ++j) o[n][j] *= al;
    }
    const float mrc = mr * CE;
#pragma unroll
    for (int t = 0; t < 4; ++t)
#pragma unroll
      for (int j = 0; j < 4; ++j)
        sc[t][j] = exp2f(fmaf(sc[t][j], CE, -mrc));
    // ---- pack P into 16x16x16 B-frags (zero cross-lane) ----
    s16x4 pb[4];
#pragma unroll
    for (int t = 0; t < 4; ++t) {
      const u32 lo = cvtpk_bf16(sc[t][0], sc[t][1]);
      const u32 hi = cvtpk_bf16(sc[t][2], sc[t][3]);
      pb[t] = __builtin_bit_cast(s16x4, u32x2{lo, hi});
    }
    // ---- row-sum via MFMA (ones A-frag): lacc[.][q=l15] += sum_k pb[k][q] ----
    __builtin_amdgcn_s_setprio(1);
#pragma unroll
    for (int t = 0; t < 4; ++t)
      lacc = __builtin_amdgcn_mfma_f32_16x16x16bf16_1k(ones, pb[t], lacc, 0, 0, 0);
    // ---- PV: o[n] += mfma_16x16x16(V frag, P frag) ----
#pragma unroll
    for (int n = 0; n < 4; ++n) {
      const int row = n * 16 + l15;
      const int sw = (row & 7) << 4;
#pragma unroll
      for (int t = 0; t < 4; ++t) {
        const s16x4 va = *(const s16x4*)(vbuf + row * 128 + ((t * 32 + l4 * 8) ^ sw));
        o[n] = __builtin_amdgcn_mfma_f32_16x16x16bf16_1k(va, pb[t], o[n], 0, 0, 0);
      }
    }
    __builtin_amdgcn_s_setprio(0);
    __syncthreads();  // drains prefetch vmcnt + protects buf swap
  };

  stage(0, 0);
  __syncthreads();
  for (int kv = 0; kv < S; kv += 128) {  // x2 unroll: buf compile-time per body
    body(0, kv);
    body(1, kv + 64);
  }
  // ---- epilogue: normalize by MFMA-accumulated row sum, pack, store ----
  const float lsum = lacc[0];
  const float inv = lsum > 0.0f ? 1.0f / lsum : 0.0f;
  const size_t obase = (size_t)(b * S + q0 + l15) * Dm + h * 64;
#pragma unroll
  for (int n = 0; n < 4; ++n) {
    const u32 lo = cvtpk_bf16(o[n][0] * inv, o[n][1] * inv);
    const u32 hi = cvtpk_bf16(o[n][2] * inv, o[n][3] * inv);
    *(u32x2*)&out[obase + n * 16 + l4 * 4] = u32x2{lo, hi};
  }
}

extern "C" void kernel_launch(void* const* d_in, const int* in_sizes, int n_in,
                              void* d_out, int out_size, void* d_ws, size_t ws_size,
                              hipStream_t stream) {
  (void)in_sizes; (void)n_in; (void)out_size; (void)ws_size;
  const float* x = (const float*)d_in[0];
  const u8* mask = (const u8*)d_in[1];
  const float* Wq = (const float*)d_in[2];
  const float* Wk = (const float*)d_in[3];
  const float* Wv = (const float*)d_in[4];
  const float* Wo = (const float*)d_in[5];
  const float* bo = (const float*)d_in[6];
  const float* W1 = (const float*)d_in[7];
  const float* b1 = (const float*)d_in[8];
  const float* W2 = (const float*)d_in[9];
  const float* b2 = (const float*)d_in[10];
  const float* g1 = (const float*)d_in[11];
  const float* be1 = (const float*)d_in[12];
  const float* g2 = (const float*)d_in[13];
  const float* be2 = (const float*)d_in[14];
  float* outp = (float*)d_out;

  const int B = 2, S = 2048, D = 1024, FF = 4096;
  const int M = B * S;  // 4096
  char* w = (char*)d_ws;
  const size_t MB = 1024 * 1024;
  u16* wqkvT = (u16*)(w + 0 * MB);    // [3072,1024] bf16   [0,6)
  u16* woT = (u16*)(w + 6 * MB);      // [1024,1024]        [6,8)
  u16* w1T = (u16*)(w + 8 * MB);      // [4096,1024]        [8,16)
  u16* w2T = (u16*)(w + 16 * MB);     // [1024,4096]        [16,24)
  u16* xb  = (u16*)(w + 24 * MB);     // [4096,1024]        [24,32)
  u16* qkv = (u16*)(w + 32 * MB);     // [4096,3072]        [32,56)
  u16* vt  = (u16*)(w + 56 * MB);     // [B*H,64,S]         [56,64)
  float* x0f = (float*)(w + 64 * MB); // [4096,1024] f32    [64,80)
  float* x1f = (float*)(w + 80 * MB); //                    [80,96)
  u16* x1b = (u16*)(w + 96 * MB);     // [4096,1024] bf16   [96,104)
  u8* msum = (u8*)(w + 64 * MB);      // 2 KB, dead before x0f is written
  u16* attn_o = xb;                   // xb dead after QKV gemm
  u16* ff1 = (u16*)(w + 32 * MB);     // [4096,4096] bf16, reuses qkv+vt [32,64)
  float* y0f = x0f;

  // weight prep (Wq/Wk/Wv transposed into one contiguous [3072,1024] block)
  transpose_f32_bf16<<<dim3(32, 32), 256, 0, stream>>>(Wq, wqkvT, 1024, 1024);
  transpose_f32_bf16<<<dim3(32, 32), 256, 0, stream>>>(Wk, wqkvT + 1024 * 1024, 1024, 1024);
  transpose_f32_bf16<<<dim3(32, 32), 256, 0, stream>>>(Wv, wqkvT + 2048 * 1024, 1024, 1024);
  transpose_f32_bf16<<<dim3(32, 32), 256, 0, stream>>>(Wo, woT, 1024, 1024);
  transpose_f32_bf16<<<dim3(128, 32), 256, 0, stream>>>(W1, w1T, 1024, 4096);
  transpose_f32_bf16<<<dim3(32, 128), 256, 0, stream>>>(W2, w2T, 4096, 1024);
  cvt_f32_bf16<<<dim3(M * D / 4 / 256), 256, 0, stream>>>(x, xb, M * D / 4);
  mask_summary<<<dim3(32, 32, 2), 256, 0, stream>>>(mask, msum);

  // fused QKV projection: [4096,1024] @ [3072,1024]^T -> [4096,3072]
  gemm_bt<0, 128><<<dim3(3 * D / 128, M / 128), 256, 0, stream>>>(xb, wqkvT, M, 3 * D, D, nullptr, nullptr, qkv, nullptr);
  // V -> V^T per batch (strided read from qkv cols 2048..3071)
  transpose_bf16_b<<<dim3(32, 64, 2), 256, 0, stream>>>(qkv, vt, 2048, 1024, 3072, 2048);

  // attention: 1024 blocks, direct bf16 out
  attn_k<<<dim3(1024), 256, 0, stream>>>(qkv, vt, mask, msum, attn_o);

  // Wo projection + bias + residual(x) -- BM=64
  gemm_bt<2, 64><<<dim3(D / 128, M / 64), 256, 0, stream>>>(attn_o, woT, M, D, D, bo, x, nullptr, x0f);
  layernorm_k<1><<<dim3(M), 256, 0, stream>>>(x0f, g1, be1, x1f, x1b);
  gemm_bt<1, 128><<<dim3(FF / 128, M / 128), 256, 0, stream>>>(x1b, w1T, M, FF, D, b1, nullptr, ff1, nullptr);
  gemm_bt<2, 64><<<dim3(D / 128, M / 64), 256, 0, stream>>>(ff1, w2T, M, D, FF, b2, x1f, nullptr, y0f);
  layernorm_k<0><<<dim3(M), 256, 0, stream>>>(y0f, g2, be2, outp, nullptr);
}

// Round 11
// 296.605 us; speedup vs baseline: 1.0681x; 1.0097x over previous
//
#include <hip/hip_runtime.h>
#include <math.h>

typedef unsigned short u16;
typedef unsigned char u8;
typedef unsigned int u32;
typedef __attribute__((ext_vector_type(4))) float f32x4;
typedef __attribute__((ext_vector_type(8))) short s16x8;
typedef __attribute__((ext_vector_type(4))) short s16x4;
typedef __attribute__((ext_vector_type(4))) u32 u32x4;
typedef __attribute__((ext_vector_type(2))) u32 u32x2;

__device__ __forceinline__ u16 f2bf(float f) {
  unsigned u = __builtin_bit_cast(unsigned, f);
  u += 0x7fffu + ((u >> 16) & 1u);
  return (u16)(u >> 16);
}

__device__ __forceinline__ u32 cvtpk_bf16(float lo, float hi) {
  u32 r;
  asm("v_cvt_pk_bf16_f32 %0, %1, %2" : "=v"(r) : "v"(lo), "v"(hi));
  return r;
}

__device__ __forceinline__ float max3f(float a, float b, float c) {
  return fmaxf(fmaxf(a, b), c);  // fuses to v_max3_f32
}

#define GLDS16(g, l) __builtin_amdgcn_global_load_lds( \
    (const __attribute__((address_space(1))) void*)(g), \
    (__attribute__((address_space(3))) void*)(l), 16, 0, 0)

// ---------------- GEMM 2-phase (proven): C = A @ BT^T, BM x 128 tile ----------------
template <int EPI, int BM>
__global__ __launch_bounds__(256, 2) void gemm_bt(
    const u16* __restrict__ A, const u16* __restrict__ BT, int M, int N, int K,
    const float* __restrict__ bias, const float* __restrict__ resid,
    u16* __restrict__ outB, float* __restrict__ outF) {
  constexpr int MT = BM / 32;
  __shared__ __align__(16) u16 lA[2][BM * 32];
  __shared__ __align__(16) u16 lB[2][128 * 32];
  const int tid = threadIdx.x;
  const int wave = __builtin_amdgcn_readfirstlane(tid >> 6);
  const int lane = tid & 63;
  const int l15 = lane & 15, l4 = lane >> 4;
  const int wr = wave >> 1, wc = wave & 1;
  const int nwg = gridDim.x * gridDim.y;
  int wg = blockIdx.y * gridDim.x + blockIdx.x;
  wg = (wg & 7) * (nwg >> 3) + (wg >> 3);  // XCD swizzle (bijective: nwg%8==0)
  const int bx = wg % gridDim.x, by = wg / gridDim.x;
  const int row0 = by * BM, col0 = bx * 128;

  f32x4 acc[MT][4] = {};

  auto stage = [&](int bi, int k0) {
#pragma unroll
    for (int c = 0; c < BM / 64; ++c) {
      const int chunk = c * 4 + wave;
      const int idx = chunk * 64 + lane;
      const int r = idx >> 2, cb = (idx & 3) * 8;
      GLDS16(A + (size_t)(row0 + r) * K + k0 + cb, &lA[bi][chunk * 512]);
    }
#pragma unroll
    for (int c = 0; c < 2; ++c) {
      const int chunk = c * 4 + wave;
      const int idx = chunk * 64 + lane;
      const int r = idx >> 2, cb = (idx & 3) * 8;
      GLDS16(BT + (size_t)(col0 + r) * K + k0 + cb, &lB[bi][chunk * 512]);
    }
  };

  stage(0, 0);
  __syncthreads();
  int buf = 0;

  for (int k0 = 0; k0 < K; k0 += 32) {
    if (k0 + 32 < K) stage(buf ^ 1, k0 + 32);
    s16x8 af[MT], bfr[4];
#pragma unroll
    for (int m = 0; m < MT; ++m)
      af[m] = *(const s16x8*)&lA[buf][(wr * (BM / 2) + m * 16 + l15) * 32 + l4 * 8];
#pragma unroll
    for (int n = 0; n < 4; ++n)
      bfr[n] = *(const s16x8*)&lB[buf][(wc * 64 + n * 16 + l15) * 32 + l4 * 8];
#pragma unroll
    for (int m = 0; m < MT; ++m)
#pragma unroll
      for (int n = 0; n < 4; ++n)
        acc[m][n] = __builtin_amdgcn_mfma_f32_16x16x32_bf16(af[m], bfr[n], acc[m][n], 0, 0, 0);
    __syncthreads();
    buf ^= 1;
  }

#pragma unroll
  for (int m = 0; m < MT; ++m) {
    const int rowb = row0 + wr * (BM / 2) + m * 16 + l4 * 4;
#pragma unroll
    for (int n = 0; n < 4; ++n) {
      const int col = col0 + wc * 64 + n * 16 + l15;
#pragma unroll
      for (int j = 0; j < 4; ++j) {
        const int r = rowb + j;
        float v = acc[m][n][j];
        if (EPI == 0) {
          outB[(size_t)r * N + col] = f2bf(v);
        } else if (EPI == 1) {
          v += bias[col];
          outB[(size_t)r * N + col] = f2bf(v > 0.0f ? v : 0.0f);
        } else {
          v += bias[col] + resid[(size_t)r * N + col];
          outF[(size_t)r * N + col] = v;
        }
      }
    }
  }
}

// ---------------- GEMM 256x128 triple-buffered, counted-vmcnt (T4) ----------------
// 512 threads = 8 waves (2M x 4N); per-wave C = 128x32 (8 Mfrag x 2 Nfrag).
// BK=64; LDS = 3 x (A 32KB + B 16KB) = 144KB dynamic; XOR-swizzled rows (T2).
// Depth-2 prefetch; main loop NEVER drains vmcnt to 0: each iter issues
// stage(kt+2), waits vmcnt(12) (own 6 oldest = tile kt), raw s_barrier.
// Race-free: stage into (kt+2)%3 is issued only after the barrier that ends
// iter kt-1 -- the last reader of that buffer.
template <int EPI>
__global__ __launch_bounds__(512, 1) void gemm256(
    const u16* __restrict__ A, const u16* __restrict__ BT, int M, int N, int K,
    const float* __restrict__ bias, u16* __restrict__ outB) {
  extern __shared__ __align__(16) u16 smem[];
  u16* lA = smem;           // 3 x 16384 u16 (32KB each)
  u16* lB = smem + 49152;   // 3 x 8192 u16 (16KB each)
  const int tid = threadIdx.x;
  const int wave = __builtin_amdgcn_readfirstlane(tid >> 6);
  const int lane = tid & 63;
  const int l15 = lane & 15, l4 = lane >> 4;
  const int wr = wave >> 2, wc = wave & 3;
  const int nwg = gridDim.x * gridDim.y;
  int wg = blockIdx.y * gridDim.x + blockIdx.x;
  wg = (wg & 7) * (nwg >> 3) + (wg >> 3);  // XCD swizzle (bijective: nwg%8==0)
  const int bx = wg % gridDim.x, by = wg / gridDim.x;
  const int row0 = by * 256, col0 = bx * 128;
  const int NT = K >> 6;  // K-tiles of 64

  f32x4 acc[8][2] = {};

  // stage K-tile kt into buffer bi: LDS linear dest, global source pre-swizzled
  // with cb ^= ((row&7)<<4) so swizzled ds_reads see linear data (rule #21).
  auto stage = [&](int bi, int kt) {
    const int k0 = kt << 6;
#pragma unroll
    for (int c = 0; c < 4; ++c) {  // A: 256 rows x 128B
      const int byt = ((c * 8 + wave) * 64 + lane) * 16;
      const int row = byt >> 7;
      const int cb = (byt & 127) ^ ((row & 7) << 4);
      GLDS16(A + (size_t)(row0 + row) * K + k0 + (cb >> 1),
             &lA[bi * 16384 + (c * 8 + wave) * 512]);
    }
#pragma unroll
    for (int c = 0; c < 2; ++c) {  // B: 128 rows x 128B
      const int byt = ((c * 8 + wave) * 64 + lane) * 16;
      const int row = byt >> 7;
      const int cb = (byt & 127) ^ ((row & 7) << 4);
      GLDS16(BT + (size_t)(col0 + row) * K + k0 + (cb >> 1),
             &lB[bi * 8192 + (c * 8 + wave) * 512]);
    }
  };

  stage(0, 0);
  stage(1, 1);
  int cur = 0;

  for (int kt = 0; kt < NT; ++kt) {
    if (kt + 2 < NT) {
      stage(cur == 0 ? 2 : cur - 1, kt + 2);  // (kt+2)%3
      asm volatile("s_waitcnt vmcnt(12)" ::: "memory");  // own 6 oldest = tile kt
    } else if (kt + 1 < NT) {
      asm volatile("s_waitcnt vmcnt(6)" ::: "memory");
    } else {
      asm volatile("s_waitcnt vmcnt(0)" ::: "memory");
    }
    __builtin_amdgcn_sched_barrier(0);
    __builtin_amdgcn_s_barrier();  // raw: no compiler vmcnt(0) drain
    __builtin_amdgcn_sched_barrier(0);

    const char* curA = (const char*)&lA[cur * 16384];
    const char* curB = (const char*)&lB[cur * 8192];
#pragma unroll
    for (int s = 0; s < 2; ++s) {  // two K=32 sub-steps
      s16x8 af[8], bf[2];
#pragma unroll
      for (int m = 0; m < 8; ++m) {
        const int row = wr * 128 + m * 16 + l15;
        af[m] = *(const s16x8*)(curA + row * 128 + ((s * 64 + l4 * 16) ^ ((row & 7) << 4)));
      }
#pragma unroll
      for (int n = 0; n < 2; ++n) {
        const int row = wc * 32 + n * 16 + l15;
        bf[n] = *(const s16x8*)(curB + row * 128 + ((s * 64 + l4 * 16) ^ ((row & 7) << 4)));
      }
      __builtin_amdgcn_s_setprio(1);
#pragma unroll
      for (int m = 0; m < 8; ++m)
#pragma unroll
        for (int n = 0; n < 2; ++n)
          acc[m][n] = __builtin_amdgcn_mfma_f32_16x16x32_bf16(af[m], bf[n], acc[m][n], 0, 0, 0);
      __builtin_amdgcn_s_setprio(0);
    }
    __builtin_amdgcn_sched_barrier(0);
    __builtin_amdgcn_s_barrier();  // end-of-iter: all waves done reading cur
    cur = (cur == 2) ? 0 : cur + 1;
  }

#pragma unroll
  for (int m = 0; m < 8; ++m) {
    const int rowb = row0 + wr * 128 + m * 16 + l4 * 4;
#pragma unroll
    for (int n = 0; n < 2; ++n) {
      const int col = col0 + wc * 32 + n * 16 + l15;
#pragma unroll
      for (int j = 0; j < 4; ++j) {
        float v = acc[m][n][j];
        if (EPI == 1) {
          v += bias[col];
          v = v > 0.0f ? v : 0.0f;
        }
        outB[(size_t)(rowb + j) * N + col] = f2bf(v);
      }
    }
  }
}

// ---------------- weight transpose f32 -> bf16 ----------------
__global__ __launch_bounds__(256) void transpose_f32_bf16(
    const float* __restrict__ in, u16* __restrict__ out, int R, int C) {
  __shared__ float t[32][33];
  const int c0 = blockIdx.x * 32, r0 = blockIdx.y * 32;
  const int tx = threadIdx.x & 31, ty = threadIdx.x >> 5;
#pragma unroll
  for (int i = 0; i < 4; ++i)
    t[ty + i * 8][tx] = in[(size_t)(r0 + ty + i * 8) * C + c0 + tx];
  __syncthreads();
#pragma unroll
  for (int i = 0; i < 4; ++i)
    out[(size_t)(c0 + ty + i * 8) * R + r0 + tx] = f2bf(t[tx][ty + i * 8]);
}

// ---------------- batched bf16 transpose (strided input, col-offset) ----------------
__global__ __launch_bounds__(256) void transpose_bf16_b(
    const u16* __restrict__ in, u16* __restrict__ out, int R, int C, int rstr, int coff) {
  __shared__ u16 t[32][34];
  const int b = blockIdx.z;
  const u16* pi = in + (size_t)b * R * rstr + coff;
  u16* po = out + (size_t)b * R * C;
  const int c0 = blockIdx.x * 32, r0 = blockIdx.y * 32;
  const int tx = threadIdx.x & 31, ty = threadIdx.x >> 5;
#pragma unroll
  for (int i = 0; i < 4; ++i)
    t[ty + i * 8][tx] = pi[(size_t)(r0 + ty + i * 8) * rstr + c0 + tx];
  __syncthreads();
#pragma unroll
  for (int i = 0; i < 4; ++i)
    po[(size_t)(c0 + ty + i * 8) * R + r0 + tx] = t[tx][ty + i * 8];
}

// ---------------- f32 -> bf16 elementwise ----------------
__global__ __launch_bounds__(256) void cvt_f32_bf16(
    const float* __restrict__ in, u16* __restrict__ out, int n4) {
  const int i = blockIdx.x * 256 + threadIdx.x;
  if (i >= n4) return;
  f32x4 v = *(const f32x4*)&in[(size_t)i * 4];
  s16x4 o;
#pragma unroll
  for (int j = 0; j < 4; ++j) o[j] = (short)f2bf(v[j]);
  *(s16x4*)&out[(size_t)i * 4] = o;
}

// ---------------- LayerNorm over D=1024 ----------------
template <int WB>
__global__ __launch_bounds__(256) void layernorm_k(
    const float* __restrict__ in, const float* __restrict__ gm, const float* __restrict__ bt,
    float* __restrict__ outF, u16* __restrict__ outB) {
  const int row = blockIdx.x;
  const int t = threadIdx.x;
  const float* xr = in + (size_t)row * 1024;
  f32x4 v = *(const f32x4*)&xr[t * 4];
  float s = v[0] + v[1] + v[2] + v[3];
  float s2 = v[0] * v[0] + v[1] * v[1] + v[2] * v[2] + v[3] * v[3];
#pragma unroll
  for (int o = 32; o; o >>= 1) {
    s += __shfl_down(s, o);
    s2 += __shfl_down(s2, o);
  }
  __shared__ float red[8];
  const int lane = t & 63, wv = t >> 6;
  if (lane == 0) { red[wv] = s; red[4 + wv] = s2; }
  __syncthreads();
  s = red[0] + red[1] + red[2] + red[3];
  s2 = red[4] + red[5] + red[6] + red[7];
  const float mu = s * (1.0f / 1024.0f);
  const float var = fmaxf(s2 * (1.0f / 1024.0f) - mu * mu, 0.0f);
  const float rs = rsqrtf(var + 1e-5f);
  f32x4 g4 = *(const f32x4*)&gm[t * 4];
  f32x4 b4 = *(const f32x4*)&bt[t * 4];
  f32x4 ov;
#pragma unroll
  for (int j = 0; j < 4; ++j) ov[j] = (v[j] - mu) * rs * g4[j] + b4[j];
  *(f32x4*)&outF[(size_t)row * 1024 + t * 4] = ov;
  if (WB) {
    s16x4 ob;
#pragma unroll
    for (int j = 0; j < 4; ++j) ob[j] = (short)f2bf(ov[j]);
    *(s16x4*)&outB[(size_t)row * 1024 + t * 4] = ob;
  }
}

// ---------------- mask tile summary: any() over 64x64 tiles ----------------
__global__ __launch_bounds__(256) void mask_summary(
    const u8* __restrict__ mask, u8* __restrict__ msum) {
  const int kt = blockIdx.x, qt = blockIdx.y, b = blockIdx.z;
  const int tid = threadIdx.x;
  __shared__ int any_flag;
  if (tid == 0) any_flag = 0;
  __syncthreads();
  const u8* base = mask + ((size_t)(b * 2048 + qt * 64 + (tid >> 2))) * 2048 + kt * 64 + (tid & 3) * 16;
  const u32x4 v = *(const u32x4*)base;
  if (v[0] | v[1] | v[2] | v[3]) any_flag = 1;
  __syncthreads();
  if (tid == 0) msum[((size_t)b * 32 + qt) * 32 + kt] = (u8)any_flag;
}

// ---------------- flash attention: R5-exact body (52 VGPR, 102us proven) ----------------
__global__ __launch_bounds__(256) void attn_k(
    const u16* __restrict__ QKV, const u16* __restrict__ VT,
    const u8* __restrict__ mask, const u8* __restrict__ msum, u16* __restrict__ out) {
  const int S = 2048, QSTR = 3072, Dm = 1024;
  const int wgid = blockIdx.x;  // 0..1023
  const int xcd = wgid & 7, slot = wgid >> 3;
  const int bh = xcd * 4 + (slot >> 5);  // 4 bh per XCD -> 2MB KV L2-resident
  const int qt = slot & 31;
  const int b = bh >> 4, h = bh & 15;
  const int wave = threadIdx.x >> 6, lane = threadIdx.x & 63;
  const int l15 = lane & 15, l4 = lane >> 4;
  const int q0 = qt * 64 + wave * 16;
  const float CE = 0.125f * 1.44269504f;  // 1/sqrt(64) * log2(e)

  __shared__ __align__(16) u16 lK[2][4096];  // [buf][64 x 64], XOR-swizzled
  __shared__ __align__(16) u16 lV[2][4096];

  const size_t qoff = (size_t)(b * S + q0 + l15) * QSTR + h * 64;
  const s16x8 qa0 = *(const s16x8*)&QKV[qoff + l4 * 8];
  const s16x8 qa1 = *(const s16x8*)&QKV[qoff + 32 + l4 * 8];

  f32x4 o[4] = {};
  float mr = -1e30f, lr = 0.0f;
  const u8* mb = mask + (size_t)b * S * S;
  const u8* msb = msum + (size_t)(b * 32 + qt) * 32;
  const u16* vbase = VT + (size_t)bh * 64 * S;
  const int bS = b * S;

  auto stage = [&](int bi, int kvv) {
#pragma unroll
    for (int c = 0; c < 2; ++c) {
      const int byt = ((c * 4 + wave) * 64 + lane) * 16;
      const int row = byt >> 7;
      const int cb = (byt & 127) ^ ((row & 7) << 4);
      GLDS16(QKV + (size_t)(bS + kvv + row) * QSTR + 1024 + h * 64 + (cb >> 1),
             &lK[bi][(c * 4 + wave) * 512]);
      GLDS16(vbase + (size_t)row * S + kvv + (cb >> 1),
             &lV[bi][(c * 4 + wave) * 512]);
    }
  };

  auto body = [&](int bi, int kvv) {
    if (kvv + 64 < S) stage(bi ^ 1, kvv + 64);
    const char* kbuf = (const char*)&lK[bi][0];
    const char* vbuf = (const char*)&lV[bi][0];

    f32x4 sc[4];
    __builtin_amdgcn_s_setprio(1);
#pragma unroll
    for (int t = 0; t < 4; ++t) {
      const int row = t * 16 + l15;
      const int sw = (row & 7) << 4;
      const s16x8 kf0 = *(const s16x8*)(kbuf + row * 128 + ((l4 * 16) ^ sw));
      const s16x8 kf1 = *(const s16x8*)(kbuf + row * 128 + ((64 + l4 * 16) ^ sw));
      f32x4 z = {};
      z = __builtin_amdgcn_mfma_f32_16x16x32_bf16(kf0, qa0, z, 0, 0, 0);
      z = __builtin_amdgcn_mfma_f32_16x16x32_bf16(kf1, qa1, z, 0, 0, 0);
      sc[t] = z;
    }
    __builtin_amdgcn_s_setprio(0);
    if (msb[kvv >> 6]) {
#pragma unroll
      for (int t = 0; t < 4; ++t) {
        const uchar4 m4 = *(const uchar4*)&mb[(size_t)(q0 + l15) * S + kvv + t * 16 + l4 * 4];
        if (m4.x) sc[t][0] = -1e30f;
        if (m4.y) sc[t][1] = -1e30f;
        if (m4.z) sc[t][2] = -1e30f;
        if (m4.w) sc[t][3] = -1e30f;
      }
    }
    float pm = max3f(sc[0][0], sc[0][1], sc[0][2]);
    pm = max3f(pm, sc[0][3], sc[1][0]);
    pm = max3f(pm, sc[1][1], sc[1][2]);
    pm = max3f(pm, sc[1][3], sc[2][0]);
    pm = max3f(pm, sc[2][1], sc[2][2]);
    pm = max3f(pm, sc[2][3], sc[3][0]);
    pm = max3f(pm, sc[3][1], sc[3][2]);
    pm = fmaxf(pm, sc[3][3]);
    pm = fmaxf(pm, __shfl_xor(pm, 16));
    pm = fmaxf(pm, __shfl_xor(pm, 32));
    if (!__all(pm <= mr + 44.0f)) {  // 44 raw = 8 exp2-units
      const float mn = fmaxf(mr, pm);
      const float al = exp2f((mr - mn) * CE);
      mr = mn;
      lr *= al;
#pragma unroll
      for (int n = 0; n < 4; ++n)
#pragma unroll
        for (int j = 0; j < 4; ++j) o[n][j] *= al;
    }
    const float mrc = mr * CE;
    float rsum = 0.0f;
#pragma unroll
    for (int t = 0; t < 4; ++t)
#pragma unroll
      for (int j = 0; j < 4; ++j) {
        const float p = exp2f(fmaf(sc[t][j], CE, -mrc));
        sc[t][j] = p;
        rsum += p;
      }
    rsum += __shfl_xor(rsum, 16);
    rsum += __shfl_xor(rsum, 32);
    lr += rsum;
    s16x4 pb[4];
#pragma unroll
    for (int t = 0; t < 4; ++t) {
      const u32 lo = cvtpk_bf16(sc[t][0], sc[t][1]);
      const u32 hi = cvtpk_bf16(sc[t][2], sc[t][3]);
      pb[t] = __builtin_bit_cast(s16x4, u32x2{lo, hi});
    }
    __builtin_amdgcn_s_setprio(1);
#pragma unroll
    for (int n = 0; n < 4; ++n) {
      const int row = n * 16 + l15;
      const int sw = (row & 7) << 4;
#pragma unroll
      for (int t = 0; t < 4; ++t) {
        const s16x4 va = *(const s16x4*)(vbuf + row * 128 + ((t * 32 + l4 * 8) ^ sw));
        o[n] = __builtin_amdgcn_mfma_f32_16x16x16bf16_1k(va, pb[t], o[n], 0, 0, 0);
      }
    }
    __builtin_amdgcn_s_setprio(0);
    __syncthreads();
  };

  stage(0, 0);
  __syncthreads();
  for (int kv = 0; kv < S; kv += 128) {
    body(0, kv);
    body(1, kv + 64);
  }
  const float inv = lr > 0.0f ? 1.0f / lr : 0.0f;
  const size_t obase = (size_t)(b * S + q0 + l15) * Dm + h * 64;
#pragma unroll
  for (int n = 0; n < 4; ++n) {
    const u32 lo = cvtpk_bf16(o[n][0] * inv, o[n][1] * inv);
    const u32 hi = cvtpk_bf16(o[n][2] * inv, o[n][3] * inv);
    *(u32x2*)&out[obase + n * 16 + l4 * 4] = u32x2{lo, hi};
  }
}

extern "C" void kernel_launch(void* const* d_in, const int* in_sizes, int n_in,
                              void* d_out, int out_size, void* d_ws, size_t ws_size,
                              hipStream_t stream) {
  (void)in_sizes; (void)n_in; (void)out_size; (void)ws_size;
  const float* x = (const float*)d_in[0];
  const u8* mask = (const u8*)d_in[1];
  const float* Wq = (const float*)d_in[2];
  const float* Wk = (const float*)d_in[3];
  const float* Wv = (const float*)d_in[4];
  const float* Wo = (const float*)d_in[5];
  const float* bo = (const float*)d_in[6];
  const float* W1 = (const float*)d_in[7];
  const float* b1 = (const float*)d_in[8];
  const float* W2 = (const float*)d_in[9];
  const float* b2 = (const float*)d_in[10];
  const float* g1 = (const float*)d_in[11];
  const float* be1 = (const float*)d_in[12];
  const float* g2 = (const float*)d_in[13];
  const float* be2 = (const float*)d_in[14];
  float* outp = (float*)d_out;

  const int B = 2, S = 2048, D = 1024, FF = 4096;
  const int M = B * S;  // 4096
  char* w = (char*)d_ws;
  const size_t MB = 1024 * 1024;
  u16* wqkvT = (u16*)(w + 0 * MB);    // [3072,1024] bf16   [0,6)
  u16* woT = (u16*)(w + 6 * MB);      // [1024,1024]        [6,8)
  u16* w1T = (u16*)(w + 8 * MB);      // [4096,1024]        [8,16)
  u16* w2T = (u16*)(w + 16 * MB);     // [1024,4096]        [16,24)
  u16* xb  = (u16*)(w + 24 * MB);     // [4096,1024]        [24,32)
  u16* qkv = (u16*)(w + 32 * MB);     // [4096,3072]        [32,56)
  u16* vt  = (u16*)(w + 56 * MB);     // [B*H,64,S]         [56,64)
  float* x0f = (float*)(w + 64 * MB); // [4096,1024] f32    [64,80)
  float* x1f = (float*)(w + 80 * MB); //                    [80,96)
  u16* x1b = (u16*)(w + 96 * MB);     // [4096,1024] bf16   [96,104)
  u8* msum = (u8*)(w + 64 * MB);      // 2 KB, dead before x0f is written
  u16* attn_o = xb;                   // xb dead after QKV gemm
  u16* ff1 = (u16*)(w + 32 * MB);     // [4096,4096] bf16, reuses qkv+vt [32,64)
  float* y0f = x0f;

  // weight prep (Wq/Wk/Wv transposed into one contiguous [3072,1024] block)
  transpose_f32_bf16<<<dim3(32, 32), 256, 0, stream>>>(Wq, wqkvT, 1024, 1024);
  transpose_f32_bf16<<<dim3(32, 32), 256, 0, stream>>>(Wk, wqkvT + 1024 * 1024, 1024, 1024);
  transpose_f32_bf16<<<dim3(32, 32), 256, 0, stream>>>(Wv, wqkvT + 2048 * 1024, 1024, 1024);
  transpose_f32_bf16<<<dim3(32, 32), 256, 0, stream>>>(Wo, woT, 1024, 1024);
  transpose_f32_bf16<<<dim3(128, 32), 256, 0, stream>>>(W1, w1T, 1024, 4096);
  transpose_f32_bf16<<<dim3(32, 128), 256, 0, stream>>>(W2, w2T, 4096, 1024);
  cvt_f32_bf16<<<dim3(M * D / 4 / 256), 256, 0, stream>>>(x, xb, M * D / 4);
  mask_summary<<<dim3(32, 32, 2), 256, 0, stream>>>(mask, msum);

  // fused QKV projection: 256x128-tile triple-buffered GEMM (144KB dynamic LDS)
  gemm256<0><<<dim3(3 * D / 128, M / 256), 512, 147456, stream>>>(xb, wqkvT, M, 3 * D, D, nullptr, qkv);
  // V -> V^T per batch (strided read from qkv cols 2048..3071)
  transpose_bf16_b<<<dim3(32, 64, 2), 256, 0, stream>>>(qkv, vt, 2048, 1024, 3072, 2048);

  // attention: R5-proven body, 1024 blocks
  attn_k<<<dim3(1024), 256, 0, stream>>>(qkv, vt, mask, msum, attn_o);

  // Wo projection + bias + residual(x) -- proven 2-phase BM=64
  gemm_bt<2, 64><<<dim3(D / 128, M / 64), 256, 0, stream>>>(attn_o, woT, M, D, D, bo, x, nullptr, x0f);
  layernorm_k<1><<<dim3(M), 256, 0, stream>>>(x0f, g1, be1, x1f, x1b);
  // FFN1: 256x128-tile GEMM with bias+ReLU epilogue
  gemm256<1><<<dim3(FF / 128, M / 256), 512, 147456, stream>>>(x1b, w1T, M, FF, D, b1, ff1);
  gemm_bt<2, 64><<<dim3(D / 128, M / 64), 256, 0, stream>>>(ff1, w2T, M, D, FF, b2, x1f, nullptr, y0f);
  layernorm_k<0><<<dim3(M), 256, 0, stream>>>(y0f, g2, be2, outp, nullptr);
}

// Round 13
// 285.607 us; speedup vs baseline: 1.1092x; 1.0385x over previous
//
#include <hip/hip_runtime.h>
#include <math.h>

typedef unsigned short u16;
typedef unsigned char u8;
typedef unsigned int u32;
typedef __attribute__((ext_vector_type(4))) float f32x4;
typedef __attribute__((ext_vector_type(8))) short s16x8;
typedef __attribute__((ext_vector_type(4))) short s16x4;
typedef __attribute__((ext_vector_type(4))) u32 u32x4;
typedef __attribute__((ext_vector_type(2))) u32 u32x2;

__device__ __forceinline__ u16 f2bf(float f) {
  unsigned u = __builtin_bit_cast(unsigned, f);
  u += 0x7fffu + ((u >> 16) & 1u);
  return (u16)(u >> 16);
}

__device__ __forceinline__ u32 cvtpk_bf16(float lo, float hi) {
  u32 r;
  asm("v_cvt_pk_bf16_f32 %0, %1, %2" : "=v"(r) : "v"(lo), "v"(hi));
  return r;
}

__device__ __forceinline__ float max3f(float a, float b, float c) {
  return fmaxf(fmaxf(a, b), c);  // fuses to v_max3_f32
}

#define GLDS16(g, l) __builtin_amdgcn_global_load_lds( \
    (const __attribute__((address_space(1))) void*)(g), \
    (__attribute__((address_space(3))) void*)(l), 16, 0, 0)

// ---------------- GEMM 2-phase (proven): C = A @ BT^T, BM x 128 tile ----------------
// XCD-aware block swizzle (all launched grids %8==0 -> bijective).
template <int EPI, int BM>
__global__ __launch_bounds__(256, 2) void gemm_bt(
    const u16* __restrict__ A, const u16* __restrict__ BT, int M, int N, int K,
    const float* __restrict__ bias, const float* __restrict__ resid,
    u16* __restrict__ outB, float* __restrict__ outF) {
  constexpr int MT = BM / 32;
  __shared__ __align__(16) u16 lA[2][BM * 32];
  __shared__ __align__(16) u16 lB[2][128 * 32];
  const int tid = threadIdx.x;
  const int wave = __builtin_amdgcn_readfirstlane(tid >> 6);
  const int lane = tid & 63;
  const int l15 = lane & 15, l4 = lane >> 4;
  const int wr = wave >> 1, wc = wave & 1;
  const int nwg = gridDim.x * gridDim.y;
  int wg = blockIdx.y * gridDim.x + blockIdx.x;
  wg = (wg & 7) * (nwg >> 3) + (wg >> 3);  // XCD swizzle (bijective: nwg%8==0)
  const int bx = wg % gridDim.x, by = wg / gridDim.x;
  const int row0 = by * BM, col0 = bx * 128;

  f32x4 acc[MT][4] = {};

  auto stage = [&](int bi, int k0) {
#pragma unroll
    for (int c = 0; c < BM / 64; ++c) {
      const int chunk = c * 4 + wave;
      const int idx = chunk * 64 + lane;
      const int r = idx >> 2, cb = (idx & 3) * 8;
      GLDS16(A + (size_t)(row0 + r) * K + k0 + cb, &lA[bi][chunk * 512]);
    }
#pragma unroll
    for (int c = 0; c < 2; ++c) {
      const int chunk = c * 4 + wave;
      const int idx = chunk * 64 + lane;
      const int r = idx >> 2, cb = (idx & 3) * 8;
      GLDS16(BT + (size_t)(col0 + r) * K + k0 + cb, &lB[bi][chunk * 512]);
    }
  };

  stage(0, 0);
  __syncthreads();
  int buf = 0;

  for (int k0 = 0; k0 < K; k0 += 32) {
    if (k0 + 32 < K) stage(buf ^ 1, k0 + 32);
    s16x8 af[MT], bfr[4];
#pragma unroll
    for (int m = 0; m < MT; ++m)
      af[m] = *(const s16x8*)&lA[buf][(wr * (BM / 2) + m * 16 + l15) * 32 + l4 * 8];
#pragma unroll
    for (int n = 0; n < 4; ++n)
      bfr[n] = *(const s16x8*)&lB[buf][(wc * 64 + n * 16 + l15) * 32 + l4 * 8];
#pragma unroll
    for (int m = 0; m < MT; ++m)
#pragma unroll
      for (int n = 0; n < 4; ++n)
        acc[m][n] = __builtin_amdgcn_mfma_f32_16x16x32_bf16(af[m], bfr[n], acc[m][n], 0, 0, 0);
    __syncthreads();
    buf ^= 1;
  }

#pragma unroll
  for (int m = 0; m < MT; ++m) {
    const int rowb = row0 + wr * (BM / 2) + m * 16 + l4 * 4;
#pragma unroll
    for (int n = 0; n < 4; ++n) {
      const int col = col0 + wc * 64 + n * 16 + l15;
#pragma unroll
      for (int j = 0; j < 4; ++j) {
        const int r = rowb + j;
        float v = acc[m][n][j];
        if (EPI == 0) {
          outB[(size_t)r * N + col] = f2bf(v);
        } else if (EPI == 1) {
          v += bias[col];
          outB[(size_t)r * N + col] = f2bf(v > 0.0f ? v : 0.0f);
        } else {
          v += bias[col] + resid[(size_t)r * N + col];
          outF[(size_t)r * N + col] = v;
        }
      }
    }
  }
}

// ---------------- weight transpose f32 -> bf16 ----------------
__global__ __launch_bounds__(256) void transpose_f32_bf16(
    const float* __restrict__ in, u16* __restrict__ out, int R, int C) {
  __shared__ float t[32][33];
  const int c0 = blockIdx.x * 32, r0 = blockIdx.y * 32;
  const int tx = threadIdx.x & 31, ty = threadIdx.x >> 5;
#pragma unroll
  for (int i = 0; i < 4; ++i)
    t[ty + i * 8][tx] = in[(size_t)(r0 + ty + i * 8) * C + c0 + tx];
  __syncthreads();
#pragma unroll
  for (int i = 0; i < 4; ++i)
    out[(size_t)(c0 + ty + i * 8) * R + r0 + tx] = f2bf(t[tx][ty + i * 8]);
}

// ---------------- batched bf16 transpose (strided input, col-offset) ----------------
__global__ __launch_bounds__(256) void transpose_bf16_b(
    const u16* __restrict__ in, u16* __restrict__ out, int R, int C, int rstr, int coff) {
  __shared__ u16 t[32][34];
  const int b = blockIdx.z;
  const u16* pi = in + (size_t)b * R * rstr + coff;
  u16* po = out + (size_t)b * R * C;
  const int c0 = blockIdx.x * 32, r0 = blockIdx.y * 32;
  const int tx = threadIdx.x & 31, ty = threadIdx.x >> 5;
#pragma unroll
  for (int i = 0; i < 4; ++i)
    t[ty + i * 8][tx] = pi[(size_t)(r0 + ty + i * 8) * rstr + c0 + tx];
  __syncthreads();
#pragma unroll
  for (int i = 0; i < 4; ++i)
    po[(size_t)(c0 + ty + i * 8) * R + r0 + tx] = t[tx][ty + i * 8];
}

// ---------------- f32 -> bf16 elementwise ----------------
__global__ __launch_bounds__(256) void cvt_f32_bf16(
    const float* __restrict__ in, u16* __restrict__ out, int n4) {
  const int i = blockIdx.x * 256 + threadIdx.x;
  if (i >= n4) return;
  f32x4 v = *(const f32x4*)&in[(size_t)i * 4];
  s16x4 o;
#pragma unroll
  for (int j = 0; j < 4; ++j) o[j] = (short)f2bf(v[j]);
  *(s16x4*)&out[(size_t)i * 4] = o;
}

// ---------------- LayerNorm over D=1024 ----------------
template <int WB>
__global__ __launch_bounds__(256) void layernorm_k(
    const float* __restrict__ in, const float* __restrict__ gm, const float* __restrict__ bt,
    float* __restrict__ outF, u16* __restrict__ outB) {
  const int row = blockIdx.x;
  const int t = threadIdx.x;
  const float* xr = in + (size_t)row * 1024;
  f32x4 v = *(const f32x4*)&xr[t * 4];
  float s = v[0] + v[1] + v[2] + v[3];
  float s2 = v[0] * v[0] + v[1] * v[1] + v[2] * v[2] + v[3] * v[3];
#pragma unroll
  for (int o = 32; o; o >>= 1) {
    s += __shfl_down(s, o);
    s2 += __shfl_down(s2, o);
  }
  __shared__ float red[8];
  const int lane = t & 63, wv = t >> 6;
  if (lane == 0) { red[wv] = s; red[4 + wv] = s2; }
  __syncthreads();
  s = red[0] + red[1] + red[2] + red[3];
  s2 = red[4] + red[5] + red[6] + red[7];
  const float mu = s * (1.0f / 1024.0f);
  const float var = fmaxf(s2 * (1.0f / 1024.0f) - mu * mu, 0.0f);
  const float rs = rsqrtf(var + 1e-5f);
  f32x4 g4 = *(const f32x4*)&gm[t * 4];
  f32x4 b4 = *(const f32x4*)&bt[t * 4];
  f32x4 ov;
#pragma unroll
  for (int j = 0; j < 4; ++j) ov[j] = (v[j] - mu) * rs * g4[j] + b4[j];
  *(f32x4*)&outF[(size_t)row * 1024 + t * 4] = ov;
  if (WB) {
    s16x4 ob;
#pragma unroll
    for (int j = 0; j < 4; ++j) ob[j] = (short)f2bf(ov[j]);
    *(s16x4*)&outB[(size_t)row * 1024 + t * 4] = ob;
  }
}

// ---------------- mask tile summary: any() over 64x64 tiles ----------------
__global__ __launch_bounds__(256) void mask_summary(
    const u8* __restrict__ mask, u8* __restrict__ msum) {
  const int kt = blockIdx.x, qt = blockIdx.y, b = blockIdx.z;
  const int tid = threadIdx.x;
  __shared__ int any_flag;
  if (tid == 0) any_flag = 0;
  __syncthreads();
  const u8* base = mask + ((size_t)(b * 2048 + qt * 64 + (tid >> 2))) * 2048 + kt * 64 + (tid & 3) * 16;
  const u32x4 v = *(const u32x4*)base;
  if (v[0] | v[1] | v[2] | v[3]) any_flag = 1;
  __syncthreads();
  if (tid == 0) msum[((size_t)b * 32 + qt) * 32 + kt] = (u8)any_flag;
}

// ---------------- flash attention: R11 body (96us best-measured) ----------------
__global__ __launch_bounds__(256) void attn_k(
    const u16* __restrict__ QKV, const u16* __restrict__ VT,
    const u8* __restrict__ mask, const u8* __restrict__ msum, u16* __restrict__ out) {
  const int S = 2048, QSTR = 3072, Dm = 1024;
  const int wgid = blockIdx.x;  // 0..1023
  const int xcd = wgid & 7, slot = wgid >> 3;
  const int bh = xcd * 4 + (slot >> 5);  // 4 bh per XCD -> 2MB KV L2-resident
  const int qt = slot & 31;
  const int b = bh >> 4, h = bh & 15;
  const int wave = threadIdx.x >> 6, lane = threadIdx.x & 63;
  const int l15 = lane & 15, l4 = lane >> 4;
  const int q0 = qt * 64 + wave * 16;
  const float CE = 0.125f * 1.44269504f;  // 1/sqrt(64) * log2(e)

  __shared__ __align__(16) u16 lK[2][4096];  // [buf][64 x 64], XOR-swizzled
  __shared__ __align__(16) u16 lV[2][4096];

  const size_t qoff = (size_t)(b * S + q0 + l15) * QSTR + h * 64;
  const s16x8 qa0 = *(const s16x8*)&QKV[qoff + l4 * 8];
  const s16x8 qa1 = *(const s16x8*)&QKV[qoff + 32 + l4 * 8];

  f32x4 o[4] = {};
  float mr = -1e30f, lr = 0.0f;
  const u8* mb = mask + (size_t)b * S * S;
  const u8* msb = msum + (size_t)(b * 32 + qt) * 32;
  const u16* vbase = VT + (size_t)bh * 64 * S;
  const int bS = b * S;

  auto stage = [&](int bi, int kvv) {
#pragma unroll
    for (int c = 0; c < 2; ++c) {
      const int byt = ((c * 4 + wave) * 64 + lane) * 16;
      const int row = byt >> 7;
      const int cb = (byt & 127) ^ ((row & 7) << 4);
      GLDS16(QKV + (size_t)(bS + kvv + row) * QSTR + 1024 + h * 64 + (cb >> 1),
             &lK[bi][(c * 4 + wave) * 512]);
      GLDS16(vbase + (size_t)row * S + kvv + (cb >> 1),
             &lV[bi][(c * 4 + wave) * 512]);
    }
  };

  auto body = [&](int bi, int kvv) {
    if (kvv + 64 < S) stage(bi ^ 1, kvv + 64);
    const char* kbuf = (const char*)&lK[bi][0];
    const char* vbuf = (const char*)&lV[bi][0];

    f32x4 sc[4];
    __builtin_amdgcn_s_setprio(1);
#pragma unroll
    for (int t = 0; t < 4; ++t) {
      const int row = t * 16 + l15;
      const int sw = (row & 7) << 4;
      const s16x8 kf0 = *(const s16x8*)(kbuf + row * 128 + ((l4 * 16) ^ sw));
      const s16x8 kf1 = *(const s16x8*)(kbuf + row * 128 + ((64 + l4 * 16) ^ sw));
      f32x4 z = {};
      z = __builtin_amdgcn_mfma_f32_16x16x32_bf16(kf0, qa0, z, 0, 0, 0);
      z = __builtin_amdgcn_mfma_f32_16x16x32_bf16(kf1, qa1, z, 0, 0, 0);
      sc[t] = z;
    }
    __builtin_amdgcn_s_setprio(0);
    if (msb[kvv >> 6]) {
#pragma unroll
      for (int t = 0; t < 4; ++t) {
        const uchar4 m4 = *(const uchar4*)&mb[(size_t)(q0 + l15) * S + kvv + t * 16 + l4 * 4];
        if (m4.x) sc[t][0] = -1e30f;
        if (m4.y) sc[t][1] = -1e30f;
        if (m4.z) sc[t][2] = -1e30f;
        if (m4.w) sc[t][3] = -1e30f;
      }
    }
    float pm = max3f(sc[0][0], sc[0][1], sc[0][2]);
    pm = max3f(pm, sc[0][3], sc[1][0]);
    pm = max3f(pm, sc[1][1], sc[1][2]);
    pm = max3f(pm, sc[1][3], sc[2][0]);
    pm = max3f(pm, sc[2][1], sc[2][2]);
    pm = max3f(pm, sc[2][3], sc[3][0]);
    pm = max3f(pm, sc[3][1], sc[3][2]);
    pm = fmaxf(pm, sc[3][3]);
    pm = fmaxf(pm, __shfl_xor(pm, 16));
    pm = fmaxf(pm, __shfl_xor(pm, 32));
    if (!__all(pm <= mr + 44.0f)) {  // 44 raw = 8 exp2-units
      const float mn = fmaxf(mr, pm);
      const float al = exp2f((mr - mn) * CE);
      mr = mn;
      lr *= al;
#pragma unroll
      for (int n = 0; n < 4; ++n)
#pragma unroll
        for (int j = 0; j < 4; ++j) o[n][j] *= al;
    }
    const float mrc = mr * CE;
    float rsum = 0.0f;
#pragma unroll
    for (int t = 0; t < 4; ++t)
#pragma unroll
      for (int j = 0; j < 4; ++j) {
        const float p = exp2f(fmaf(sc[t][j], CE, -mrc));
        sc[t][j] = p;
        rsum += p;
      }
    rsum += __shfl_xor(rsum, 16);
    rsum += __shfl_xor(rsum, 32);
    lr += rsum;
    s16x4 pb[4];
#pragma unroll
    for (int t = 0; t < 4; ++t) {
      const u32 lo = cvtpk_bf16(sc[t][0], sc[t][1]);
      const u32 hi = cvtpk_bf16(sc[t][2], sc[t][3]);
      pb[t] = __builtin_bit_cast(s16x4, u32x2{lo, hi});
    }
    __builtin_amdgcn_s_setprio(1);
#pragma unroll
    for (int n = 0; n < 4; ++n) {
      const int row = n * 16 + l15;
      const int sw = (row & 7) << 4;
#pragma unroll
      for (int t = 0; t < 4; ++t) {
        const s16x4 va = *(const s16x4*)(vbuf + row * 128 + ((t * 32 + l4 * 8) ^ sw));
        o[n] = __builtin_amdgcn_mfma_f32_16x16x16bf16_1k(va, pb[t], o[n], 0, 0, 0);
      }
    }
    __builtin_amdgcn_s_setprio(0);
    __syncthreads();
  };

  stage(0, 0);
  __syncthreads();
  for (int kv = 0; kv < S; kv += 128) {
    body(0, kv);
    body(1, kv + 64);
  }
  const float inv = lr > 0.0f ? 1.0f / lr : 0.0f;
  const size_t obase = (size_t)(b * S + q0 + l15) * Dm + h * 64;
#pragma unroll
  for (int n = 0; n < 4; ++n) {
    const u32 lo = cvtpk_bf16(o[n][0] * inv, o[n][1] * inv);
    const u32 hi = cvtpk_bf16(o[n][2] * inv, o[n][3] * inv);
    *(u32x2*)&out[obase + n * 16 + l4 * 4] = u32x2{lo, hi};
  }
}

extern "C" void kernel_launch(void* const* d_in, const int* in_sizes, int n_in,
                              void* d_out, int out_size, void* d_ws, size_t ws_size,
                              hipStream_t stream) {
  (void)in_sizes; (void)n_in; (void)out_size; (void)ws_size;
  const float* x = (const float*)d_in[0];
  const u8* mask = (const u8*)d_in[1];
  const float* Wq = (const float*)d_in[2];
  const float* Wk = (const float*)d_in[3];
  const float* Wv = (const float*)d_in[4];
  const float* Wo = (const float*)d_in[5];
  const float* bo = (const float*)d_in[6];
  const float* W1 = (const float*)d_in[7];
  const float* b1 = (const float*)d_in[8];
  const float* W2 = (const float*)d_in[9];
  const float* b2 = (const float*)d_in[10];
  const float* g1 = (const float*)d_in[11];
  const float* be1 = (const float*)d_in[12];
  const float* g2 = (const float*)d_in[13];
  const float* be2 = (const float*)d_in[14];
  float* outp = (float*)d_out;

  const int B = 2, S = 2048, D = 1024, FF = 4096;
  const int M = B * S;  // 4096
  char* w = (char*)d_ws;
  const size_t MB = 1024 * 1024;
  u16* wqkvT = (u16*)(w + 0 * MB);    // [3072,1024] bf16   [0,6)
  u16* woT = (u16*)(w + 6 * MB);      // [1024,1024]        [6,8)
  u16* w1T = (u16*)(w + 8 * MB);      // [4096,1024]        [8,16)
  u16* w2T = (u16*)(w + 16 * MB);     // [1024,4096]        [16,24)
  u16* xb  = (u16*)(w + 24 * MB);     // [4096,1024]        [24,32)
  u16* qkv = (u16*)(w + 32 * MB);     // [4096,3072]        [32,56)
  u16* vt  = (u16*)(w + 56 * MB);     // [B*H,64,S]         [56,64)
  float* x0f = (float*)(w + 64 * MB); // [4096,1024] f32    [64,80)
  float* x1f = (float*)(w + 80 * MB); //                    [80,96)
  u16* x1b = (u16*)(w + 96 * MB);     // [4096,1024] bf16   [96,104)
  u8* msum = (u8*)(w + 64 * MB);      // 2 KB, dead before x0f is written
  u16* attn_o = xb;                   // xb dead after QKV gemm
  u16* ff1 = (u16*)(w + 32 * MB);     // [4096,4096] bf16, reuses qkv+vt [32,64)
  float* y0f = x0f;

  // weight prep (Wq/Wk/Wv transposed into one contiguous [3072,1024] block)
  transpose_f32_bf16<<<dim3(32, 32), 256, 0, stream>>>(Wq, wqkvT, 1024, 1024);
  transpose_f32_bf16<<<dim3(32, 32), 256, 0, stream>>>(Wk, wqkvT + 1024 * 1024, 1024, 1024);
  transpose_f32_bf16<<<dim3(32, 32), 256, 0, stream>>>(Wv, wqkvT + 2048 * 1024, 1024, 1024);
  transpose_f32_bf16<<<dim3(32, 32), 256, 0, stream>>>(Wo, woT, 1024, 1024);
  transpose_f32_bf16<<<dim3(128, 32), 256, 0, stream>>>(W1, w1T, 1024, 4096);
  transpose_f32_bf16<<<dim3(32, 128), 256, 0, stream>>>(W2, w2T, 4096, 1024);
  cvt_f32_bf16<<<dim3(M * D / 4 / 256), 256, 0, stream>>>(x, xb, M * D / 4);
  mask_summary<<<dim3(32, 32, 2), 256, 0, stream>>>(mask, msum);

  // fused QKV projection (proven 2-phase 128-tile)
  gemm_bt<0, 128><<<dim3(3 * D / 128, M / 128), 256, 0, stream>>>(xb, wqkvT, M, 3 * D, D, nullptr, nullptr, qkv, nullptr);
  // V -> V^T per batch (strided read from qkv cols 2048..3071)
  transpose_bf16_b<<<dim3(32, 64, 2), 256, 0, stream>>>(qkv, vt, 2048, 1024, 3072, 2048);

  // attention: R11-proven body, 1024 blocks
  attn_k<<<dim3(1024), 256, 0, stream>>>(qkv, vt, mask, msum, attn_o);

  // Wo projection + bias + residual(x) -- proven 2-phase BM=64
  gemm_bt<2, 64><<<dim3(D / 128, M / 64), 256, 0, stream>>>(attn_o, woT, M, D, D, bo, x, nullptr, x0f);
  layernorm_k<1><<<dim3(M), 256, 0, stream>>>(x0f, g1, be1, x1f, x1b);
  // FFN1 (proven 2-phase 128-tile)
  gemm_bt<1, 128><<<dim3(FF / 128, M / 128), 256, 0, stream>>>(x1b, w1T, M, FF, D, b1, nullptr, ff1, nullptr);
  gemm_bt<2, 64><<<dim3(D / 128, M / 64), 256, 0, stream>>>(ff1, w2T, M, D, FF, b2, x1f, nullptr, y0f);
  layernorm_k<0><<<dim3(M), 256, 0, stream>>>(y0f, g2, be2, outp, nullptr);
}

// Round 14
// 279.048 us; speedup vs baseline: 1.1353x; 1.0235x over previous
//
#include <hip/hip_runtime.h>
#include <math.h>

typedef unsigned short u16;
typedef unsigned char u8;
typedef unsigned int u32;
typedef __attribute__((ext_vector_type(4))) float f32x4;
typedef __attribute__((ext_vector_type(8))) short s16x8;
typedef __attribute__((ext_vector_type(4))) short s16x4;
typedef __attribute__((ext_vector_type(4))) u32 u32x4;
typedef __attribute__((ext_vector_type(2))) u32 u32x2;

__device__ __forceinline__ u16 f2bf(float f) {
  unsigned u = __builtin_bit_cast(unsigned, f);
  u += 0x7fffu + ((u >> 16) & 1u);
  return (u16)(u >> 16);
}

__device__ __forceinline__ u32 cvtpk_bf16(float lo, float hi) {
  u32 r;
  asm("v_cvt_pk_bf16_f32 %0, %1, %2" : "=v"(r) : "v"(lo), "v"(hi));
  return r;
}

__device__ __forceinline__ float max3f(float a, float b, float c) {
  return fmaxf(fmaxf(a, b), c);  // fuses to v_max3_f32
}

#define GLDS16(g, l) __builtin_amdgcn_global_load_lds( \
    (const __attribute__((address_space(1))) void*)(g), \
    (__attribute__((address_space(3))) void*)(l), 16, 0, 0)

// ---------------- GEMM 2-phase (proven): C = A @ BT^T, BM x 128 tile ----------------
// XCD-aware block swizzle (all launched grids %8==0 -> bijective).
template <int EPI, int BM>
__global__ __launch_bounds__(256, 2) void gemm_bt(
    const u16* __restrict__ A, const u16* __restrict__ BT, int M, int N, int K,
    const float* __restrict__ bias, const float* __restrict__ resid,
    u16* __restrict__ outB, float* __restrict__ outF) {
  constexpr int MT = BM / 32;
  __shared__ __align__(16) u16 lA[2][BM * 32];
  __shared__ __align__(16) u16 lB[2][128 * 32];
  const int tid = threadIdx.x;
  const int wave = __builtin_amdgcn_readfirstlane(tid >> 6);
  const int lane = tid & 63;
  const int l15 = lane & 15, l4 = lane >> 4;
  const int wr = wave >> 1, wc = wave & 1;
  const int nwg = gridDim.x * gridDim.y;
  int wg = blockIdx.y * gridDim.x + blockIdx.x;
  wg = (wg & 7) * (nwg >> 3) + (wg >> 3);  // XCD swizzle (bijective: nwg%8==0)
  const int bx = wg % gridDim.x, by = wg / gridDim.x;
  const int row0 = by * BM, col0 = bx * 128;

  f32x4 acc[MT][4] = {};

  auto stage = [&](int bi, int k0) {
#pragma unroll
    for (int c = 0; c < BM / 64; ++c) {
      const int chunk = c * 4 + wave;
      const int idx = chunk * 64 + lane;
      const int r = idx >> 2, cb = (idx & 3) * 8;
      GLDS16(A + (size_t)(row0 + r) * K + k0 + cb, &lA[bi][chunk * 512]);
    }
#pragma unroll
    for (int c = 0; c < 2; ++c) {
      const int chunk = c * 4 + wave;
      const int idx = chunk * 64 + lane;
      const int r = idx >> 2, cb = (idx & 3) * 8;
      GLDS16(BT + (size_t)(col0 + r) * K + k0 + cb, &lB[bi][chunk * 512]);
    }
  };

  stage(0, 0);
  __syncthreads();
  int buf = 0;

  for (int k0 = 0; k0 < K; k0 += 32) {
    if (k0 + 32 < K) stage(buf ^ 1, k0 + 32);
    s16x8 af[MT], bfr[4];
#pragma unroll
    for (int m = 0; m < MT; ++m)
      af[m] = *(const s16x8*)&lA[buf][(wr * (BM / 2) + m * 16 + l15) * 32 + l4 * 8];
#pragma unroll
    for (int n = 0; n < 4; ++n)
      bfr[n] = *(const s16x8*)&lB[buf][(wc * 64 + n * 16 + l15) * 32 + l4 * 8];
#pragma unroll
    for (int m = 0; m < MT; ++m)
#pragma unroll
      for (int n = 0; n < 4; ++n)
        acc[m][n] = __builtin_amdgcn_mfma_f32_16x16x32_bf16(af[m], bfr[n], acc[m][n], 0, 0, 0);
    __syncthreads();
    buf ^= 1;
  }

#pragma unroll
  for (int m = 0; m < MT; ++m) {
    const int rowb = row0 + wr * (BM / 2) + m * 16 + l4 * 4;
#pragma unroll
    for (int n = 0; n < 4; ++n) {
      const int col = col0 + wc * 64 + n * 16 + l15;
#pragma unroll
      for (int j = 0; j < 4; ++j) {
        const int r = rowb + j;
        float v = acc[m][n][j];
        if (EPI == 0) {
          outB[(size_t)r * N + col] = f2bf(v);
        } else if (EPI == 1) {
          v += bias[col];
          outB[(size_t)r * N + col] = f2bf(v > 0.0f ? v : 0.0f);
        } else {
          v += bias[col] + resid[(size_t)r * N + col];
          outF[(size_t)r * N + col] = v;
        }
      }
    }
  }
}

// ---------------- batched weight transpose f32 -> bf16: 4x [1024,1024] ----------------
// z selects source; z<3 -> wqkvT block z, z==3 -> woT.
__global__ __launch_bounds__(256) void transpose4_f32_bf16(
    const float* __restrict__ s0, const float* __restrict__ s1,
    const float* __restrict__ s2, const float* __restrict__ s3,
    u16* __restrict__ dqkv, u16* __restrict__ dwo) {
  __shared__ float t[32][33];
  const int z = blockIdx.z;
  const float* in = (z == 0) ? s0 : (z == 1) ? s1 : (z == 2) ? s2 : s3;
  u16* out = (z < 3) ? (dqkv + (size_t)z * 1024 * 1024) : dwo;
  const int c0 = blockIdx.x * 32, r0 = blockIdx.y * 32;
  const int tx = threadIdx.x & 31, ty = threadIdx.x >> 5;
#pragma unroll
  for (int i = 0; i < 4; ++i)
    t[ty + i * 8][tx] = in[(size_t)(r0 + ty + i * 8) * 1024 + c0 + tx];
  __syncthreads();
#pragma unroll
  for (int i = 0; i < 4; ++i)
    out[(size_t)(c0 + ty + i * 8) * 1024 + r0 + tx] = f2bf(t[tx][ty + i * 8]);
}

// ---------------- weight transpose f32 -> bf16 ----------------
__global__ __launch_bounds__(256) void transpose_f32_bf16(
    const float* __restrict__ in, u16* __restrict__ out, int R, int C) {
  __shared__ float t[32][33];
  const int c0 = blockIdx.x * 32, r0 = blockIdx.y * 32;
  const int tx = threadIdx.x & 31, ty = threadIdx.x >> 5;
#pragma unroll
  for (int i = 0; i < 4; ++i)
    t[ty + i * 8][tx] = in[(size_t)(r0 + ty + i * 8) * C + c0 + tx];
  __syncthreads();
#pragma unroll
  for (int i = 0; i < 4; ++i)
    out[(size_t)(c0 + ty + i * 8) * R + r0 + tx] = f2bf(t[tx][ty + i * 8]);
}

// ---------------- batched bf16 transpose (strided input, col-offset) ----------------
__global__ __launch_bounds__(256) void transpose_bf16_b(
    const u16* __restrict__ in, u16* __restrict__ out, int R, int C, int rstr, int coff) {
  __shared__ u16 t[32][34];
  const int b = blockIdx.z;
  const u16* pi = in + (size_t)b * R * rstr + coff;
  u16* po = out + (size_t)b * R * C;
  const int c0 = blockIdx.x * 32, r0 = blockIdx.y * 32;
  const int tx = threadIdx.x & 31, ty = threadIdx.x >> 5;
#pragma unroll
  for (int i = 0; i < 4; ++i)
    t[ty + i * 8][tx] = pi[(size_t)(r0 + ty + i * 8) * rstr + c0 + tx];
  __syncthreads();
#pragma unroll
  for (int i = 0; i < 4; ++i)
    po[(size_t)(c0 + ty + i * 8) * R + r0 + tx] = t[tx][ty + i * 8];
}

// ---------------- f32 -> bf16 elementwise ----------------
__global__ __launch_bounds__(256) void cvt_f32_bf16(
    const float* __restrict__ in, u16* __restrict__ out, int n4) {
  const int i = blockIdx.x * 256 + threadIdx.x;
  if (i >= n4) return;
  f32x4 v = *(const f32x4*)&in[(size_t)i * 4];
  s16x4 o;
#pragma unroll
  for (int j = 0; j < 4; ++j) o[j] = (short)f2bf(v[j]);
  *(s16x4*)&out[(size_t)i * 4] = o;
}

// ---------------- LayerNorm over D=1024 ----------------
template <int WB>
__global__ __launch_bounds__(256) void layernorm_k(
    const float* __restrict__ in, const float* __restrict__ gm, const float* __restrict__ bt,
    float* __restrict__ outF, u16* __restrict__ outB) {
  const int row = blockIdx.x;
  const int t = threadIdx.x;
  const float* xr = in + (size_t)row * 1024;
  f32x4 v = *(const f32x4*)&xr[t * 4];
  float s = v[0] + v[1] + v[2] + v[3];
  float s2 = v[0] * v[0] + v[1] * v[1] + v[2] * v[2] + v[3] * v[3];
#pragma unroll
  for (int o = 32; o; o >>= 1) {
    s += __shfl_down(s, o);
    s2 += __shfl_down(s2, o);
  }
  __shared__ float red[8];
  const int lane = t & 63, wv = t >> 6;
  if (lane == 0) { red[wv] = s; red[4 + wv] = s2; }
  __syncthreads();
  s = red[0] + red[1] + red[2] + red[3];
  s2 = red[4] + red[5] + red[6] + red[7];
  const float mu = s * (1.0f / 1024.0f);
  const float var = fmaxf(s2 * (1.0f / 1024.0f) - mu * mu, 0.0f);
  const float rs = rsqrtf(var + 1e-5f);
  f32x4 g4 = *(const f32x4*)&gm[t * 4];
  f32x4 b4 = *(const f32x4*)&bt[t * 4];
  f32x4 ov;
#pragma unroll
  for (int j = 0; j < 4; ++j) ov[j] = (v[j] - mu) * rs * g4[j] + b4[j];
  *(f32x4*)&outF[(size_t)row * 1024 + t * 4] = ov;
  if (WB) {
    s16x4 ob;
#pragma unroll
    for (int j = 0; j < 4; ++j) ob[j] = (short)f2bf(ov[j]);
    *(s16x4*)&outB[(size_t)row * 1024 + t * 4] = ob;
  }
}

// ---------------- mask tile summary: any() over 64x64 tiles ----------------
__global__ __launch_bounds__(256) void mask_summary(
    const u8* __restrict__ mask, u8* __restrict__ msum) {
  const int kt = blockIdx.x, qt = blockIdx.y, b = blockIdx.z;
  const int tid = threadIdx.x;
  __shared__ int any_flag;
  if (tid == 0) any_flag = 0;
  __syncthreads();
  const u8* base = mask + ((size_t)(b * 2048 + qt * 64 + (tid >> 2))) * 2048 + kt * 64 + (tid & 3) * 16;
  const u32x4 v = *(const u32x4*)base;
  if (v[0] | v[1] | v[2] | v[3]) any_flag = 1;
  __syncthreads();
  if (tid == 0) msum[((size_t)b * 32 + qt) * 32 + kt] = (u8)any_flag;
}

// ---------------- flash attention: R11/R13 body (96us best-measured) ----------------
__global__ __launch_bounds__(256) void attn_k(
    const u16* __restrict__ QKV, const u16* __restrict__ VT,
    const u8* __restrict__ mask, const u8* __restrict__ msum, u16* __restrict__ out) {
  const int S = 2048, QSTR = 3072, Dm = 1024;
  const int wgid = blockIdx.x;  // 0..1023
  const int xcd = wgid & 7, slot = wgid >> 3;
  const int bh = xcd * 4 + (slot >> 5);  // 4 bh per XCD -> 2MB KV L2-resident
  const int qt = slot & 31;
  const int b = bh >> 4, h = bh & 15;
  const int wave = threadIdx.x >> 6, lane = threadIdx.x & 63;
  const int l15 = lane & 15, l4 = lane >> 4;
  const int q0 = qt * 64 + wave * 16;
  const float CE = 0.125f * 1.44269504f;  // 1/sqrt(64) * log2(e)

  __shared__ __align__(16) u16 lK[2][4096];  // [buf][64 x 64], XOR-swizzled
  __shared__ __align__(16) u16 lV[2][4096];

  const size_t qoff = (size_t)(b * S + q0 + l15) * QSTR + h * 64;
  const s16x8 qa0 = *(const s16x8*)&QKV[qoff + l4 * 8];
  const s16x8 qa1 = *(const s16x8*)&QKV[qoff + 32 + l4 * 8];

  f32x4 o[4] = {};
  float mr = -1e30f, lr = 0.0f;
  const u8* mb = mask + (size_t)b * S * S;
  const u8* msb = msum + (size_t)(b * 32 + qt) * 32;
  const u16* vbase = VT + (size_t)bh * 64 * S;
  const int bS = b * S;

  auto stage = [&](int bi, int kvv) {
#pragma unroll
    for (int c = 0; c < 2; ++c) {
      const int byt = ((c * 4 + wave) * 64 + lane) * 16;
      const int row = byt >> 7;
      const int cb = (byt & 127) ^ ((row & 7) << 4);
      GLDS16(QKV + (size_t)(bS + kvv + row) * QSTR + 1024 + h * 64 + (cb >> 1),
             &lK[bi][(c * 4 + wave) * 512]);
      GLDS16(vbase + (size_t)row * S + kvv + (cb >> 1),
             &lV[bi][(c * 4 + wave) * 512]);
    }
  };

  auto body = [&](int bi, int kvv) {
    if (kvv + 64 < S) stage(bi ^ 1, kvv + 64);
    const char* kbuf = (const char*)&lK[bi][0];
    const char* vbuf = (const char*)&lV[bi][0];

    f32x4 sc[4];
    __builtin_amdgcn_s_setprio(1);
#pragma unroll
    for (int t = 0; t < 4; ++t) {
      const int row = t * 16 + l15;
      const int sw = (row & 7) << 4;
      const s16x8 kf0 = *(const s16x8*)(kbuf + row * 128 + ((l4 * 16) ^ sw));
      const s16x8 kf1 = *(const s16x8*)(kbuf + row * 128 + ((64 + l4 * 16) ^ sw));
      f32x4 z = {};
      z = __builtin_amdgcn_mfma_f32_16x16x32_bf16(kf0, qa0, z, 0, 0, 0);
      z = __builtin_amdgcn_mfma_f32_16x16x32_bf16(kf1, qa1, z, 0, 0, 0);
      sc[t] = z;
    }
    __builtin_amdgcn_s_setprio(0);
    if (msb[kvv >> 6]) {
#pragma unroll
      for (int t = 0; t < 4; ++t) {
        const uchar4 m4 = *(const uchar4*)&mb[(size_t)(q0 + l15) * S + kvv + t * 16 + l4 * 4];
        if (m4.x) sc[t][0] = -1e30f;
        if (m4.y) sc[t][1] = -1e30f;
        if (m4.z) sc[t][2] = -1e30f;
        if (m4.w) sc[t][3] = -1e30f;
      }
    }
    float pm = max3f(sc[0][0], sc[0][1], sc[0][2]);
    pm = max3f(pm, sc[0][3], sc[1][0]);
    pm = max3f(pm, sc[1][1], sc[1][2]);
    pm = max3f(pm, sc[1][3], sc[2][0]);
    pm = max3f(pm, sc[2][1], sc[2][2]);
    pm = max3f(pm, sc[2][3], sc[3][0]);
    pm = max3f(pm, sc[3][1], sc[3][2]);
    pm = fmaxf(pm, sc[3][3]);
    pm = fmaxf(pm, __shfl_xor(pm, 16));
    pm = fmaxf(pm, __shfl_xor(pm, 32));
    if (!__all(pm <= mr + 44.0f)) {  // 44 raw = 8 exp2-units
      const float mn = fmaxf(mr, pm);
      const float al = exp2f((mr - mn) * CE);
      mr = mn;
      lr *= al;
#pragma unroll
      for (int n = 0; n < 4; ++n)
#pragma unroll
        for (int j = 0; j < 4; ++j) o[n][j] *= al;
    }
    const float mrc = mr * CE;
    float rsum = 0.0f;
#pragma unroll
    for (int t = 0; t < 4; ++t)
#pragma unroll
      for (int j = 0; j < 4; ++j) {
        const float p = exp2f(fmaf(sc[t][j], CE, -mrc));
        sc[t][j] = p;
        rsum += p;
      }
    rsum += __shfl_xor(rsum, 16);
    rsum += __shfl_xor(rsum, 32);
    lr += rsum;
    s16x4 pb[4];
#pragma unroll
    for (int t = 0; t < 4; ++t) {
      const u32 lo = cvtpk_bf16(sc[t][0], sc[t][1]);
      const u32 hi = cvtpk_bf16(sc[t][2], sc[t][3]);
      pb[t] = __builtin_bit_cast(s16x4, u32x2{lo, hi});
    }
    __builtin_amdgcn_s_setprio(1);
#pragma unroll
    for (int n = 0; n < 4; ++n) {
      const int row = n * 16 + l15;
      const int sw = (row & 7) << 4;
#pragma unroll
      for (int t = 0; t < 4; ++t) {
        const s16x4 va = *(const s16x4*)(vbuf + row * 128 + ((t * 32 + l4 * 8) ^ sw));
        o[n] = __builtin_amdgcn_mfma_f32_16x16x16bf16_1k(va, pb[t], o[n], 0, 0, 0);
      }
    }
    __builtin_amdgcn_s_setprio(0);
    __syncthreads();
  };

  stage(0, 0);
  __syncthreads();
  for (int kv = 0; kv < S; kv += 128) {
    body(0, kv);
    body(1, kv + 64);
  }
  const float inv = lr > 0.0f ? 1.0f / lr : 0.0f;
  const size_t obase = (size_t)(b * S + q0 + l15) * Dm + h * 64;
#pragma unroll
  for (int n = 0; n < 4; ++n) {
    const u32 lo = cvtpk_bf16(o[n][0] * inv, o[n][1] * inv);
    const u32 hi = cvtpk_bf16(o[n][2] * inv, o[n][3] * inv);
    *(u32x2*)&out[obase + n * 16 + l4 * 4] = u32x2{lo, hi};
  }
}

extern "C" void kernel_launch(void* const* d_in, const int* in_sizes, int n_in,
                              void* d_out, int out_size, void* d_ws, size_t ws_size,
                              hipStream_t stream) {
  (void)in_sizes; (void)n_in; (void)out_size; (void)ws_size;
  const float* x = (const float*)d_in[0];
  const u8* mask = (const u8*)d_in[1];
  const float* Wq = (const float*)d_in[2];
  const float* Wk = (const float*)d_in[3];
  const float* Wv = (const float*)d_in[4];
  const float* Wo = (const float*)d_in[5];
  const float* bo = (const float*)d_in[6];
  const float* W1 = (const float*)d_in[7];
  const float* b1 = (const float*)d_in[8];
  const float* W2 = (const float*)d_in[9];
  const float* b2 = (const float*)d_in[10];
  const float* g1 = (const float*)d_in[11];
  const float* be1 = (const float*)d_in[12];
  const float* g2 = (const float*)d_in[13];
  const float* be2 = (const float*)d_in[14];
  float* outp = (float*)d_out;

  const int B = 2, S = 2048, D = 1024, FF = 4096;
  const int M = B * S;  // 4096
  char* w = (char*)d_ws;
  const size_t MB = 1024 * 1024;
  u16* wqkvT = (u16*)(w + 0 * MB);    // [3072,1024] bf16   [0,6)
  u16* woT = (u16*)(w + 6 * MB);      // [1024,1024]        [6,8)
  u16* w1T = (u16*)(w + 8 * MB);      // [4096,1024]        [8,16)
  u16* w2T = (u16*)(w + 16 * MB);     // [1024,4096]        [16,24)
  u16* xb  = (u16*)(w + 24 * MB);     // [4096,1024]        [24,32)
  u16* qkv = (u16*)(w + 32 * MB);     // [4096,3072]        [32,56)
  u16* vt  = (u16*)(w + 56 * MB);     // [B*H,64,S]         [56,64)
  float* x0f = (float*)(w + 64 * MB); // [4096,1024] f32    [64,80)
  float* x1f = (float*)(w + 80 * MB); //                    [80,96)
  u16* x1b = (u16*)(w + 96 * MB);     // [4096,1024] bf16   [96,104)
  u8* msum = (u8*)(w + 64 * MB);      // 2 KB, dead before x0f is written
  u16* attn_o = xb;                   // xb dead after QKV gemm
  u16* ff1 = (u16*)(w + 32 * MB);     // [4096,4096] bf16, reuses qkv+vt [32,64)
  float* y0f = x0f;

  // weight prep: 4 [1024,1024] transposes batched into ONE dispatch
  transpose4_f32_bf16<<<dim3(32, 32, 4), 256, 0, stream>>>(Wq, Wk, Wv, Wo, wqkvT, woT);
  transpose_f32_bf16<<<dim3(128, 32), 256, 0, stream>>>(W1, w1T, 1024, 4096);
  transpose_f32_bf16<<<dim3(32, 128), 256, 0, stream>>>(W2, w2T, 4096, 1024);
  cvt_f32_bf16<<<dim3(M * D / 4 / 256), 256, 0, stream>>>(x, xb, M * D / 4);
  mask_summary<<<dim3(32, 32, 2), 256, 0, stream>>>(mask, msum);

  // fused QKV projection (proven 2-phase 128-tile)
  gemm_bt<0, 128><<<dim3(3 * D / 128, M / 128), 256, 0, stream>>>(xb, wqkvT, M, 3 * D, D, nullptr, nullptr, qkv, nullptr);
  // V -> V^T per batch (strided read from qkv cols 2048..3071)
  transpose_bf16_b<<<dim3(32, 64, 2), 256, 0, stream>>>(qkv, vt, 2048, 1024, 3072, 2048);

  // attention: R11-proven body, 1024 blocks
  attn_k<<<dim3(1024), 256, 0, stream>>>(qkv, vt, mask, msum, attn_o);

  // Wo projection + bias + residual(x) -- proven 2-phase BM=64
  gemm_bt<2, 64><<<dim3(D / 128, M / 64), 256, 0, stream>>>(attn_o, woT, M, D, D, bo, x, nullptr, x0f);
  layernorm_k<1><<<dim3(M), 256, 0, stream>>>(x0f, g1, be1, x1f, x1b);
  // FFN1 (proven 2-phase 128-tile)
  gemm_bt<1, 128><<<dim3(FF / 128, M / 128), 256, 0, stream>>>(x1b, w1T, M, FF, D, b1, nullptr, ff1, nullptr);
  gemm_bt<2, 64><<<dim3(D / 128, M / 64), 256, 0, stream>>>(ff1, w2T, M, D, FF, b2, x1f, nullptr, y0f);
  layernorm_k<0><<<dim3(M), 256, 0, stream>>>(y0f, g2, be2, outp, nullptr);
}

// Round 15
// 271.584 us; speedup vs baseline: 1.1665x; 1.0275x over previous
//
#include <hip/hip_runtime.h>
#include <math.h>

typedef unsigned short u16;
typedef unsigned char u8;
typedef unsigned int u32;
typedef __attribute__((ext_vector_type(4))) float f32x4;
typedef __attribute__((ext_vector_type(8))) short s16x8;
typedef __attribute__((ext_vector_type(4))) short s16x4;
typedef __attribute__((ext_vector_type(4))) u32 u32x4;
typedef __attribute__((ext_vector_type(2))) u32 u32x2;

__device__ __forceinline__ u16 f2bf(float f) {
  unsigned u = __builtin_bit_cast(unsigned, f);
  u += 0x7fffu + ((u >> 16) & 1u);
  return (u16)(u >> 16);
}

__device__ __forceinline__ u32 cvtpk_bf16(float lo, float hi) {
  u32 r;
  asm("v_cvt_pk_bf16_f32 %0, %1, %2" : "=v"(r) : "v"(lo), "v"(hi));
  return r;
}

__device__ __forceinline__ float max3f(float a, float b, float c) {
  return fmaxf(fmaxf(a, b), c);  // fuses to v_max3_f32
}

#define GLDS16(g, l) __builtin_amdgcn_global_load_lds( \
    (const __attribute__((address_space(1))) void*)(g), \
    (__attribute__((address_space(3))) void*)(l), 16, 0, 0)

// ---------------- GEMM 2-phase, BK=64, XOR-swizzled LDS (R11-proven math) ----------
// Same proven sync structure as BK=32 version (stage(next) -> compute -> barrier),
// but half the barrier pairs per unit K (m233: stage+bar is ~72% of 2-phase path).
// Rows are 128B so LDS is XOR-swizzled: pre-swizzled global source (rule #21) +
// swizzled ds_read_b128 -> 2-way bank aliasing (free, m136). 64KB LDS @BM=128 ->
// still 2 blocks/CU. XCD-aware block swizzle (all grids %8==0 -> bijective).
template <int EPI, int BM>
__global__ __launch_bounds__(256, 2) void gemm_bt(
    const u16* __restrict__ A, const u16* __restrict__ BT, int M, int N, int K,
    const float* __restrict__ bias, const float* __restrict__ resid,
    u16* __restrict__ outB, float* __restrict__ outF) {
  constexpr int MT = BM / 32;
  __shared__ __align__(16) u16 lA[2][BM * 64];
  __shared__ __align__(16) u16 lB[2][128 * 64];
  const int tid = threadIdx.x;
  const int wave = __builtin_amdgcn_readfirstlane(tid >> 6);
  const int lane = tid & 63;
  const int l15 = lane & 15, l4 = lane >> 4;
  const int wr = wave >> 1, wc = wave & 1;
  const int nwg = gridDim.x * gridDim.y;
  int wg = blockIdx.y * gridDim.x + blockIdx.x;
  wg = (wg & 7) * (nwg >> 3) + (wg >> 3);  // XCD swizzle (bijective: nwg%8==0)
  const int bx = wg % gridDim.x, by = wg / gridDim.x;
  const int row0 = by * BM, col0 = bx * 128;

  f32x4 acc[MT][4] = {};

  // stage one BK=64 K-tile; LDS dest linear (wave-uniform base + lane*16),
  // global source pre-swizzled with cb ^= (row&7)<<4 (byte addressing).
  auto stage = [&](int bi, int k0) {
#pragma unroll
    for (int c = 0; c < BM / 32; ++c) {  // A: BM rows x 128B
      const int byt = ((c * 4 + wave) * 64 + lane) * 16;
      const int row = byt >> 7;
      const int cb = (byt & 127) ^ ((row & 7) << 4);
      GLDS16(A + (size_t)(row0 + row) * K + k0 + (cb >> 1), &lA[bi][(c * 4 + wave) * 512]);
    }
#pragma unroll
    for (int c = 0; c < 4; ++c) {  // B: 128 rows x 128B
      const int byt = ((c * 4 + wave) * 64 + lane) * 16;
      const int row = byt >> 7;
      const int cb = (byt & 127) ^ ((row & 7) << 4);
      GLDS16(BT + (size_t)(col0 + row) * K + k0 + (cb >> 1), &lB[bi][(c * 4 + wave) * 512]);
    }
  };

  stage(0, 0);
  __syncthreads();
  int buf = 0;

  for (int k0 = 0; k0 < K; k0 += 64) {
    if (k0 + 64 < K) stage(buf ^ 1, k0 + 64);  // async prefetch; drained at loop-end barrier
    const char* bufA = (const char*)&lA[buf][0];
    const char* bufB = (const char*)&lB[buf][0];
#pragma unroll
    for (int s = 0; s < 2; ++s) {  // two K=32 sub-steps per tile
      s16x8 af[MT], bfr[4];
#pragma unroll
      for (int m = 0; m < MT; ++m) {
        const int row = wr * (BM / 2) + m * 16 + l15;
        af[m] = *(const s16x8*)(bufA + row * 128 + ((s * 64 + l4 * 16) ^ ((row & 7) << 4)));
      }
#pragma unroll
      for (int n = 0; n < 4; ++n) {
        const int row = wc * 64 + n * 16 + l15;
        bfr[n] = *(const s16x8*)(bufB + row * 128 + ((s * 64 + l4 * 16) ^ ((row & 7) << 4)));
      }
#pragma unroll
      for (int m = 0; m < MT; ++m)
#pragma unroll
        for (int n = 0; n < 4; ++n)
          acc[m][n] = __builtin_amdgcn_mfma_f32_16x16x32_bf16(af[m], bfr[n], acc[m][n], 0, 0, 0);
    }
    __syncthreads();
    buf ^= 1;
  }

#pragma unroll
  for (int m = 0; m < MT; ++m) {
    const int rowb = row0 + wr * (BM / 2) + m * 16 + l4 * 4;
#pragma unroll
    for (int n = 0; n < 4; ++n) {
      const int col = col0 + wc * 64 + n * 16 + l15;
#pragma unroll
      for (int j = 0; j < 4; ++j) {
        const int r = rowb + j;
        float v = acc[m][n][j];
        if (EPI == 0) {
          outB[(size_t)r * N + col] = f2bf(v);
        } else if (EPI == 1) {
          v += bias[col];
          outB[(size_t)r * N + col] = f2bf(v > 0.0f ? v : 0.0f);
        } else {
          v += bias[col] + resid[(size_t)r * N + col];
          outF[(size_t)r * N + col] = v;
        }
      }
    }
  }
}

// ---------------- batched weight transpose f32 -> bf16: 4x [1024,1024] ----------------
__global__ __launch_bounds__(256) void transpose4_f32_bf16(
    const float* __restrict__ s0, const float* __restrict__ s1,
    const float* __restrict__ s2, const float* __restrict__ s3,
    u16* __restrict__ dqkv, u16* __restrict__ dwo) {
  __shared__ float t[32][33];
  const int z = blockIdx.z;
  const float* in = (z == 0) ? s0 : (z == 1) ? s1 : (z == 2) ? s2 : s3;
  u16* out = (z < 3) ? (dqkv + (size_t)z * 1024 * 1024) : dwo;
  const int c0 = blockIdx.x * 32, r0 = blockIdx.y * 32;
  const int tx = threadIdx.x & 31, ty = threadIdx.x >> 5;
#pragma unroll
  for (int i = 0; i < 4; ++i)
    t[ty + i * 8][tx] = in[(size_t)(r0 + ty + i * 8) * 1024 + c0 + tx];
  __syncthreads();
#pragma unroll
  for (int i = 0; i < 4; ++i)
    out[(size_t)(c0 + ty + i * 8) * 1024 + r0 + tx] = f2bf(t[tx][ty + i * 8]);
}

// ---------------- weight transpose f32 -> bf16 ----------------
__global__ __launch_bounds__(256) void transpose_f32_bf16(
    const float* __restrict__ in, u16* __restrict__ out, int R, int C) {
  __shared__ float t[32][33];
  const int c0 = blockIdx.x * 32, r0 = blockIdx.y * 32;
  const int tx = threadIdx.x & 31, ty = threadIdx.x >> 5;
#pragma unroll
  for (int i = 0; i < 4; ++i)
    t[ty + i * 8][tx] = in[(size_t)(r0 + ty + i * 8) * C + c0 + tx];
  __syncthreads();
#pragma unroll
  for (int i = 0; i < 4; ++i)
    out[(size_t)(c0 + ty + i * 8) * R + r0 + tx] = f2bf(t[tx][ty + i * 8]);
}

// ---------------- batched bf16 transpose (strided input, col-offset) ----------------
__global__ __launch_bounds__(256) void transpose_bf16_b(
    const u16* __restrict__ in, u16* __restrict__ out, int R, int C, int rstr, int coff) {
  __shared__ u16 t[32][34];
  const int b = blockIdx.z;
  const u16* pi = in + (size_t)b * R * rstr + coff;
  u16* po = out + (size_t)b * R * C;
  const int c0 = blockIdx.x * 32, r0 = blockIdx.y * 32;
  const int tx = threadIdx.x & 31, ty = threadIdx.x >> 5;
#pragma unroll
  for (int i = 0; i < 4; ++i)
    t[ty + i * 8][tx] = pi[(size_t)(r0 + ty + i * 8) * rstr + c0 + tx];
  __syncthreads();
#pragma unroll
  for (int i = 0; i < 4; ++i)
    po[(size_t)(c0 + ty + i * 8) * R + r0 + tx] = t[tx][ty + i * 8];
}

// ---------------- f32 -> bf16 elementwise ----------------
__global__ __launch_bounds__(256) void cvt_f32_bf16(
    const float* __restrict__ in, u16* __restrict__ out, int n4) {
  const int i = blockIdx.x * 256 + threadIdx.x;
  if (i >= n4) return;
  f32x4 v = *(const f32x4*)&in[(size_t)i * 4];
  s16x4 o;
#pragma unroll
  for (int j = 0; j < 4; ++j) o[j] = (short)f2bf(v[j]);
  *(s16x4*)&out[(size_t)i * 4] = o;
}

// ---------------- LayerNorm over D=1024 ----------------
template <int WB>
__global__ __launch_bounds__(256) void layernorm_k(
    const float* __restrict__ in, const float* __restrict__ gm, const float* __restrict__ bt,
    float* __restrict__ outF, u16* __restrict__ outB) {
  const int row = blockIdx.x;
  const int t = threadIdx.x;
  const float* xr = in + (size_t)row * 1024;
  f32x4 v = *(const f32x4*)&xr[t * 4];
  float s = v[0] + v[1] + v[2] + v[3];
  float s2 = v[0] * v[0] + v[1] * v[1] + v[2] * v[2] + v[3] * v[3];
#pragma unroll
  for (int o = 32; o; o >>= 1) {
    s += __shfl_down(s, o);
    s2 += __shfl_down(s2, o);
  }
  __shared__ float red[8];
  const int lane = t & 63, wv = t >> 6;
  if (lane == 0) { red[wv] = s; red[4 + wv] = s2; }
  __syncthreads();
  s = red[0] + red[1] + red[2] + red[3];
  s2 = red[4] + red[5] + red[6] + red[7];
  const float mu = s * (1.0f / 1024.0f);
  const float var = fmaxf(s2 * (1.0f / 1024.0f) - mu * mu, 0.0f);
  const float rs = rsqrtf(var + 1e-5f);
  f32x4 g4 = *(const f32x4*)&gm[t * 4];
  f32x4 b4 = *(const f32x4*)&bt[t * 4];
  f32x4 ov;
#pragma unroll
  for (int j = 0; j < 4; ++j) ov[j] = (v[j] - mu) * rs * g4[j] + b4[j];
  *(f32x4*)&outF[(size_t)row * 1024 + t * 4] = ov;
  if (WB) {
    s16x4 ob;
#pragma unroll
    for (int j = 0; j < 4; ++j) ob[j] = (short)f2bf(ov[j]);
    *(s16x4*)&outB[(size_t)row * 1024 + t * 4] = ob;
  }
}

// ---------------- mask tile summary: any() over 64x64 tiles ----------------
__global__ __launch_bounds__(256) void mask_summary(
    const u8* __restrict__ mask, u8* __restrict__ msum) {
  const int kt = blockIdx.x, qt = blockIdx.y, b = blockIdx.z;
  const int tid = threadIdx.x;
  __shared__ int any_flag;
  if (tid == 0) any_flag = 0;
  __syncthreads();
  const u8* base = mask + ((size_t)(b * 2048 + qt * 64 + (tid >> 2))) * 2048 + kt * 64 + (tid & 3) * 16;
  const u32x4 v = *(const u32x4*)base;
  if (v[0] | v[1] | v[2] | v[3]) any_flag = 1;
  __syncthreads();
  if (tid == 0) msum[((size_t)b * 32 + qt) * 32 + kt] = (u8)any_flag;
}

// ---------------- flash attention: R11/R13 body (96us best-measured, frozen) ----------------
__global__ __launch_bounds__(256) void attn_k(
    const u16* __restrict__ QKV, const u16* __restrict__ VT,
    const u8* __restrict__ mask, const u8* __restrict__ msum, u16* __restrict__ out) {
  const int S = 2048, QSTR = 3072, Dm = 1024;
  const int wgid = blockIdx.x;  // 0..1023
  const int xcd = wgid & 7, slot = wgid >> 3;
  const int bh = xcd * 4 + (slot >> 5);  // 4 bh per XCD -> 2MB KV L2-resident
  const int qt = slot & 31;
  const int b = bh >> 4, h = bh & 15;
  const int wave = threadIdx.x >> 6, lane = threadIdx.x & 63;
  const int l15 = lane & 15, l4 = lane >> 4;
  const int q0 = qt * 64 + wave * 16;
  const float CE = 0.125f * 1.44269504f;  // 1/sqrt(64) * log2(e)

  __shared__ __align__(16) u16 lK[2][4096];  // [buf][64 x 64], XOR-swizzled
  __shared__ __align__(16) u16 lV[2][4096];

  const size_t qoff = (size_t)(b * S + q0 + l15) * QSTR + h * 64;
  const s16x8 qa0 = *(const s16x8*)&QKV[qoff + l4 * 8];
  const s16x8 qa1 = *(const s16x8*)&QKV[qoff + 32 + l4 * 8];

  f32x4 o[4] = {};
  float mr = -1e30f, lr = 0.0f;
  const u8* mb = mask + (size_t)b * S * S;
  const u8* msb = msum + (size_t)(b * 32 + qt) * 32;
  const u16* vbase = VT + (size_t)bh * 64 * S;
  const int bS = b * S;

  auto stage = [&](int bi, int kvv) {
#pragma unroll
    for (int c = 0; c < 2; ++c) {
      const int byt = ((c * 4 + wave) * 64 + lane) * 16;
      const int row = byt >> 7;
      const int cb = (byt & 127) ^ ((row & 7) << 4);
      GLDS16(QKV + (size_t)(bS + kvv + row) * QSTR + 1024 + h * 64 + (cb >> 1),
             &lK[bi][(c * 4 + wave) * 512]);
      GLDS16(vbase + (size_t)row * S + kvv + (cb >> 1),
             &lV[bi][(c * 4 + wave) * 512]);
    }
  };

  auto body = [&](int bi, int kvv) {
    if (kvv + 64 < S) stage(bi ^ 1, kvv + 64);
    const char* kbuf = (const char*)&lK[bi][0];
    const char* vbuf = (const char*)&lV[bi][0];

    f32x4 sc[4];
    __builtin_amdgcn_s_setprio(1);
#pragma unroll
    for (int t = 0; t < 4; ++t) {
      const int row = t * 16 + l15;
      const int sw = (row & 7) << 4;
      const s16x8 kf0 = *(const s16x8*)(kbuf + row * 128 + ((l4 * 16) ^ sw));
      const s16x8 kf1 = *(const s16x8*)(kbuf + row * 128 + ((64 + l4 * 16) ^ sw));
      f32x4 z = {};
      z = __builtin_amdgcn_mfma_f32_16x16x32_bf16(kf0, qa0, z, 0, 0, 0);
      z = __builtin_amdgcn_mfma_f32_16x16x32_bf16(kf1, qa1, z, 0, 0, 0);
      sc[t] = z;
    }
    __builtin_amdgcn_s_setprio(0);
    if (msb[kvv >> 6]) {
#pragma unroll
      for (int t = 0; t < 4; ++t) {
        const uchar4 m4 = *(const uchar4*)&mb[(size_t)(q0 + l15) * S + kvv + t * 16 + l4 * 4];
        if (m4.x) sc[t][0] = -1e30f;
        if (m4.y) sc[t][1] = -1e30f;
        if (m4.z) sc[t][2] = -1e30f;
        if (m4.w) sc[t][3] = -1e30f;
      }
    }
    float pm = max3f(sc[0][0], sc[0][1], sc[0][2]);
    pm = max3f(pm, sc[0][3], sc[1][0]);
    pm = max3f(pm, sc[1][1], sc[1][2]);
    pm = max3f(pm, sc[1][3], sc[2][0]);
    pm = max3f(pm, sc[2][1], sc[2][2]);
    pm = max3f(pm, sc[2][3], sc[3][0]);
    pm = max3f(pm, sc[3][1], sc[3][2]);
    pm = fmaxf(pm, sc[3][3]);
    pm = fmaxf(pm, __shfl_xor(pm, 16));
    pm = fmaxf(pm, __shfl_xor(pm, 32));
    if (!__all(pm <= mr + 44.0f)) {  // 44 raw = 8 exp2-units
      const float mn = fmaxf(mr, pm);
      const float al = exp2f((mr - mn) * CE);
      mr = mn;
      lr *= al;
#pragma unroll
      for (int n = 0; n < 4; ++n)
#pragma unroll
        for (int j = 0; j < 4; ++j) o[n][j] *= al;
    }
    const float mrc = mr * CE;
    float rsum = 0.0f;
#pragma unroll
    for (int t = 0; t < 4; ++t)
#pragma unroll
      for (int j = 0; j < 4; ++j) {
        const float p = exp2f(fmaf(sc[t][j], CE, -mrc));
        sc[t][j] = p;
        rsum += p;
      }
    rsum += __shfl_xor(rsum, 16);
    rsum += __shfl_xor(rsum, 32);
    lr += rsum;
    s16x4 pb[4];
#pragma unroll
    for (int t = 0; t < 4; ++t) {
      const u32 lo = cvtpk_bf16(sc[t][0], sc[t][1]);
      const u32 hi = cvtpk_bf16(sc[t][2], sc[t][3]);
      pb[t] = __builtin_bit_cast(s16x4, u32x2{lo, hi});
    }
    __builtin_amdgcn_s_setprio(1);
#pragma unroll
    for (int n = 0; n < 4; ++n) {
      const int row = n * 16 + l15;
      const int sw = (row & 7) << 4;
#pragma unroll
      for (int t = 0; t < 4; ++t) {
        const s16x4 va = *(const s16x4*)(vbuf + row * 128 + ((t * 32 + l4 * 8) ^ sw));
        o[n] = __builtin_amdgcn_mfma_f32_16x16x16bf16_1k(va, pb[t], o[n], 0, 0, 0);
      }
    }
    __builtin_amdgcn_s_setprio(0);
    __syncthreads();
  };

  stage(0, 0);
  __syncthreads();
  for (int kv = 0; kv < S; kv += 128) {
    body(0, kv);
    body(1, kv + 64);
  }
  const float inv = lr > 0.0f ? 1.0f / lr : 0.0f;
  const size_t obase = (size_t)(b * S + q0 + l15) * Dm + h * 64;
#pragma unroll
  for (int n = 0; n < 4; ++n) {
    const u32 lo = cvtpk_bf16(o[n][0] * inv, o[n][1] * inv);
    const u32 hi = cvtpk_bf16(o[n][2] * inv, o[n][3] * inv);
    *(u32x2*)&out[obase + n * 16 + l4 * 4] = u32x2{lo, hi};
  }
}

extern "C" void kernel_launch(void* const* d_in, const int* in_sizes, int n_in,
                              void* d_out, int out_size, void* d_ws, size_t ws_size,
                              hipStream_t stream) {
  (void)in_sizes; (void)n_in; (void)out_size; (void)ws_size;
  const float* x = (const float*)d_in[0];
  const u8* mask = (const u8*)d_in[1];
  const float* Wq = (const float*)d_in[2];
  const float* Wk = (const float*)d_in[3];
  const float* Wv = (const float*)d_in[4];
  const float* Wo = (const float*)d_in[5];
  const float* bo = (const float*)d_in[6];
  const float* W1 = (const float*)d_in[7];
  const float* b1 = (const float*)d_in[8];
  const float* W2 = (const float*)d_in[9];
  const float* b2 = (const float*)d_in[10];
  const float* g1 = (const float*)d_in[11];
  const float* be1 = (const float*)d_in[12];
  const float* g2 = (const float*)d_in[13];
  const float* be2 = (const float*)d_in[14];
  float* outp = (float*)d_out;

  const int B = 2, S = 2048, D = 1024, FF = 4096;
  const int M = B * S;  // 4096
  char* w = (char*)d_ws;
  const size_t MB = 1024 * 1024;
  u16* wqkvT = (u16*)(w + 0 * MB);    // [3072,1024] bf16   [0,6)
  u16* woT = (u16*)(w + 6 * MB);      // [1024,1024]        [6,8)
  u16* w1T = (u16*)(w + 8 * MB);      // [4096,1024]        [8,16)
  u16* w2T = (u16*)(w + 16 * MB);     // [1024,4096]        [16,24)
  u16* xb  = (u16*)(w + 24 * MB);     // [4096,1024]        [24,32)
  u16* qkv = (u16*)(w + 32 * MB);     // [4096,3072]        [32,56)
  u16* vt  = (u16*)(w + 56 * MB);     // [B*H,64,S]         [56,64)
  float* x0f = (float*)(w + 64 * MB); // [4096,1024] f32    [64,80)
  float* x1f = (float*)(w + 80 * MB); //                    [80,96)
  u16* x1b = (u16*)(w + 96 * MB);     // [4096,1024] bf16   [96,104)
  u8* msum = (u8*)(w + 64 * MB);      // 2 KB, dead before x0f is written
  u16* attn_o = xb;                   // xb dead after QKV gemm
  u16* ff1 = (u16*)(w + 32 * MB);     // [4096,4096] bf16, reuses qkv+vt [32,64)
  float* y0f = x0f;

  // weight prep: 4 [1024,1024] transposes batched into ONE dispatch
  transpose4_f32_bf16<<<dim3(32, 32, 4), 256, 0, stream>>>(Wq, Wk, Wv, Wo, wqkvT, woT);
  transpose_f32_bf16<<<dim3(128, 32), 256, 0, stream>>>(W1, w1T, 1024, 4096);
  transpose_f32_bf16<<<dim3(32, 128), 256, 0, stream>>>(W2, w2T, 4096, 1024);
  cvt_f32_bf16<<<dim3(M * D / 4 / 256), 256, 0, stream>>>(x, xb, M * D / 4);
  mask_summary<<<dim3(32, 32, 2), 256, 0, stream>>>(mask, msum);

  // fused QKV projection (2-phase BK=64 128-tile)
  gemm_bt<0, 128><<<dim3(3 * D / 128, M / 128), 256, 0, stream>>>(xb, wqkvT, M, 3 * D, D, nullptr, nullptr, qkv, nullptr);
  // V -> V^T per batch (strided read from qkv cols 2048..3071)
  transpose_bf16_b<<<dim3(32, 64, 2), 256, 0, stream>>>(qkv, vt, 2048, 1024, 3072, 2048);

  // attention: R11-proven body, 1024 blocks
  attn_k<<<dim3(1024), 256, 0, stream>>>(qkv, vt, mask, msum, attn_o);

  // Wo projection + bias + residual(x) -- 2-phase BK=64 BM=64
  gemm_bt<2, 64><<<dim3(D / 128, M / 64), 256, 0, stream>>>(attn_o, woT, M, D, D, bo, x, nullptr, x0f);
  layernorm_k<1><<<dim3(M), 256, 0, stream>>>(x0f, g1, be1, x1f, x1b);
  // FFN1 (2-phase BK=64 128-tile)
  gemm_bt<1, 128><<<dim3(FF / 128, M / 128), 256, 0, stream>>>(x1b, w1T, M, FF, D, b1, nullptr, ff1, nullptr);
  gemm_bt<2, 64><<<dim3(D / 128, M / 64), 256, 0, stream>>>(ff1, w2T, M, D, FF, b2, x1f, nullptr, y0f);
  layernorm_k<0><<<dim3(M), 256, 0, stream>>>(y0f, g2, be2, outp, nullptr);
}

// Round 16
// 268.011 us; speedup vs baseline: 1.1820x; 1.0133x over previous
//
#include <hip/hip_runtime.h>
#include <math.h>

typedef unsigned short u16;
typedef unsigned char u8;
typedef unsigned int u32;
typedef __attribute__((ext_vector_type(4))) float f32x4;
typedef __attribute__((ext_vector_type(8))) short s16x8;
typedef __attribute__((ext_vector_type(4))) short s16x4;
typedef __attribute__((ext_vector_type(4))) u32 u32x4;
typedef __attribute__((ext_vector_type(2))) u32 u32x2;

__device__ __forceinline__ u16 f2bf(float f) {
  unsigned u = __builtin_bit_cast(unsigned, f);
  u += 0x7fffu + ((u >> 16) & 1u);
  return (u16)(u >> 16);
}

__device__ __forceinline__ u32 cvtpk_bf16(float lo, float hi) {
  u32 r;
  asm("v_cvt_pk_bf16_f32 %0, %1, %2" : "=v"(r) : "v"(lo), "v"(hi));
  return r;
}

__device__ __forceinline__ float max3f(float a, float b, float c) {
  return fmaxf(fmaxf(a, b), c);  // fuses to v_max3_f32
}

#define GLDS16(g, l) __builtin_amdgcn_global_load_lds( \
    (const __attribute__((address_space(1))) void*)(g), \
    (__attribute__((address_space(3))) void*)(l), 16, 0, 0)

// ---------------- GEMM 2-phase, BK=64, XOR-swizzled LDS (R15-proven) ----------------
// EPI 0: outB = bf16(acc). EPI 1: bias+ReLU -> bf16. EPI 2: bias+resid -> f32.
// EPI 3 (QKV): Q/K col-tiles (<2048) -> bf16 into outB (stride N); V col-tiles
// (>=2048) -> written TRANSPOSED into vt=(u16*)outF as vt[bh][dk][s] (fuses the
// V^T kernel; 8B s-contiguous stores per lane, block-local scatter).
template <int EPI, int BM>
__global__ __launch_bounds__(256, 2) void gemm_bt(
    const u16* __restrict__ A, const u16* __restrict__ BT, int M, int N, int K,
    const float* __restrict__ bias, const float* __restrict__ resid,
    u16* __restrict__ outB, float* __restrict__ outF) {
  constexpr int MT = BM / 32;
  __shared__ __align__(16) u16 lA[2][BM * 64];
  __shared__ __align__(16) u16 lB[2][128 * 64];
  const int tid = threadIdx.x;
  const int wave = __builtin_amdgcn_readfirstlane(tid >> 6);
  const int lane = tid & 63;
  const int l15 = lane & 15, l4 = lane >> 4;
  const int wr = wave >> 1, wc = wave & 1;
  const int nwg = gridDim.x * gridDim.y;
  int wg = blockIdx.y * gridDim.x + blockIdx.x;
  wg = (wg & 7) * (nwg >> 3) + (wg >> 3);  // XCD swizzle (bijective: nwg%8==0)
  const int bx = wg % gridDim.x, by = wg / gridDim.x;
  const int row0 = by * BM, col0 = bx * 128;

  f32x4 acc[MT][4] = {};

  // stage one BK=64 K-tile; LDS dest linear, global source pre-swizzled
  // with cb ^= (row&7)<<4 (rule #21 both-sides).
  auto stage = [&](int bi, int k0) {
#pragma unroll
    for (int c = 0; c < BM / 32; ++c) {  // A: BM rows x 128B
      const int byt = ((c * 4 + wave) * 64 + lane) * 16;
      const int row = byt >> 7;
      const int cb = (byt & 127) ^ ((row & 7) << 4);
      GLDS16(A + (size_t)(row0 + row) * K + k0 + (cb >> 1), &lA[bi][(c * 4 + wave) * 512]);
    }
#pragma unroll
    for (int c = 0; c < 4; ++c) {  // B: 128 rows x 128B
      const int byt = ((c * 4 + wave) * 64 + lane) * 16;
      const int row = byt >> 7;
      const int cb = (byt & 127) ^ ((row & 7) << 4);
      GLDS16(BT + (size_t)(col0 + row) * K + k0 + (cb >> 1), &lB[bi][(c * 4 + wave) * 512]);
    }
  };

  stage(0, 0);
  __syncthreads();
  int buf = 0;

  for (int k0 = 0; k0 < K; k0 += 64) {
    if (k0 + 64 < K) stage(buf ^ 1, k0 + 64);  // async prefetch; drained at loop-end barrier
    const char* bufA = (const char*)&lA[buf][0];
    const char* bufB = (const char*)&lB[buf][0];
#pragma unroll
    for (int s = 0; s < 2; ++s) {  // two K=32 sub-steps per tile
      s16x8 af[MT], bfr[4];
#pragma unroll
      for (int m = 0; m < MT; ++m) {
        const int row = wr * (BM / 2) + m * 16 + l15;
        af[m] = *(const s16x8*)(bufA + row * 128 + ((s * 64 + l4 * 16) ^ ((row & 7) << 4)));
      }
#pragma unroll
      for (int n = 0; n < 4; ++n) {
        const int row = wc * 64 + n * 16 + l15;
        bfr[n] = *(const s16x8*)(bufB + row * 128 + ((s * 64 + l4 * 16) ^ ((row & 7) << 4)));
      }
#pragma unroll
      for (int m = 0; m < MT; ++m)
#pragma unroll
        for (int n = 0; n < 4; ++n)
          acc[m][n] = __builtin_amdgcn_mfma_f32_16x16x32_bf16(af[m], bfr[n], acc[m][n], 0, 0, 0);
    }
    __syncthreads();
    buf ^= 1;
  }

  if (EPI == 3 && col0 >= 2048) {
    // V block: write transposed into vt[bh][dk][s] (vt passed via outF)
    u16* vtp = (u16*)outF;
#pragma unroll
    for (int m = 0; m < MT; ++m) {
      const int rowb = row0 + wr * (BM / 2) + m * 16 + l4 * 4;
      const int s0 = rowb & 2047, bb = rowb >> 11;
#pragma unroll
      for (int n = 0; n < 4; ++n) {
        const int cv = col0 + wc * 64 + n * 16 + l15 - 2048;
        const int hv = cv >> 6, dk = cv & 63;
        const u32 lo = cvtpk_bf16(acc[m][n][0], acc[m][n][1]);
        const u32 hi = cvtpk_bf16(acc[m][n][2], acc[m][n][3]);
        u16* p = vtp + ((size_t)(bb * 16 + hv) * 64 + dk) * 2048 + s0;
        *(u32x2*)p = u32x2{lo, hi};
      }
    }
    return;
  }

#pragma unroll
  for (int m = 0; m < MT; ++m) {
    const int rowb = row0 + wr * (BM / 2) + m * 16 + l4 * 4;
#pragma unroll
    for (int n = 0; n < 4; ++n) {
      const int col = col0 + wc * 64 + n * 16 + l15;
#pragma unroll
      for (int j = 0; j < 4; ++j) {
        const int r = rowb + j;
        float v = acc[m][n][j];
        if (EPI == 0 || EPI == 3) {
          outB[(size_t)r * N + col] = f2bf(v);
        } else if (EPI == 1) {
          v += bias[col];
          outB[(size_t)r * N + col] = f2bf(v > 0.0f ? v : 0.0f);
        } else {
          v += bias[col] + resid[(size_t)r * N + col];
          outF[(size_t)r * N + col] = v;
        }
      }
    }
  }
}

// ---------------- batched weight transpose f32 -> bf16: 4x [1024,1024] ----------------
__global__ __launch_bounds__(256) void transpose4_f32_bf16(
    const float* __restrict__ s0, const float* __restrict__ s1,
    const float* __restrict__ s2, const float* __restrict__ s3,
    u16* __restrict__ dqkv, u16* __restrict__ dwo) {
  __shared__ float t[32][33];
  const int z = blockIdx.z;
  const float* in = (z == 0) ? s0 : (z == 1) ? s1 : (z == 2) ? s2 : s3;
  u16* out = (z < 3) ? (dqkv + (size_t)z * 1024 * 1024) : dwo;
  const int c0 = blockIdx.x * 32, r0 = blockIdx.y * 32;
  const int tx = threadIdx.x & 31, ty = threadIdx.x >> 5;
#pragma unroll
  for (int i = 0; i < 4; ++i)
    t[ty + i * 8][tx] = in[(size_t)(r0 + ty + i * 8) * 1024 + c0 + tx];
  __syncthreads();
#pragma unroll
  for (int i = 0; i < 4; ++i)
    out[(size_t)(c0 + ty + i * 8) * 1024 + r0 + tx] = f2bf(t[tx][ty + i * 8]);
}

// ---------------- merged W1+W2 transpose f32 -> bf16 (flat 8192-block grid) ----------
__global__ __launch_bounds__(256) void transpose_w12(
    const float* __restrict__ W1, const float* __restrict__ W2,
    u16* __restrict__ w1T, u16* __restrict__ w2T) {
  __shared__ float t[32][33];
  int id = blockIdx.x;
  const float* in;
  u16* out;
  int R, C, bx, by;
  if (id < 4096) {  // W1: [1024,4096] -> [4096,1024]
    in = W1; out = w1T; R = 1024; C = 4096; bx = id & 127; by = id >> 7;
  } else {          // W2: [4096,1024] -> [1024,4096]
    id -= 4096; in = W2; out = w2T; R = 4096; C = 1024; bx = id & 31; by = id >> 5;
  }
  const int c0 = bx * 32, r0 = by * 32;
  const int tx = threadIdx.x & 31, ty = threadIdx.x >> 5;
#pragma unroll
  for (int i = 0; i < 4; ++i)
    t[ty + i * 8][tx] = in[(size_t)(r0 + ty + i * 8) * C + c0 + tx];
  __syncthreads();
#pragma unroll
  for (int i = 0; i < 4; ++i)
    out[(size_t)(c0 + ty + i * 8) * R + r0 + tx] = f2bf(t[tx][ty + i * 8]);
}

// ---------------- f32 -> bf16 elementwise ----------------
__global__ __launch_bounds__(256) void cvt_f32_bf16(
    const float* __restrict__ in, u16* __restrict__ out, int n4) {
  const int i = blockIdx.x * 256 + threadIdx.x;
  if (i >= n4) return;
  f32x4 v = *(const f32x4*)&in[(size_t)i * 4];
  s16x4 o;
#pragma unroll
  for (int j = 0; j < 4; ++j) o[j] = (short)f2bf(v[j]);
  *(s16x4*)&out[(size_t)i * 4] = o;
}

// ---------------- LayerNorm over D=1024 ----------------
template <int WB>
__global__ __launch_bounds__(256) void layernorm_k(
    const float* __restrict__ in, const float* __restrict__ gm, const float* __restrict__ bt,
    float* __restrict__ outF, u16* __restrict__ outB) {
  const int row = blockIdx.x;
  const int t = threadIdx.x;
  const float* xr = in + (size_t)row * 1024;
  f32x4 v = *(const f32x4*)&xr[t * 4];
  float s = v[0] + v[1] + v[2] + v[3];
  float s2 = v[0] * v[0] + v[1] * v[1] + v[2] * v[2] + v[3] * v[3];
#pragma unroll
  for (int o = 32; o; o >>= 1) {
    s += __shfl_down(s, o);
    s2 += __shfl_down(s2, o);
  }
  __shared__ float red[8];
  const int lane = t & 63, wv = t >> 6;
  if (lane == 0) { red[wv] = s; red[4 + wv] = s2; }
  __syncthreads();
  s = red[0] + red[1] + red[2] + red[3];
  s2 = red[4] + red[5] + red[6] + red[7];
  const float mu = s * (1.0f / 1024.0f);
  const float var = fmaxf(s2 * (1.0f / 1024.0f) - mu * mu, 0.0f);
  const float rs = rsqrtf(var + 1e-5f);
  f32x4 g4 = *(const f32x4*)&gm[t * 4];
  f32x4 b4 = *(const f32x4*)&bt[t * 4];
  f32x4 ov;
#pragma unroll
  for (int j = 0; j < 4; ++j) ov[j] = (v[j] - mu) * rs * g4[j] + b4[j];
  *(f32x4*)&outF[(size_t)row * 1024 + t * 4] = ov;
  if (WB) {
    s16x4 ob;
#pragma unroll
    for (int j = 0; j < 4; ++j) ob[j] = (short)f2bf(ov[j]);
    *(s16x4*)&outB[(size_t)row * 1024 + t * 4] = ob;
  }
}

// ---------------- mask tile summary: any() over 64x64 tiles ----------------
__global__ __launch_bounds__(256) void mask_summary(
    const u8* __restrict__ mask, u8* __restrict__ msum) {
  const int kt = blockIdx.x, qt = blockIdx.y, b = blockIdx.z;
  const int tid = threadIdx.x;
  __shared__ int any_flag;
  if (tid == 0) any_flag = 0;
  __syncthreads();
  const u8* base = mask + ((size_t)(b * 2048 + qt * 64 + (tid >> 2))) * 2048 + kt * 64 + (tid & 3) * 16;
  const u32x4 v = *(const u32x4*)base;
  if (v[0] | v[1] | v[2] | v[3]) any_flag = 1;
  __syncthreads();
  if (tid == 0) msum[((size_t)b * 32 + qt) * 32 + kt] = (u8)any_flag;
}

// ---------------- flash attention: R11/R13 body (96us best-measured, frozen) ----------------
__global__ __launch_bounds__(256) void attn_k(
    const u16* __restrict__ QKV, const u16* __restrict__ VT,
    const u8* __restrict__ mask, const u8* __restrict__ msum, u16* __restrict__ out) {
  const int S = 2048, QSTR = 3072, Dm = 1024;
  const int wgid = blockIdx.x;  // 0..1023
  const int xcd = wgid & 7, slot = wgid >> 3;
  const int bh = xcd * 4 + (slot >> 5);  // 4 bh per XCD -> 2MB KV L2-resident
  const int qt = slot & 31;
  const int b = bh >> 4, h = bh & 15;
  const int wave = threadIdx.x >> 6, lane = threadIdx.x & 63;
  const int l15 = lane & 15, l4 = lane >> 4;
  const int q0 = qt * 64 + wave * 16;
  const float CE = 0.125f * 1.44269504f;  // 1/sqrt(64) * log2(e)

  __shared__ __align__(16) u16 lK[2][4096];  // [buf][64 x 64], XOR-swizzled
  __shared__ __align__(16) u16 lV[2][4096];

  const size_t qoff = (size_t)(b * S + q0 + l15) * QSTR + h * 64;
  const s16x8 qa0 = *(const s16x8*)&QKV[qoff + l4 * 8];
  const s16x8 qa1 = *(const s16x8*)&QKV[qoff + 32 + l4 * 8];

  f32x4 o[4] = {};
  float mr = -1e30f, lr = 0.0f;
  const u8* mb = mask + (size_t)b * S * S;
  const u8* msb = msum + (size_t)(b * 32 + qt) * 32;
  const u16* vbase = VT + (size_t)bh * 64 * S;
  const int bS = b * S;

  auto stage = [&](int bi, int kvv) {
#pragma unroll
    for (int c = 0; c < 2; ++c) {
      const int byt = ((c * 4 + wave) * 64 + lane) * 16;
      const int row = byt >> 7;
      const int cb = (byt & 127) ^ ((row & 7) << 4);
      GLDS16(QKV + (size_t)(bS + kvv + row) * QSTR + 1024 + h * 64 + (cb >> 1),
             &lK[bi][(c * 4 + wave) * 512]);
      GLDS16(vbase + (size_t)row * S + kvv + (cb >> 1),
             &lV[bi][(c * 4 + wave) * 512]);
    }
  };

  auto body = [&](int bi, int kvv) {
    if (kvv + 64 < S) stage(bi ^ 1, kvv + 64);
    const char* kbuf = (const char*)&lK[bi][0];
    const char* vbuf = (const char*)&lV[bi][0];

    f32x4 sc[4];
    __builtin_amdgcn_s_setprio(1);
#pragma unroll
    for (int t = 0; t < 4; ++t) {
      const int row = t * 16 + l15;
      const int sw = (row & 7) << 4;
      const s16x8 kf0 = *(const s16x8*)(kbuf + row * 128 + ((l4 * 16) ^ sw));
      const s16x8 kf1 = *(const s16x8*)(kbuf + row * 128 + ((64 + l4 * 16) ^ sw));
      f32x4 z = {};
      z = __builtin_amdgcn_mfma_f32_16x16x32_bf16(kf0, qa0, z, 0, 0, 0);
      z = __builtin_amdgcn_mfma_f32_16x16x32_bf16(kf1, qa1, z, 0, 0, 0);
      sc[t] = z;
    }
    __builtin_amdgcn_s_setprio(0);
    if (msb[kvv >> 6]) {
#pragma unroll
      for (int t = 0; t < 4; ++t) {
        const uchar4 m4 = *(const uchar4*)&mb[(size_t)(q0 + l15) * S + kvv + t * 16 + l4 * 4];
        if (m4.x) sc[t][0] = -1e30f;
        if (m4.y) sc[t][1] = -1e30f;
        if (m4.z) sc[t][2] = -1e30f;
        if (m4.w) sc[t][3] = -1e30f;
      }
    }
    float pm = max3f(sc[0][0], sc[0][1], sc[0][2]);
    pm = max3f(pm, sc[0][3], sc[1][0]);
    pm = max3f(pm, sc[1][1], sc[1][2]);
    pm = max3f(pm, sc[1][3], sc[2][0]);
    pm = max3f(pm, sc[2][1], sc[2][2]);
    pm = max3f(pm, sc[2][3], sc[3][0]);
    pm = max3f(pm, sc[3][1], sc[3][2]);
    pm = fmaxf(pm, sc[3][3]);
    pm = fmaxf(pm, __shfl_xor(pm, 16));
    pm = fmaxf(pm, __shfl_xor(pm, 32));
    if (!__all(pm <= mr + 44.0f)) {  // 44 raw = 8 exp2-units
      const float mn = fmaxf(mr, pm);
      const float al = exp2f((mr - mn) * CE);
      mr = mn;
      lr *= al;
#pragma unroll
      for (int n = 0; n < 4; ++n)
#pragma unroll
        for (int j = 0; j < 4; ++j) o[n][j] *= al;
    }
    const float mrc = mr * CE;
    float rsum = 0.0f;
#pragma unroll
    for (int t = 0; t < 4; ++t)
#pragma unroll
      for (int j = 0; j < 4; ++j) {
        const float p = exp2f(fmaf(sc[t][j], CE, -mrc));
        sc[t][j] = p;
        rsum += p;
      }
    rsum += __shfl_xor(rsum, 16);
    rsum += __shfl_xor(rsum, 32);
    lr += rsum;
    s16x4 pb[4];
#pragma unroll
    for (int t = 0; t < 4; ++t) {
      const u32 lo = cvtpk_bf16(sc[t][0], sc[t][1]);
      const u32 hi = cvtpk_bf16(sc[t][2], sc[t][3]);
      pb[t] = __builtin_bit_cast(s16x4, u32x2{lo, hi});
    }
    __builtin_amdgcn_s_setprio(1);
#pragma unroll
    for (int n = 0; n < 4; ++n) {
      const int row = n * 16 + l15;
      const int sw = (row & 7) << 4;
#pragma unroll
      for (int t = 0; t < 4; ++t) {
        const s16x4 va = *(const s16x4*)(vbuf + row * 128 + ((t * 32 + l4 * 8) ^ sw));
        o[n] = __builtin_amdgcn_mfma_f32_16x16x16bf16_1k(va, pb[t], o[n], 0, 0, 0);
      }
    }
    __builtin_amdgcn_s_setprio(0);
    __syncthreads();
  };

  stage(0, 0);
  __syncthreads();
  for (int kv = 0; kv < S; kv += 128) {
    body(0, kv);
    body(1, kv + 64);
  }
  const float inv = lr > 0.0f ? 1.0f / lr : 0.0f;
  const size_t obase = (size_t)(b * S + q0 + l15) * Dm + h * 64;
#pragma unroll
  for (int n = 0; n < 4; ++n) {
    const u32 lo = cvtpk_bf16(o[n][0] * inv, o[n][1] * inv);
    const u32 hi = cvtpk_bf16(o[n][2] * inv, o[n][3] * inv);
    *(u32x2*)&out[obase + n * 16 + l4 * 4] = u32x2{lo, hi};
  }
}

extern "C" void kernel_launch(void* const* d_in, const int* in_sizes, int n_in,
                              void* d_out, int out_size, void* d_ws, size_t ws_size,
                              hipStream_t stream) {
  (void)in_sizes; (void)n_in; (void)out_size; (void)ws_size;
  const float* x = (const float*)d_in[0];
  const u8* mask = (const u8*)d_in[1];
  const float* Wq = (const float*)d_in[2];
  const float* Wk = (const float*)d_in[3];
  const float* Wv = (const float*)d_in[4];
  const float* Wo = (const float*)d_in[5];
  const float* bo = (const float*)d_in[6];
  const float* W1 = (const float*)d_in[7];
  const float* b1 = (const float*)d_in[8];
  const float* W2 = (const float*)d_in[9];
  const float* b2 = (const float*)d_in[10];
  const float* g1 = (const float*)d_in[11];
  const float* be1 = (const float*)d_in[12];
  const float* g2 = (const float*)d_in[13];
  const float* be2 = (const float*)d_in[14];
  float* outp = (float*)d_out;

  const int B = 2, S = 2048, D = 1024, FF = 4096;
  const int M = B * S;  // 4096
  char* w = (char*)d_ws;
  const size_t MB = 1024 * 1024;
  u16* wqkvT = (u16*)(w + 0 * MB);    // [3072,1024] bf16   [0,6)
  u16* woT = (u16*)(w + 6 * MB);      // [1024,1024]        [6,8)
  u16* w1T = (u16*)(w + 8 * MB);      // [4096,1024]        [8,16)
  u16* w2T = (u16*)(w + 16 * MB);     // [1024,4096]        [16,24)
  u16* xb  = (u16*)(w + 24 * MB);     // [4096,1024]        [24,32)
  u16* qkv = (u16*)(w + 32 * MB);     // [4096,3072]        [32,56)
  u16* vt  = (u16*)(w + 56 * MB);     // [B*H,64,S]         [56,64)
  float* x0f = (float*)(w + 64 * MB); // [4096,1024] f32    [64,80)
  float* x1f = (float*)(w + 80 * MB); //                    [80,96)
  u16* x1b = (u16*)(w + 96 * MB);     // [4096,1024] bf16   [96,104)
  u8* msum = (u8*)(w + 64 * MB);      // 2 KB, dead before x0f is written
  u16* attn_o = xb;                   // xb dead after QKV gemm
  u16* ff1 = (u16*)(w + 32 * MB);     // [4096,4096] bf16, reuses qkv+vt [32,64)
  float* y0f = x0f;

  // weight prep: QKVO transposes in ONE dispatch; W1+W2 in ONE dispatch
  transpose4_f32_bf16<<<dim3(32, 32, 4), 256, 0, stream>>>(Wq, Wk, Wv, Wo, wqkvT, woT);
  transpose_w12<<<dim3(8192), 256, 0, stream>>>(W1, W2, w1T, w2T);
  cvt_f32_bf16<<<dim3(M * D / 4 / 256), 256, 0, stream>>>(x, xb, M * D / 4);
  mask_summary<<<dim3(32, 32, 2), 256, 0, stream>>>(mask, msum);

  // fused QKV projection; V third written directly transposed into vt (EPI=3)
  gemm_bt<3, 128><<<dim3(3 * D / 128, M / 128), 256, 0, stream>>>(xb, wqkvT, M, 3 * D, D, nullptr, nullptr, qkv, (float*)vt);

  // attention: R11-proven body, 1024 blocks
  attn_k<<<dim3(1024), 256, 0, stream>>>(qkv, vt, mask, msum, attn_o);

  // Wo projection + bias + residual(x) -- 2-phase BK=64 BM=64
  gemm_bt<2, 64><<<dim3(D / 128, M / 64), 256, 0, stream>>>(attn_o, woT, M, D, D, bo, x, nullptr, x0f);
  layernorm_k<1><<<dim3(M), 256, 0, stream>>>(x0f, g1, be1, x1f, x1b);
  // FFN1 (2-phase BK=64 128-tile)
  gemm_bt<1, 128><<<dim3(FF / 128, M / 128), 256, 0, stream>>>(x1b, w1T, M, FF, D, b1, nullptr, ff1, nullptr);
  gemm_bt<2, 64><<<dim3(D / 128, M / 64), 256, 0, stream>>>(ff1, w2T, M, D, FF, b2, x1f, nullptr, y0f);
  layernorm_k<0><<<dim3(M), 256, 0, stream>>>(y0f, g2, be2, outp, nullptr);
}

// Round 17
// 261.253 us; speedup vs baseline: 1.2126x; 1.0259x over previous
//
#include <hip/hip_runtime.h>
#include <math.h>

typedef unsigned short u16;
typedef unsigned char u8;
typedef unsigned int u32;
typedef __attribute__((ext_vector_type(4))) float f32x4;
typedef __attribute__((ext_vector_type(8))) short s16x8;
typedef __attribute__((ext_vector_type(4))) short s16x4;
typedef __attribute__((ext_vector_type(4))) u32 u32x4;
typedef __attribute__((ext_vector_type(2))) u32 u32x2;

__device__ __forceinline__ u16 f2bf(float f) {
  unsigned u = __builtin_bit_cast(unsigned, f);
  u += 0x7fffu + ((u >> 16) & 1u);
  return (u16)(u >> 16);
}

__device__ __forceinline__ u32 cvtpk_bf16(float lo, float hi) {
  u32 r;
  asm("v_cvt_pk_bf16_f32 %0, %1, %2" : "=v"(r) : "v"(lo), "v"(hi));
  return r;
}

__device__ __forceinline__ float max3f(float a, float b, float c) {
  return fmaxf(fmaxf(a, b), c);  // fuses to v_max3_f32
}

#define GLDS16(g, l) __builtin_amdgcn_global_load_lds( \
    (const __attribute__((address_space(1))) void*)(g), \
    (__attribute__((address_space(3))) void*)(l), 16, 0, 0)

// ---------------- GEMM 2-phase, BK=64, XOR-swizzled LDS (R15/R16-proven) ----------------
// EPI 0: outB = bf16(acc). EPI 1: bias+ReLU -> bf16. EPI 2: bias+resid -> f32.
// EPI 3 (QKV): Q/K col-tiles -> outB; V col-tiles (>=2048) transposed into vt (outF).
template <int EPI, int BM>
__global__ __launch_bounds__(256, 2) void gemm_bt(
    const u16* __restrict__ A, const u16* __restrict__ BT, int M, int N, int K,
    const float* __restrict__ bias, const float* __restrict__ resid,
    u16* __restrict__ outB, float* __restrict__ outF) {
  constexpr int MT = BM / 32;
  __shared__ __align__(16) u16 lA[2][BM * 64];
  __shared__ __align__(16) u16 lB[2][128 * 64];
  const int tid = threadIdx.x;
  const int wave = __builtin_amdgcn_readfirstlane(tid >> 6);
  const int lane = tid & 63;
  const int l15 = lane & 15, l4 = lane >> 4;
  const int wr = wave >> 1, wc = wave & 1;
  const int nwg = gridDim.x * gridDim.y;
  int wg = blockIdx.y * gridDim.x + blockIdx.x;
  wg = (wg & 7) * (nwg >> 3) + (wg >> 3);  // XCD swizzle (bijective: nwg%8==0)
  const int bx = wg % gridDim.x, by = wg / gridDim.x;
  const int row0 = by * BM, col0 = bx * 128;

  f32x4 acc[MT][4] = {};

  auto stage = [&](int bi, int k0) {
#pragma unroll
    for (int c = 0; c < BM / 32; ++c) {  // A: BM rows x 128B
      const int byt = ((c * 4 + wave) * 64 + lane) * 16;
      const int row = byt >> 7;
      const int cb = (byt & 127) ^ ((row & 7) << 4);
      GLDS16(A + (size_t)(row0 + row) * K + k0 + (cb >> 1), &lA[bi][(c * 4 + wave) * 512]);
    }
#pragma unroll
    for (int c = 0; c < 4; ++c) {  // B: 128 rows x 128B
      const int byt = ((c * 4 + wave) * 64 + lane) * 16;
      const int row = byt >> 7;
      const int cb = (byt & 127) ^ ((row & 7) << 4);
      GLDS16(BT + (size_t)(col0 + row) * K + k0 + (cb >> 1), &lB[bi][(c * 4 + wave) * 512]);
    }
  };

  stage(0, 0);
  __syncthreads();
  int buf = 0;

  for (int k0 = 0; k0 < K; k0 += 64) {
    if (k0 + 64 < K) stage(buf ^ 1, k0 + 64);  // async prefetch; drained at loop-end barrier
    const char* bufA = (const char*)&lA[buf][0];
    const char* bufB = (const char*)&lB[buf][0];
#pragma unroll
    for (int s = 0; s < 2; ++s) {
      s16x8 af[MT], bfr[4];
#pragma unroll
      for (int m = 0; m < MT; ++m) {
        const int row = wr * (BM / 2) + m * 16 + l15;
        af[m] = *(const s16x8*)(bufA + row * 128 + ((s * 64 + l4 * 16) ^ ((row & 7) << 4)));
      }
#pragma unroll
      for (int n = 0; n < 4; ++n) {
        const int row = wc * 64 + n * 16 + l15;
        bfr[n] = *(const s16x8*)(bufB + row * 128 + ((s * 64 + l4 * 16) ^ ((row & 7) << 4)));
      }
#pragma unroll
      for (int m = 0; m < MT; ++m)
#pragma unroll
        for (int n = 0; n < 4; ++n)
          acc[m][n] = __builtin_amdgcn_mfma_f32_16x16x32_bf16(af[m], bfr[n], acc[m][n], 0, 0, 0);
    }
    __syncthreads();
    buf ^= 1;
  }

  if (EPI == 3 && col0 >= 2048) {
    // V block: write transposed into vt[bh][dk][s] (vt passed via outF)
    u16* vtp = (u16*)outF;
#pragma unroll
    for (int m = 0; m < MT; ++m) {
      const int rowb = row0 + wr * (BM / 2) + m * 16 + l4 * 4;
      const int s0 = rowb & 2047, bb = rowb >> 11;
#pragma unroll
      for (int n = 0; n < 4; ++n) {
        const int cv = col0 + wc * 64 + n * 16 + l15 - 2048;
        const int hv = cv >> 6, dk = cv & 63;
        const u32 lo = cvtpk_bf16(acc[m][n][0], acc[m][n][1]);
        const u32 hi = cvtpk_bf16(acc[m][n][2], acc[m][n][3]);
        u16* p = vtp + ((size_t)(bb * 16 + hv) * 64 + dk) * 2048 + s0;
        *(u32x2*)p = u32x2{lo, hi};
      }
    }
    return;
  }

#pragma unroll
  for (int m = 0; m < MT; ++m) {
    const int rowb = row0 + wr * (BM / 2) + m * 16 + l4 * 4;
#pragma unroll
    for (int n = 0; n < 4; ++n) {
      const int col = col0 + wc * 64 + n * 16 + l15;
#pragma unroll
      for (int j = 0; j < 4; ++j) {
        const int r = rowb + j;
        float v = acc[m][n][j];
        if (EPI == 0 || EPI == 3) {
          outB[(size_t)r * N + col] = f2bf(v);
        } else if (EPI == 1) {
          v += bias[col];
          outB[(size_t)r * N + col] = f2bf(v > 0.0f ? v : 0.0f);
        } else {
          v += bias[col] + resid[(size_t)r * N + col];
          outF[(size_t)r * N + col] = v;
        }
      }
    }
  }
}

// ---------------- ALL weight transposes f32 -> bf16 in one flat dispatch ----------------
// id<4096: four 1024x1024 (Wq/Wk/Wv->wqkvT blocks, Wo->woT); 4096..8191: W1; else W2.
__global__ __launch_bounds__(256) void prep_weights(
    const float* __restrict__ Wq, const float* __restrict__ Wk,
    const float* __restrict__ Wv, const float* __restrict__ Wo,
    const float* __restrict__ W1, const float* __restrict__ W2,
    u16* __restrict__ wqkvT, u16* __restrict__ woT,
    u16* __restrict__ w1T, u16* __restrict__ w2T) {
  __shared__ float t[32][33];
  int id = blockIdx.x;
  const float* in;
  u16* out;
  int R, C, bx, by;
  if (id < 4096) {
    const int z = id >> 10, r = id & 1023;
    in = (z == 0) ? Wq : (z == 1) ? Wk : (z == 2) ? Wv : Wo;
    out = (z < 3) ? (wqkvT + (size_t)z * 1024 * 1024) : woT;
    R = 1024; C = 1024; bx = r & 31; by = r >> 5;
  } else if (id < 8192) {
    const int r = id - 4096;
    in = W1; out = w1T; R = 1024; C = 4096; bx = r & 127; by = r >> 7;
  } else {
    const int r = id - 8192;
    in = W2; out = w2T; R = 4096; C = 1024; bx = r & 31; by = r >> 5;
  }
  const int c0 = bx * 32, r0 = by * 32;
  const int tx = threadIdx.x & 31, ty = threadIdx.x >> 5;
#pragma unroll
  for (int i = 0; i < 4; ++i)
    t[ty + i * 8][tx] = in[(size_t)(r0 + ty + i * 8) * C + c0 + tx];
  __syncthreads();
#pragma unroll
  for (int i = 0; i < 4; ++i)
    out[(size_t)(c0 + ty + i * 8) * R + r0 + tx] = f2bf(t[tx][ty + i * 8]);
}

// ---------------- f32 -> bf16 elementwise ----------------
__global__ __launch_bounds__(256) void cvt_f32_bf16(
    const float* __restrict__ in, u16* __restrict__ out, int n4) {
  const int i = blockIdx.x * 256 + threadIdx.x;
  if (i >= n4) return;
  f32x4 v = *(const f32x4*)&in[(size_t)i * 4];
  s16x4 o;
#pragma unroll
  for (int j = 0; j < 4; ++j) o[j] = (short)f2bf(v[j]);
  *(s16x4*)&out[(size_t)i * 4] = o;
}

// ---------------- LayerNorm over D=1024 ----------------
template <int WB>
__global__ __launch_bounds__(256) void layernorm_k(
    const float* __restrict__ in, const float* __restrict__ gm, const float* __restrict__ bt,
    float* __restrict__ outF, u16* __restrict__ outB) {
  const int row = blockIdx.x;
  const int t = threadIdx.x;
  const float* xr = in + (size_t)row * 1024;
  f32x4 v = *(const f32x4*)&xr[t * 4];
  float s = v[0] + v[1] + v[2] + v[3];
  float s2 = v[0] * v[0] + v[1] * v[1] + v[2] * v[2] + v[3] * v[3];
#pragma unroll
  for (int o = 32; o; o >>= 1) {
    s += __shfl_down(s, o);
    s2 += __shfl_down(s2, o);
  }
  __shared__ float red[8];
  const int lane = t & 63, wv = t >> 6;
  if (lane == 0) { red[wv] = s; red[4 + wv] = s2; }
  __syncthreads();
  s = red[0] + red[1] + red[2] + red[3];
  s2 = red[4] + red[5] + red[6] + red[7];
  const float mu = s * (1.0f / 1024.0f);
  const float var = fmaxf(s2 * (1.0f / 1024.0f) - mu * mu, 0.0f);
  const float rs = rsqrtf(var + 1e-5f);
  f32x4 g4 = *(const f32x4*)&gm[t * 4];
  f32x4 b4 = *(const f32x4*)&bt[t * 4];
  f32x4 ov;
#pragma unroll
  for (int j = 0; j < 4; ++j) ov[j] = (v[j] - mu) * rs * g4[j] + b4[j];
  *(f32x4*)&outF[(size_t)row * 1024 + t * 4] = ov;
  if (WB) {
    s16x4 ob;
#pragma unroll
    for (int j = 0; j < 4; ++j) ob[j] = (short)f2bf(ov[j]);
    *(s16x4*)&outB[(size_t)row * 1024 + t * 4] = ob;
  }
}

// ---------------- mask tile summary: any() over 64x64 tiles ----------------
__global__ __launch_bounds__(256) void mask_summary(
    const u8* __restrict__ mask, u8* __restrict__ msum) {
  const int kt = blockIdx.x, qt = blockIdx.y, b = blockIdx.z;
  const int tid = threadIdx.x;
  __shared__ int any_flag;
  if (tid == 0) any_flag = 0;
  __syncthreads();
  const u8* base = mask + ((size_t)(b * 2048 + qt * 64 + (tid >> 2))) * 2048 + kt * 64 + (tid & 3) * 16;
  const u32x4 v = *(const u32x4*)base;
  if (v[0] | v[1] | v[2] | v[3]) any_flag = 1;
  __syncthreads();
  if (tid == 0) msum[((size_t)b * 32 + qt) * 32 + kt] = (u8)any_flag;
}

// ---------------- flash attention: frozen 64-VGPR wave body, 8 waves share K/V ----------
// 512 blocks x 512 threads. Each wave = one 16-row q-group (identical to the proven
// R11/R13 body); 8 waves (128 q-rows) share one staged K/V tile -> half the K/V
// fetch and half the stage issues per q-row vs the 4-wave version. Same residency
// (2 blocks/CU x 8 waves = 16 waves/CU, 32KB LDS/block, VGPR 64).
__global__ __launch_bounds__(512) void attn_k(
    const u16* __restrict__ QKV, const u16* __restrict__ VT,
    const u8* __restrict__ mask, const u8* __restrict__ msum, u16* __restrict__ out) {
  const int S = 2048, QSTR = 3072, Dm = 1024;
  const int wgid = blockIdx.x;  // 0..511
  const int xcd = wgid & 7, slot = wgid >> 3;  // slot 0..63
  const int bh = xcd * 4 + (slot >> 4);        // 4 bh per XCD -> KV L2-resident
  const int qt = slot & 15;                    // 16 q-tiles of 128 rows
  const int b = bh >> 4, h = bh & 15;
  const int wave = threadIdx.x >> 6, lane = threadIdx.x & 63;
  const int l15 = lane & 15, l4 = lane >> 4;
  const int q0 = qt * 128 + wave * 16;
  const float CE = 0.125f * 1.44269504f;  // 1/sqrt(64) * log2(e)

  __shared__ __align__(16) u16 lK[2][4096];  // [buf][64 x 64], XOR-swizzled
  __shared__ __align__(16) u16 lV[2][4096];

  const size_t qoff = (size_t)(b * S + q0 + l15) * QSTR + h * 64;
  const s16x8 qa0 = *(const s16x8*)&QKV[qoff + l4 * 8];
  const s16x8 qa1 = *(const s16x8*)&QKV[qoff + 32 + l4 * 8];

  f32x4 o[4] = {};
  float mr = -1e30f, lr = 0.0f;
  const u8* mb = mask + (size_t)b * S * S;
  const u8* msb = msum + (size_t)(b * 32 + qt * 2 + (wave >> 2)) * 32;
  const u16* vbase = VT + (size_t)bh * 64 * S;
  const int bS = b * S;

  // 8 waves each stage 1KB of K and V per kv-64 tile (one GLDS16 per matrix).
  auto stage = [&](int bi, int kvv) {
    const int byt = (wave * 64 + lane) * 16;  // 0..8191
    const int row = byt >> 7;
    const int cb = (byt & 127) ^ ((row & 7) << 4);
    GLDS16(QKV + (size_t)(bS + kvv + row) * QSTR + 1024 + h * 64 + (cb >> 1),
           &lK[bi][wave * 512]);
    GLDS16(vbase + (size_t)row * S + kvv + (cb >> 1),
           &lV[bi][wave * 512]);
  };

  auto body = [&](int bi, int kvv) {
    if (kvv + 64 < S) stage(bi ^ 1, kvv + 64);
    const char* kbuf = (const char*)&lK[bi][0];
    const char* vbuf = (const char*)&lV[bi][0];

    f32x4 sc[4];
    __builtin_amdgcn_s_setprio(1);
#pragma unroll
    for (int t = 0; t < 4; ++t) {
      const int row = t * 16 + l15;
      const int sw = (row & 7) << 4;
      const s16x8 kf0 = *(const s16x8*)(kbuf + row * 128 + ((l4 * 16) ^ sw));
      const s16x8 kf1 = *(const s16x8*)(kbuf + row * 128 + ((64 + l4 * 16) ^ sw));
      f32x4 z = {};
      z = __builtin_amdgcn_mfma_f32_16x16x32_bf16(kf0, qa0, z, 0, 0, 0);
      z = __builtin_amdgcn_mfma_f32_16x16x32_bf16(kf1, qa1, z, 0, 0, 0);
      sc[t] = z;
    }
    __builtin_amdgcn_s_setprio(0);
    if (msb[kvv >> 6]) {
#pragma unroll
      for (int t = 0; t < 4; ++t) {
        const uchar4 m4 = *(const uchar4*)&mb[(size_t)(q0 + l15) * S + kvv + t * 16 + l4 * 4];
        if (m4.x) sc[t][0] = -1e30f;
        if (m4.y) sc[t][1] = -1e30f;
        if (m4.z) sc[t][2] = -1e30f;
        if (m4.w) sc[t][3] = -1e30f;
      }
    }
    float pm = max3f(sc[0][0], sc[0][1], sc[0][2]);
    pm = max3f(pm, sc[0][3], sc[1][0]);
    pm = max3f(pm, sc[1][1], sc[1][2]);
    pm = max3f(pm, sc[1][3], sc[2][0]);
    pm = max3f(pm, sc[2][1], sc[2][2]);
    pm = max3f(pm, sc[2][3], sc[3][0]);
    pm = max3f(pm, sc[3][1], sc[3][2]);
    pm = fmaxf(pm, sc[3][3]);
    pm = fmaxf(pm, __shfl_xor(pm, 16));
    pm = fmaxf(pm, __shfl_xor(pm, 32));
    if (!__all(pm <= mr + 44.0f)) {  // 44 raw = 8 exp2-units
      const float mn = fmaxf(mr, pm);
      const float al = exp2f((mr - mn) * CE);
      mr = mn;
      lr *= al;
#pragma unroll
      for (int n = 0; n < 4; ++n)
#pragma unroll
        for (int j = 0; j < 4; ++j) o[n][j] *= al;
    }
    const float mrc = mr * CE;
    float rsum = 0.0f;
#pragma unroll
    for (int t = 0; t < 4; ++t)
#pragma unroll
      for (int j = 0; j < 4; ++j) {
        const float p = exp2f(fmaf(sc[t][j], CE, -mrc));
        sc[t][j] = p;
        rsum += p;
      }
    rsum += __shfl_xor(rsum, 16);
    rsum += __shfl_xor(rsum, 32);
    lr += rsum;
    s16x4 pb[4];
#pragma unroll
    for (int t = 0; t < 4; ++t) {
      const u32 lo = cvtpk_bf16(sc[t][0], sc[t][1]);
      const u32 hi = cvtpk_bf16(sc[t][2], sc[t][3]);
      pb[t] = __builtin_bit_cast(s16x4, u32x2{lo, hi});
    }
    __builtin_amdgcn_s_setprio(1);
#pragma unroll
    for (int n = 0; n < 4; ++n) {
      const int row = n * 16 + l15;
      const int sw = (row & 7) << 4;
#pragma unroll
      for (int t = 0; t < 4; ++t) {
        const s16x4 va = *(const s16x4*)(vbuf + row * 128 + ((t * 32 + l4 * 8) ^ sw));
        o[n] = __builtin_amdgcn_mfma_f32_16x16x16bf16_1k(va, pb[t], o[n], 0, 0, 0);
      }
    }
    __builtin_amdgcn_s_setprio(0);
    __syncthreads();
  };

  stage(0, 0);
  __syncthreads();
  for (int kv = 0; kv < S; kv += 128) {
    body(0, kv);
    body(1, kv + 64);
  }
  const float inv = lr > 0.0f ? 1.0f / lr : 0.0f;
  const size_t obase = (size_t)(b * S + q0 + l15) * Dm + h * 64;
#pragma unroll
  for (int n = 0; n < 4; ++n) {
    const u32 lo = cvtpk_bf16(o[n][0] * inv, o[n][1] * inv);
    const u32 hi = cvtpk_bf16(o[n][2] * inv, o[n][3] * inv);
    *(u32x2*)&out[obase + n * 16 + l4 * 4] = u32x2{lo, hi};
  }
}

extern "C" void kernel_launch(void* const* d_in, const int* in_sizes, int n_in,
                              void* d_out, int out_size, void* d_ws, size_t ws_size,
                              hipStream_t stream) {
  (void)in_sizes; (void)n_in; (void)out_size; (void)ws_size;
  const float* x = (const float*)d_in[0];
  const u8* mask = (const u8*)d_in[1];
  const float* Wq = (const float*)d_in[2];
  const float* Wk = (const float*)d_in[3];
  const float* Wv = (const float*)d_in[4];
  const float* Wo = (const float*)d_in[5];
  const float* bo = (const float*)d_in[6];
  const float* W1 = (const float*)d_in[7];
  const float* b1 = (const float*)d_in[8];
  const float* W2 = (const float*)d_in[9];
  const float* b2 = (const float*)d_in[10];
  const float* g1 = (const float*)d_in[11];
  const float* be1 = (const float*)d_in[12];
  const float* g2 = (const float*)d_in[13];
  const float* be2 = (const float*)d_in[14];
  float* outp = (float*)d_out;

  const int B = 2, S = 2048, D = 1024, FF = 4096;
  const int M = B * S;  // 4096
  char* w = (char*)d_ws;
  const size_t MB = 1024 * 1024;
  u16* wqkvT = (u16*)(w + 0 * MB);    // [3072,1024] bf16   [0,6)
  u16* woT = (u16*)(w + 6 * MB);      // [1024,1024]        [6,8)
  u16* w1T = (u16*)(w + 8 * MB);      // [4096,1024]        [8,16)
  u16* w2T = (u16*)(w + 16 * MB);     // [1024,4096]        [16,24)
  u16* xb  = (u16*)(w + 24 * MB);     // [4096,1024]        [24,32)
  u16* qkv = (u16*)(w + 32 * MB);     // [4096,3072]        [32,56)
  u16* vt  = (u16*)(w + 56 * MB);     // [B*H,64,S]         [56,64)
  float* x0f = (float*)(w + 64 * MB); // [4096,1024] f32    [64,80)
  float* x1f = (float*)(w + 80 * MB); //                    [80,96)
  u16* x1b = (u16*)(w + 96 * MB);     // [4096,1024] bf16   [96,104)
  u8* msum = (u8*)(w + 64 * MB);      // 2 KB, dead before x0f is written
  u16* attn_o = xb;                   // xb dead after QKV gemm
  u16* ff1 = (u16*)(w + 32 * MB);     // [4096,4096] bf16, reuses qkv+vt [32,64)
  float* y0f = x0f;

  // weight prep: ALL transposes in ONE dispatch
  prep_weights<<<dim3(12288), 256, 0, stream>>>(Wq, Wk, Wv, Wo, W1, W2, wqkvT, woT, w1T, w2T);
  cvt_f32_bf16<<<dim3(M * D / 4 / 256), 256, 0, stream>>>(x, xb, M * D / 4);
  mask_summary<<<dim3(32, 32, 2), 256, 0, stream>>>(mask, msum);

  // fused QKV projection; V third written directly transposed into vt (EPI=3)
  gemm_bt<3, 128><<<dim3(3 * D / 128, M / 128), 256, 0, stream>>>(xb, wqkvT, M, 3 * D, D, nullptr, nullptr, qkv, (float*)vt);

  // attention: 512 blocks x 8 waves (frozen wave body, shared K/V staging)
  attn_k<<<dim3(512), 512, 0, stream>>>(qkv, vt, mask, msum, attn_o);

  // Wo projection + bias + residual(x) -- 2-phase BK=64 BM=64
  gemm_bt<2, 64><<<dim3(D / 128, M / 64), 256, 0, stream>>>(attn_o, woT, M, D, D, bo, x, nullptr, x0f);
  layernorm_k<1><<<dim3(M), 256, 0, stream>>>(x0f, g1, be1, x1f, x1b);
  // FFN1 (2-phase BK=64 128-tile)
  gemm_bt<1, 128><<<dim3(FF / 128, M / 128), 256, 0, stream>>>(x1b, w1T, M, FF, D, b1, nullptr, ff1, nullptr);
  gemm_bt<2, 64><<<dim3(D / 128, M / 64), 256, 0, stream>>>(ff1, w2T, M, D, FF, b2, x1f, nullptr, y0f);
  layernorm_k<0><<<dim3(M), 256, 0, stream>>>(y0f, g2, be2, outp, nullptr);
}

// Round 18
// 256.440 us; speedup vs baseline: 1.2354x; 1.0188x over previous
//
#include <hip/hip_runtime.h>
#include <math.h>

typedef unsigned short u16;
typedef unsigned char u8;
typedef unsigned int u32;
typedef __attribute__((ext_vector_type(4))) float f32x4;
typedef __attribute__((ext_vector_type(8))) short s16x8;
typedef __attribute__((ext_vector_type(4))) short s16x4;
typedef __attribute__((ext_vector_type(4))) u32 u32x4;
typedef __attribute__((ext_vector_type(2))) u32 u32x2;

__device__ __forceinline__ u16 f2bf(float f) {
  unsigned u = __builtin_bit_cast(unsigned, f);
  u += 0x7fffu + ((u >> 16) & 1u);
  return (u16)(u >> 16);
}

__device__ __forceinline__ u32 cvtpk_bf16(float lo, float hi) {
  u32 r;
  asm("v_cvt_pk_bf16_f32 %0, %1, %2" : "=v"(r) : "v"(lo), "v"(hi));
  return r;
}

__device__ __forceinline__ float max3f(float a, float b, float c) {
  return fmaxf(fmaxf(a, b), c);  // fuses to v_max3_f32
}

#define GLDS16(g, l) __builtin_amdgcn_global_load_lds( \
    (const __attribute__((address_space(1))) void*)(g), \
    (__attribute__((address_space(3))) void*)(l), 16, 0, 0)

// ---------------- GEMM 2-phase, BK=64, XOR-swizzled LDS (R15/R16-proven) ----------------
// EPI 0: outB = bf16(acc). EPI 1: bias+ReLU -> bf16. EPI 2: bias+resid -> f32.
// EPI 3 (QKV): Q/K col-tiles -> outB; V col-tiles (>=2048) transposed into vt (outF).
template <int EPI, int BM>
__global__ __launch_bounds__(256, 2) void gemm_bt(
    const u16* __restrict__ A, const u16* __restrict__ BT, int M, int N, int K,
    const float* __restrict__ bias, const float* __restrict__ resid,
    u16* __restrict__ outB, float* __restrict__ outF) {
  constexpr int MT = BM / 32;
  __shared__ __align__(16) u16 lA[2][BM * 64];
  __shared__ __align__(16) u16 lB[2][128 * 64];
  const int tid = threadIdx.x;
  const int wave = __builtin_amdgcn_readfirstlane(tid >> 6);
  const int lane = tid & 63;
  const int l15 = lane & 15, l4 = lane >> 4;
  const int wr = wave >> 1, wc = wave & 1;
  const int nwg = gridDim.x * gridDim.y;
  int wg = blockIdx.y * gridDim.x + blockIdx.x;
  wg = (wg & 7) * (nwg >> 3) + (wg >> 3);  // XCD swizzle (bijective: nwg%8==0)
  const int bx = wg % gridDim.x, by = wg / gridDim.x;
  const int row0 = by * BM, col0 = bx * 128;

  f32x4 acc[MT][4] = {};

  auto stage = [&](int bi, int k0) {
#pragma unroll
    for (int c = 0; c < BM / 32; ++c) {  // A: BM rows x 128B
      const int byt = ((c * 4 + wave) * 64 + lane) * 16;
      const int row = byt >> 7;
      const int cb = (byt & 127) ^ ((row & 7) << 4);
      GLDS16(A + (size_t)(row0 + row) * K + k0 + (cb >> 1), &lA[bi][(c * 4 + wave) * 512]);
    }
#pragma unroll
    for (int c = 0; c < 4; ++c) {  // B: 128 rows x 128B
      const int byt = ((c * 4 + wave) * 64 + lane) * 16;
      const int row = byt >> 7;
      const int cb = (byt & 127) ^ ((row & 7) << 4);
      GLDS16(BT + (size_t)(col0 + row) * K + k0 + (cb >> 1), &lB[bi][(c * 4 + wave) * 512]);
    }
  };

  stage(0, 0);
  __syncthreads();
  int buf = 0;

  for (int k0 = 0; k0 < K; k0 += 64) {
    if (k0 + 64 < K) stage(buf ^ 1, k0 + 64);  // async prefetch; drained at loop-end barrier
    const char* bufA = (const char*)&lA[buf][0];
    const char* bufB = (const char*)&lB[buf][0];
#pragma unroll
    for (int s = 0; s < 2; ++s) {
      s16x8 af[MT], bfr[4];
#pragma unroll
      for (int m = 0; m < MT; ++m) {
        const int row = wr * (BM / 2) + m * 16 + l15;
        af[m] = *(const s16x8*)(bufA + row * 128 + ((s * 64 + l4 * 16) ^ ((row & 7) << 4)));
      }
#pragma unroll
      for (int n = 0; n < 4; ++n) {
        const int row = wc * 64 + n * 16 + l15;
        bfr[n] = *(const s16x8*)(bufB + row * 128 + ((s * 64 + l4 * 16) ^ ((row & 7) << 4)));
      }
#pragma unroll
      for (int m = 0; m < MT; ++m)
#pragma unroll
        for (int n = 0; n < 4; ++n)
          acc[m][n] = __builtin_amdgcn_mfma_f32_16x16x32_bf16(af[m], bfr[n], acc[m][n], 0, 0, 0);
    }
    __syncthreads();
    buf ^= 1;
  }

  if (EPI == 3 && col0 >= 2048) {
    // V block: write transposed into vt[bh][dk][s] (vt passed via outF)
    u16* vtp = (u16*)outF;
#pragma unroll
    for (int m = 0; m < MT; ++m) {
      const int rowb = row0 + wr * (BM / 2) + m * 16 + l4 * 4;
      const int s0 = rowb & 2047, bb = rowb >> 11;
#pragma unroll
      for (int n = 0; n < 4; ++n) {
        const int cv = col0 + wc * 64 + n * 16 + l15 - 2048;
        const int hv = cv >> 6, dk = cv & 63;
        const u32 lo = cvtpk_bf16(acc[m][n][0], acc[m][n][1]);
        const u32 hi = cvtpk_bf16(acc[m][n][2], acc[m][n][3]);
        u16* p = vtp + ((size_t)(bb * 16 + hv) * 64 + dk) * 2048 + s0;
        *(u32x2*)p = u32x2{lo, hi};
      }
    }
    return;
  }

#pragma unroll
  for (int m = 0; m < MT; ++m) {
    const int rowb = row0 + wr * (BM / 2) + m * 16 + l4 * 4;
#pragma unroll
    for (int n = 0; n < 4; ++n) {
      const int col = col0 + wc * 64 + n * 16 + l15;
#pragma unroll
      for (int j = 0; j < 4; ++j) {
        const int r = rowb + j;
        float v = acc[m][n][j];
        if (EPI == 0 || EPI == 3) {
          outB[(size_t)r * N + col] = f2bf(v);
        } else if (EPI == 1) {
          v += bias[col];
          outB[(size_t)r * N + col] = f2bf(v > 0.0f ? v : 0.0f);
        } else {
          v += bias[col] + resid[(size_t)r * N + col];
          outF[(size_t)r * N + col] = v;
        }
      }
    }
  }
}

// ---------------- ALL weight transposes f32 -> bf16 in one flat dispatch ----------------
__global__ __launch_bounds__(256) void prep_weights(
    const float* __restrict__ Wq, const float* __restrict__ Wk,
    const float* __restrict__ Wv, const float* __restrict__ Wo,
    const float* __restrict__ W1, const float* __restrict__ W2,
    u16* __restrict__ wqkvT, u16* __restrict__ woT,
    u16* __restrict__ w1T, u16* __restrict__ w2T) {
  __shared__ float t[32][33];
  int id = blockIdx.x;
  const float* in;
  u16* out;
  int R, C, bx, by;
  if (id < 4096) {
    const int z = id >> 10, r = id & 1023;
    in = (z == 0) ? Wq : (z == 1) ? Wk : (z == 2) ? Wv : Wo;
    out = (z < 3) ? (wqkvT + (size_t)z * 1024 * 1024) : woT;
    R = 1024; C = 1024; bx = r & 31; by = r >> 5;
  } else if (id < 8192) {
    const int r = id - 4096;
    in = W1; out = w1T; R = 1024; C = 4096; bx = r & 127; by = r >> 7;
  } else {
    const int r = id - 8192;
    in = W2; out = w2T; R = 4096; C = 1024; bx = r & 31; by = r >> 5;
  }
  const int c0 = bx * 32, r0 = by * 32;
  const int tx = threadIdx.x & 31, ty = threadIdx.x >> 5;
#pragma unroll
  for (int i = 0; i < 4; ++i)
    t[ty + i * 8][tx] = in[(size_t)(r0 + ty + i * 8) * C + c0 + tx];
  __syncthreads();
#pragma unroll
  for (int i = 0; i < 4; ++i)
    out[(size_t)(c0 + ty + i * 8) * R + r0 + tx] = f2bf(t[tx][ty + i * 8]);
}

// ---------------- f32 -> bf16 elementwise ----------------
__global__ __launch_bounds__(256) void cvt_f32_bf16(
    const float* __restrict__ in, u16* __restrict__ out, int n4) {
  const int i = blockIdx.x * 256 + threadIdx.x;
  if (i >= n4) return;
  f32x4 v = *(const f32x4*)&in[(size_t)i * 4];
  s16x4 o;
#pragma unroll
  for (int j = 0; j < 4; ++j) o[j] = (short)f2bf(v[j]);
  *(s16x4*)&out[(size_t)i * 4] = o;
}

// ---------------- LayerNorm over D=1024 ----------------
template <int WB>
__global__ __launch_bounds__(256) void layernorm_k(
    const float* __restrict__ in, const float* __restrict__ gm, const float* __restrict__ bt,
    float* __restrict__ outF, u16* __restrict__ outB) {
  const int row = blockIdx.x;
  const int t = threadIdx.x;
  const float* xr = in + (size_t)row * 1024;
  f32x4 v = *(const f32x4*)&xr[t * 4];
  float s = v[0] + v[1] + v[2] + v[3];
  float s2 = v[0] * v[0] + v[1] * v[1] + v[2] * v[2] + v[3] * v[3];
#pragma unroll
  for (int o = 32; o; o >>= 1) {
    s += __shfl_down(s, o);
    s2 += __shfl_down(s2, o);
  }
  __shared__ float red[8];
  const int lane = t & 63, wv = t >> 6;
  if (lane == 0) { red[wv] = s; red[4 + wv] = s2; }
  __syncthreads();
  s = red[0] + red[1] + red[2] + red[3];
  s2 = red[4] + red[5] + red[6] + red[7];
  const float mu = s * (1.0f / 1024.0f);
  const float var = fmaxf(s2 * (1.0f / 1024.0f) - mu * mu, 0.0f);
  const float rs = rsqrtf(var + 1e-5f);
  f32x4 g4 = *(const f32x4*)&gm[t * 4];
  f32x4 b4 = *(const f32x4*)&bt[t * 4];
  f32x4 ov;
#pragma unroll
  for (int j = 0; j < 4; ++j) ov[j] = (v[j] - mu) * rs * g4[j] + b4[j];
  *(f32x4*)&outF[(size_t)row * 1024 + t * 4] = ov;
  if (WB) {
    s16x4 ob;
#pragma unroll
    for (int j = 0; j < 4; ++j) ob[j] = (short)f2bf(ov[j]);
    *(s16x4*)&outB[(size_t)row * 1024 + t * 4] = ob;
  }
}

// ---------------- mask tile summary: any() over 64x64 tiles ----------------
__global__ __launch_bounds__(256) void mask_summary(
    const u8* __restrict__ mask, u8* __restrict__ msum) {
  const int kt = blockIdx.x, qt = blockIdx.y, b = blockIdx.z;
  const int tid = threadIdx.x;
  __shared__ int any_flag;
  if (tid == 0) any_flag = 0;
  __syncthreads();
  const u8* base = mask + ((size_t)(b * 2048 + qt * 64 + (tid >> 2))) * 2048 + kt * 64 + (tid & 3) * 16;
  const u32x4 v = *(const u32x4*)base;
  if (v[0] | v[1] | v[2] | v[3]) any_flag = 1;
  __syncthreads();
  if (tid == 0) msum[((size_t)b * 32 + qt) * 32 + kt] = (u8)any_flag;
}

// ---------------- flash attention: 8-wave shared staging, KVBLK=128 ----------------
// 512 blocks x 512 threads; wave = one frozen 16-row q-group. Staged tile now
// covers 128 kv rows (K: [128][64] 16KB; VT: [64][128] 16KB; x2 dbuf = 64KB LDS)
// -> 16 barriers/block instead of 32, and each barrier-drain hides under 2x compute.
// Same 2-phase protocol: stage(next) -> compute both 64-halves -> one barrier.
__global__ __launch_bounds__(512) void attn_k(
    const u16* __restrict__ QKV, const u16* __restrict__ VT,
    const u8* __restrict__ mask, const u8* __restrict__ msum, u16* __restrict__ out) {
  const int S = 2048, QSTR = 3072, Dm = 1024;
  const int wgid = blockIdx.x;  // 0..511
  const int xcd = wgid & 7, slot = wgid >> 3;  // slot 0..63
  const int bh = xcd * 4 + (slot >> 4);        // 4 bh per XCD -> KV L2-resident
  const int qt = slot & 15;                    // 16 q-tiles of 128 rows
  const int b = bh >> 4, h = bh & 15;
  const int wave = threadIdx.x >> 6, lane = threadIdx.x & 63;
  const int l15 = lane & 15, l4 = lane >> 4;
  const int q0 = qt * 128 + wave * 16;
  const float CE = 0.125f * 1.44269504f;  // 1/sqrt(64) * log2(e)

  __shared__ __align__(16) u16 lK[2][8192];  // [buf][128 kv x 64 dk], 128B rows, XOR-swz
  __shared__ __align__(16) u16 lV[2][8192];  // [buf][64 dk x 128 kv], 256B rows, XOR-swz

  const size_t qoff = (size_t)(b * S + q0 + l15) * QSTR + h * 64;
  const s16x8 qa0 = *(const s16x8*)&QKV[qoff + l4 * 8];
  const s16x8 qa1 = *(const s16x8*)&QKV[qoff + 32 + l4 * 8];

  f32x4 o[4] = {};
  float mr = -1e30f, lr = 0.0f;
  const u8* mb = mask + (size_t)b * S * S;
  const u8* msb = msum + (size_t)(b * 32 + qt * 2 + (wave >> 2)) * 32;
  const u16* vbase = VT + (size_t)bh * 64 * S;
  const int bS = b * S;

  // stage one kv-128 tile: each wave moves 2KB of K and 2KB of V (2 GLDS16 each).
  auto stage = [&](int bi, int kvv) {
#pragma unroll
    for (int c = 0; c < 2; ++c) {
      const int byt = ((c * 8 + wave) * 64 + lane) * 16;  // 0..16383
      const int krow = byt >> 7;                           // K: 128B rows
      const int kcb = (byt & 127) ^ ((krow & 7) << 4);
      GLDS16(QKV + (size_t)(bS + kvv + krow) * QSTR + 1024 + h * 64 + (kcb >> 1),
             &lK[bi][(c * 8 + wave) * 512]);
      const int vrow = byt >> 8;                           // V: 256B rows
      const int vcb = (byt & 255) ^ ((vrow & 7) << 4);
      GLDS16(vbase + (size_t)vrow * S + kvv + (vcb >> 1),
             &lV[bi][(c * 8 + wave) * 512]);
    }
  };

  auto body = [&](int bi, int kvv) {
    if (kvv + 128 < S) stage(bi ^ 1, kvv + 128);
    const char* kbuf = (const char*)&lK[bi][0];
    const char* vbuf = (const char*)&lV[bi][0];
#pragma unroll
    for (int hf = 0; hf < 2; ++hf) {
      const int kvh = kvv + hf * 64;
      // ---- QK^T (swapped): sc[t] = mfma(K, Q) ----
      f32x4 sc[4];
      __builtin_amdgcn_s_setprio(1);
#pragma unroll
      for (int t = 0; t < 4; ++t) {
        const int row = hf * 64 + t * 16 + l15;
        const int sw = (row & 7) << 4;
        const s16x8 kf0 = *(const s16x8*)(kbuf + row * 128 + ((l4 * 16) ^ sw));
        const s16x8 kf1 = *(const s16x8*)(kbuf + row * 128 + ((64 + l4 * 16) ^ sw));
        f32x4 z = {};
        z = __builtin_amdgcn_mfma_f32_16x16x32_bf16(kf0, qa0, z, 0, 0, 0);
        z = __builtin_amdgcn_mfma_f32_16x16x32_bf16(kf1, qa1, z, 0, 0, 0);
        sc[t] = z;
      }
      __builtin_amdgcn_s_setprio(0);
      // ---- mask (rare slow path via tile summary) ----
      if (msb[kvh >> 6]) {
#pragma unroll
        for (int t = 0; t < 4; ++t) {
          const uchar4 m4 = *(const uchar4*)&mb[(size_t)(q0 + l15) * S + kvh + t * 16 + l4 * 4];
          if (m4.x) sc[t][0] = -1e30f;
          if (m4.y) sc[t][1] = -1e30f;
          if (m4.z) sc[t][2] = -1e30f;
          if (m4.w) sc[t][3] = -1e30f;
        }
      }
      // ---- online softmax with defer-max; max via v_max3 tree ----
      float pm = max3f(sc[0][0], sc[0][1], sc[0][2]);
      pm = max3f(pm, sc[0][3], sc[1][0]);
      pm = max3f(pm, sc[1][1], sc[1][2]);
      pm = max3f(pm, sc[1][3], sc[2][0]);
      pm = max3f(pm, sc[2][1], sc[2][2]);
      pm = max3f(pm, sc[2][3], sc[3][0]);
      pm = max3f(pm, sc[3][1], sc[3][2]);
      pm = fmaxf(pm, sc[3][3]);
      pm = fmaxf(pm, __shfl_xor(pm, 16));
      pm = fmaxf(pm, __shfl_xor(pm, 32));
      if (!__all(pm <= mr + 44.0f)) {  // 44 raw = 8 exp2-units
        const float mn = fmaxf(mr, pm);
        const float al = exp2f((mr - mn) * CE);
        mr = mn;
        lr *= al;
#pragma unroll
        for (int n = 0; n < 4; ++n)
#pragma unroll
          for (int j = 0; j < 4; ++j) o[n][j] *= al;
      }
      const float mrc = mr * CE;
      float rsum = 0.0f;
#pragma unroll
      for (int t = 0; t < 4; ++t)
#pragma unroll
        for (int j = 0; j < 4; ++j) {
          const float p = exp2f(fmaf(sc[t][j], CE, -mrc));
          sc[t][j] = p;
          rsum += p;
        }
      rsum += __shfl_xor(rsum, 16);
      rsum += __shfl_xor(rsum, 32);
      lr += rsum;
      // ---- pack P into 16x16x16 B-frags (zero cross-lane) ----
      s16x4 pb[4];
#pragma unroll
      for (int t = 0; t < 4; ++t) {
        const u32 lo = cvtpk_bf16(sc[t][0], sc[t][1]);
        const u32 hi = cvtpk_bf16(sc[t][2], sc[t][3]);
        pb[t] = __builtin_bit_cast(s16x4, u32x2{lo, hi});
      }
      // ---- PV: o[n] += mfma_16x16x16(V frag, P frag) ----
      __builtin_amdgcn_s_setprio(1);
#pragma unroll
      for (int n = 0; n < 4; ++n) {
        const int row = n * 16 + l15;
        const int sw = (row & 7) << 4;
#pragma unroll
        for (int t = 0; t < 4; ++t) {
          const s16x4 va = *(const s16x4*)(vbuf + row * 256 + ((hf * 128 + t * 32 + l4 * 8) ^ sw));
          o[n] = __builtin_amdgcn_mfma_f32_16x16x16bf16_1k(va, pb[t], o[n], 0, 0, 0);
        }
      }
      __builtin_amdgcn_s_setprio(0);
    }
    __syncthreads();  // drains prefetch vmcnt + protects buf swap
  };

  stage(0, 0);
  __syncthreads();
  for (int kv = 0; kv < S; kv += 256) {  // x2 unroll: buf compile-time per body
    body(0, kv);
    body(1, kv + 128);
  }
  const float inv = lr > 0.0f ? 1.0f / lr : 0.0f;
  const size_t obase = (size_t)(b * S + q0 + l15) * Dm + h * 64;
#pragma unroll
  for (int n = 0; n < 4; ++n) {
    const u32 lo = cvtpk_bf16(o[n][0] * inv, o[n][1] * inv);
    const u32 hi = cvtpk_bf16(o[n][2] * inv, o[n][3] * inv);
    *(u32x2*)&out[obase + n * 16 + l4 * 4] = u32x2{lo, hi};
  }
}

extern "C" void kernel_launch(void* const* d_in, const int* in_sizes, int n_in,
                              void* d_out, int out_size, void* d_ws, size_t ws_size,
                              hipStream_t stream) {
  (void)in_sizes; (void)n_in; (void)out_size; (void)ws_size;
  const float* x = (const float*)d_in[0];
  const u8* mask = (const u8*)d_in[1];
  const float* Wq = (const float*)d_in[2];
  const float* Wk = (const float*)d_in[3];
  const float* Wv = (const float*)d_in[4];
  const float* Wo = (const float*)d_in[5];
  const float* bo = (const float*)d_in[6];
  const float* W1 = (const float*)d_in[7];
  const float* b1 = (const float*)d_in[8];
  const float* W2 = (const float*)d_in[9];
  const float* b2 = (const float*)d_in[10];
  const float* g1 = (const float*)d_in[11];
  const float* be1 = (const float*)d_in[12];
  const float* g2 = (const float*)d_in[13];
  const float* be2 = (const float*)d_in[14];
  float* outp = (float*)d_out;

  const int B = 2, S = 2048, D = 1024, FF = 4096;
  const int M = B * S;  // 4096
  char* w = (char*)d_ws;
  const size_t MB = 1024 * 1024;
  u16* wqkvT = (u16*)(w + 0 * MB);    // [3072,1024] bf16   [0,6)
  u16* woT = (u16*)(w + 6 * MB);      // [1024,1024]        [6,8)
  u16* w1T = (u16*)(w + 8 * MB);      // [4096,1024]        [8,16)
  u16* w2T = (u16*)(w + 16 * MB);     // [1024,4096]        [16,24)
  u16* xb  = (u16*)(w + 24 * MB);     // [4096,1024]        [24,32)
  u16* qkv = (u16*)(w + 32 * MB);     // [4096,3072]        [32,56)
  u16* vt  = (u16*)(w + 56 * MB);     // [B*H,64,S]         [56,64)
  float* x0f = (float*)(w + 64 * MB); // [4096,1024] f32    [64,80)
  float* x1f = (float*)(w + 80 * MB); //                    [80,96)
  u16* x1b = (u16*)(w + 96 * MB);     // [4096,1024] bf16   [96,104)
  u8* msum = (u8*)(w + 64 * MB);      // 2 KB, dead before x0f is written
  u16* attn_o = xb;                   // xb dead after QKV gemm
  u16* ff1 = (u16*)(w + 32 * MB);     // [4096,4096] bf16, reuses qkv+vt [32,64)
  float* y0f = x0f;

  // weight prep: ALL transposes in ONE dispatch
  prep_weights<<<dim3(12288), 256, 0, stream>>>(Wq, Wk, Wv, Wo, W1, W2, wqkvT, woT, w1T, w2T);
  cvt_f32_bf16<<<dim3(M * D / 4 / 256), 256, 0, stream>>>(x, xb, M * D / 4);
  mask_summary<<<dim3(32, 32, 2), 256, 0, stream>>>(mask, msum);

  // fused QKV projection; V third written directly transposed into vt (EPI=3)
  gemm_bt<3, 128><<<dim3(3 * D / 128, M / 128), 256, 0, stream>>>(xb, wqkvT, M, 3 * D, D, nullptr, nullptr, qkv, (float*)vt);

  // attention: 512 blocks x 8 waves, KVBLK=128 (16 barriers/block)
  attn_k<<<dim3(512), 512, 0, stream>>>(qkv, vt, mask, msum, attn_o);

  // Wo projection + bias + residual(x) -- 2-phase BK=64 BM=64
  gemm_bt<2, 64><<<dim3(D / 128, M / 64), 256, 0, stream>>>(attn_o, woT, M, D, D, bo, x, nullptr, x0f);
  layernorm_k<1><<<dim3(M), 256, 0, stream>>>(x0f, g1, be1, x1f, x1b);
  // FFN1 (2-phase BK=64 128-tile)
  gemm_bt<1, 128><<<dim3(FF / 128, M / 128), 256, 0, stream>>>(x1b, w1T, M, FF, D, b1, nullptr, ff1, nullptr);
  gemm_bt<2, 64><<<dim3(D / 128, M / 64), 256, 0, stream>>>(ff1, w2T, M, D, FF, b2, x1f, nullptr, y0f);
  layernorm_k<0><<<dim3(M), 256, 0, stream>>>(y0f, g2, be2, outp, nullptr);
}